// Round 1
// baseline (8267.403 us; speedup 1.0000x reference)
//
#include <hip/hip_runtime.h>
#include <hip/hip_bf16.h>
#include <cstdint>
#include <cstddef>

#define NW 30000
#define NE 30000
#define EE 480000
#define HD 512
#define NL 4
#define SLOPE 0.2f
#define LAM 0.5f

static __device__ __forceinline__ float lrelu_f(float x){
    return fmaxf(x, 0.f) + SLOPE * fminf(x, 0.f);
}

// ---------------- CSR build ----------------

__global__ void count_kernel(const int* __restrict__ dst, int* __restrict__ deg, int E){
    int e = blockIdx.x * 256 + threadIdx.x;
    if (e < E) atomicAdd(&deg[dst[e]], 1);
}

// 3 relations, one block each; inclusive scan -> exclusive offsets
__global__ void scan3_kernel(const int* d0, int n0, int* o0,
                             const int* d1, int n1, int* o1,
                             const int* d2, int n2, int* o2){
    const int* deg; int n; int* off;
    if (blockIdx.x == 0){ deg=d0; n=n0; off=o0; }
    else if (blockIdx.x == 1){ deg=d1; n=n1; off=o1; }
    else { deg=d2; n=n2; off=o2; }
    __shared__ int tmp[1024];
    int t = threadIdx.x;
    int carry = 0;
    if (t == 0) off[0] = 0;
    for (int base = 0; base < n; base += 1024){
        int v = (base + t < n) ? deg[base + t] : 0;
        tmp[t] = v; __syncthreads();
        for (int d = 1; d < 1024; d <<= 1){
            int add = (t >= d) ? tmp[t - d] : 0;
            __syncthreads();
            tmp[t] += add;
            __syncthreads();
        }
        if (base + t < n) off[base + t + 1] = tmp[t] + carry;
        carry += tmp[1023];
        __syncthreads();
    }
}

__global__ void fill_kernel(const int* __restrict__ src, const int* __restrict__ dst,
                            int* __restrict__ cur, const int* __restrict__ off,
                            int* __restrict__ elist, int E){
    int e = blockIdx.x * 256 + threadIdx.x;
    if (e < E){
        int d = dst[e];
        int p = atomicAdd(&cur[d], 1);
        elist[off[d] + p] = src[e];
    }
}

// ---------------- segment mean (one block per dst node) ----------------

__global__ __launch_bounds__(256)
void seg_mean_kernel(const float* __restrict__ h, const int* __restrict__ off,
                     const int* __restrict__ elist, float* __restrict__ out){
    int dst = blockIdx.x;
    int t = threadIdx.x;
    int s0 = off[dst], s1 = off[dst + 1];
    float a0 = 0.f, a1 = 0.f;
    for (int e = s0; e < s1; ++e){
        int src = elist[e];
        const float* row = h + (size_t)src * HD;
        a0 += row[t];
        a1 += row[t + 256];
    }
    float inv = (s1 > s0) ? 1.0f / (float)(s1 - s0) : 0.0f;
    size_t o = (size_t)dst * HD;
    out[o + t] = a0 * inv;
    out[o + t + 256] = a1 * inv;
}

// ---------------- fp32 tiled GEMM: C (+)= A[M,K] @ B[K,N] (+bias)(lrelu) ----------------

template<int ACCUM, int BIAS, int ACT, int AVEC>
__global__ __launch_bounds__(256)
void gemm_kernel(const float* __restrict__ A, const float* __restrict__ B,
                 const float* __restrict__ bias, float* __restrict__ C,
                 int M, int N, int K){
    const int BM = 128, BN = 64, BK = 16;
    __shared__ float As[BK][BM];
    __shared__ float Bs[BK][BN];
    int m0 = blockIdx.y * BM, n0 = blockIdx.x * BN;
    int t = threadIdx.x;
    int tx = t & 15, ty = t >> 4;
    float acc[8][4] = {};
    for (int k0 = 0; k0 < K; k0 += BK){
        if (AVEC){
            #pragma unroll
            for (int i = 0; i < 2; ++i){
                int idx = i * 256 + t;      // 0..511
                int row = idx >> 2;         // 0..127
                int kg  = idx & 3;          // 0..3
                float4 v = make_float4(0,0,0,0);
                int gr = m0 + row, gk = k0 + kg * 4;
                if (gr < M){
                    if (gk + 4 <= K){
                        v = *reinterpret_cast<const float4*>(A + (size_t)gr * K + gk);
                    } else {
                        float tp[4] = {0,0,0,0};
                        #pragma unroll
                        for (int j = 0; j < 4; ++j) if (gk + j < K) tp[j] = A[(size_t)gr * K + gk + j];
                        v = make_float4(tp[0], tp[1], tp[2], tp[3]);
                    }
                }
                As[kg*4+0][row] = v.x; As[kg*4+1][row] = v.y;
                As[kg*4+2][row] = v.z; As[kg*4+3][row] = v.w;
            }
        } else {
            #pragma unroll
            for (int j = 0; j < 8; ++j){
                int idx = j * 256 + t;
                int row = idx >> 4, k = idx & 15;
                int gr = m0 + row, gk = k0 + k;
                float v = (gr < M && gk < K) ? A[(size_t)gr * K + gk] : 0.0f;
                As[k][row] = v;
            }
        }
        {
            int row = t >> 4, cg = t & 15;
            int gk = k0 + row, col = n0 + cg * 4;
            float4 v = make_float4(0,0,0,0);
            if (gk < K){
                if (col + 4 <= N){
                    v = *reinterpret_cast<const float4*>(B + (size_t)gk * N + col);
                } else {
                    float tp[4] = {0,0,0,0};
                    #pragma unroll
                    for (int j = 0; j < 4; ++j) if (col + j < N) tp[j] = B[(size_t)gk * N + col + j];
                    v = make_float4(tp[0], tp[1], tp[2], tp[3]);
                }
            }
            *reinterpret_cast<float4*>(&Bs[row][cg*4]) = v;
        }
        __syncthreads();
        #pragma unroll
        for (int k = 0; k < BK; ++k){
            float a[8], b[4];
            #pragma unroll
            for (int r = 0; r < 8; ++r) a[r] = As[k][ty*8 + r];
            #pragma unroll
            for (int c = 0; c < 4; ++c) b[c] = Bs[k][tx*4 + c];
            #pragma unroll
            for (int r = 0; r < 8; ++r)
                #pragma unroll
                for (int c = 0; c < 4; ++c)
                    acc[r][c] = fmaf(a[r], b[c], acc[r][c]);
        }
        __syncthreads();
    }
    #pragma unroll
    for (int r = 0; r < 8; ++r){
        int gr = m0 + ty*8 + r;
        if (gr >= M) continue;
        #pragma unroll
        for (int c = 0; c < 4; ++c){
            int gc = n0 + tx*4 + c;
            if (gc >= N) continue;
            float v = acc[r][c];
            if (BIAS) v += bias[gc];
            if (ACCUM) v += C[(size_t)gr * N + gc];
            if (ACT) v = lrelu_f(v);
            C[(size_t)gr * N + gc] = v;
        }
    }
}

// ---------------- elementwise ----------------

__global__ void lrelu_scale_kernel(const float* __restrict__ x, float* __restrict__ y,
                                   float s, int n4){
    int i = blockIdx.x * 256 + threadIdx.x;
    if (i < n4){
        float4 v = reinterpret_cast<const float4*>(x)[i];
        v.x = lrelu_f(v.x * s); v.y = lrelu_f(v.y * s);
        v.z = lrelu_f(v.z * s); v.w = lrelu_f(v.w * s);
        reinterpret_cast<float4*>(y)[i] = v;
    }
}

__global__ void addmat_kernel(const float* __restrict__ a, const float* __restrict__ b,
                              float* __restrict__ c, int n4){
    int i = blockIdx.x * 256 + threadIdx.x;
    if (i < n4){
        float4 x = reinterpret_cast<const float4*>(a)[i];
        float4 y = reinterpret_cast<const float4*>(b)[i];
        x.x += y.x; x.y += y.y; x.z += y.z; x.w += y.w;
        reinterpret_cast<float4*>(c)[i] = x;
    }
}

// ---------------- pooling ----------------

__global__ void score_kernel(const float* __restrict__ he, const float* __restrict__ w,
                             float* __restrict__ score){
    int row = blockIdx.x * 4 + (threadIdx.x >> 6);
    int lane = threadIdx.x & 63;
    if (row >= NE) return;
    const float* r = he + (size_t)row * HD;
    float s = 0.f;
    #pragma unroll
    for (int j = 0; j < 8; ++j) s += r[lane + j*64] * w[lane + j*64];
    #pragma unroll
    for (int off = 32; off > 0; off >>= 1) s += __shfl_down(s, off);
    if (lane == 0) score[row] = s;
}

__global__ __launch_bounds__(256)
void pool_kernel(const float* __restrict__ he, const float* __restrict__ hw,
                 const float* __restrict__ score, const int* __restrict__ off,
                 const int* __restrict__ elist, float* __restrict__ outp){
    int dst = blockIdx.x;
    int t = threadIdx.x;
    int s0 = off[dst], s1 = off[dst + 1];
    __shared__ float red[256];
    float m = -INFINITY;
    for (int e = s0 + t; e < s1; e += 256) m = fmaxf(m, score[elist[e]]);
    red[t] = m; __syncthreads();
    for (int s = 128; s > 0; s >>= 1){
        if (t < s) red[t] = fmaxf(red[t], red[t + s]);
        __syncthreads();
    }
    float mv = red[0];
    __syncthreads();
    float z = 0.f;
    for (int e = s0 + t; e < s1; e += 256) z += expf(score[elist[e]] - mv);
    red[t] = z; __syncthreads();
    for (int s = 128; s > 0; s >>= 1){
        if (t < s) red[t] += red[t + s];
        __syncthreads();
    }
    float zv = red[0];
    float zinv = 1.0f / fmaxf(zv, 1e-12f);
    float p0 = 0.f, p1 = 0.f;
    for (int e = s0; e < s1; ++e){
        int src = elist[e];
        float att = expf(score[src] - mv) * zinv;
        p0 += att * he[(size_t)src * HD + t];
        p1 += att * he[(size_t)src * HD + t + 256];
    }
    size_t o = (size_t)dst * HD;
    outp[o + t]       = hw[o + t]       + LAM * p0;
    outp[o + t + 256] = hw[o + t + 256] + LAM * p1;
}

// ---------------- host ----------------

extern "C" void kernel_launch(void* const* d_in, const int* in_sizes, int n_in,
                              void* d_out, int out_size, void* d_ws, size_t ws_size,
                              hipStream_t stream){
    const float* x_window = (const float*)d_in[0];
    const float* x_example= (const float*)d_in[1];
    const int*   e_near   = (const int*)d_in[2];
    const int*   e_close  = (const int*)d_in[3];
    const int*   e_refer  = (const int*)d_in[4];
    const float* W_win    = (const float*)d_in[5];
    const float* W_exp    = (const float*)d_in[6];
    const float* W_post   = (const float*)d_in[7];
    // d_in[8] = W_ey (unused; _example_y dropped by HeteroConv)
    const float* Wl_near  = (const float*)d_in[9];
    const float* Wr_near  = (const float*)d_in[10];
    const float* b_near   = (const float*)d_in[11];
    const float* Wl_close = (const float*)d_in[12];
    const float* Wr_close = (const float*)d_in[13];
    const float* b_close  = (const float*)d_in[14];
    const float* Wl_refer = (const float*)d_in[15];
    const float* Wr_refer = (const float*)d_in[16];
    const float* b_refer  = (const float*)d_in[17];
    const float* w_pool   = (const float*)d_in[18];
    const float* W_lin    = (const float*)d_in[19];
    const float* b_lin    = (const float*)d_in[20];
    float* out = (float*)d_out;

    // workspace layout
    char* w = (char*)d_ws;
    size_t o = 0;
    auto alloc = [&](size_t bytes)->char*{
        char* p = w + o;
        o += (bytes + 255) & ~(size_t)255;
        return p;
    };
    const size_t HB = (size_t)30000 * HD * sizeof(float);
    float* h_win = (float*)alloc(HB);
    float* h_exp = (float*)alloc(HB);
    float* Abuf  = (float*)alloc(HB);
    float* Zw    = (float*)alloc(HB);
    float* Ze    = (float*)alloc(HB);
    float* Wcomb = (float*)alloc((size_t)HD * HD * sizeof(float));
    float* score = (float*)alloc((size_t)NE * sizeof(float));
    int* degcur  = (int*)alloc((size_t)6 * 30000 * sizeof(int)); // deg_n, deg_r, deg_c, cur_n, cur_r, cur_c
    int* deg_n = degcur;
    int* deg_r = degcur + 30000;
    int* deg_c = degcur + 60000;
    int* cur_n = degcur + 90000;
    int* cur_r = degcur + 120000;
    int* cur_c = degcur + 150000;
    int* off_n = (int*)alloc((size_t)(NW + 1) * sizeof(int));
    int* off_r = (int*)alloc((size_t)(NW + 1) * sizeof(int));
    int* off_c = (int*)alloc((size_t)(NE + 1) * sizeof(int));
    int* el_n  = (int*)alloc((size_t)EE * sizeof(int));
    int* el_r  = (int*)alloc((size_t)EE * sizeof(int));
    int* el_c  = (int*)alloc((size_t)EE * sizeof(int));
    (void)ws_size; (void)in_sizes; (void)n_in; (void)out_size;

    const int* src_n = e_near;        const int* dst_n = e_near + EE;
    const int* src_c = e_close;       const int* dst_c = e_close + EE;
    const int* src_r = e_refer;       const int* dst_r = e_refer + EE;

    // ---- CSR build ----
    hipMemsetAsync(degcur, 0, (size_t)6 * 30000 * sizeof(int), stream);
    int eg = (EE + 255) / 256;
    hipLaunchKernelGGL(count_kernel, dim3(eg), dim3(256), 0, stream, dst_n, deg_n, EE);
    hipLaunchKernelGGL(count_kernel, dim3(eg), dim3(256), 0, stream, dst_r, deg_r, EE);
    hipLaunchKernelGGL(count_kernel, dim3(eg), dim3(256), 0, stream, dst_c, deg_c, EE);
    hipLaunchKernelGGL(scan3_kernel, dim3(3), dim3(1024), 0, stream,
                       deg_n, NW, off_n, deg_r, NW, off_r, deg_c, NE, off_c);
    hipLaunchKernelGGL(fill_kernel, dim3(eg), dim3(256), 0, stream, src_n, dst_n, cur_n, off_n, el_n, EE);
    hipLaunchKernelGGL(fill_kernel, dim3(eg), dim3(256), 0, stream, src_r, dst_r, cur_r, off_r, el_r, EE);
    hipLaunchKernelGGL(fill_kernel, dim3(eg), dim3(256), 0, stream, src_c, dst_c, cur_c, off_c, el_c, EE);

    #define GEMM(ACCUM,BIAS,ACT,AVEC, Ap,Bp,biasp,Cp,Mv,Nv,Kv) \
        hipLaunchKernelGGL((gemm_kernel<ACCUM,BIAS,ACT,AVEC>), \
            dim3(((Nv)+63)/64, ((Mv)+127)/128), dim3(256), 0, stream, Ap, Bp, biasp, Cp, Mv, Nv, Kv)

    // ---- feature transforms: h = lrelu(lrelu(x@W) @ W_post) ----
    GEMM(0,0,1,1, x_example, W_exp, (const float*)nullptr, Abuf, NE, HD, 100);
    GEMM(0,0,1,1, Abuf, W_post, (const float*)nullptr, h_exp, NE, HD, HD);
    GEMM(0,0,1,0, x_window, W_win, (const float*)nullptr, Abuf, NW, HD, 1949);
    GEMM(0,0,1,1, Abuf, W_post, (const float*)nullptr, h_win, NW, HD, HD);

    int n4h = 30000 * HD / 4;
    // ---- layers ----
    for (int l = 0; l < NL; ++l){
        const float* Wl_n = Wl_near  + (size_t)l * HD * HD;
        const float* Wr_n = Wr_near  + (size_t)l * HD * HD;
        const float* b_n  = b_near   + (size_t)l * HD;
        const float* Wl_c = Wl_close + (size_t)l * HD * HD;
        const float* Wr_c = Wr_close + (size_t)l * HD * HD;
        const float* b_c  = b_close  + (size_t)l * HD;
        const float* Wl_r = Wl_refer + (size_t)l * HD * HD;
        const float* Wr_r = Wr_refer + (size_t)l * HD * HD;
        const float* b_r  = b_refer  + (size_t)l * HD;

        // window target: Zw = aggN@Wl_n + b_n + aggR@Wl_r + b_r + h_win@(Wr_n+Wr_r)
        hipLaunchKernelGGL(seg_mean_kernel, dim3(NW), dim3(256), 0, stream, h_win, off_n, el_n, Abuf);
        GEMM(0,1,0,1, Abuf, Wl_n, b_n, Zw, NW, HD, HD);
        hipLaunchKernelGGL(seg_mean_kernel, dim3(NW), dim3(256), 0, stream, h_exp, off_r, el_r, Abuf);
        GEMM(1,1,0,1, Abuf, Wl_r, b_r, Zw, NW, HD, HD);
        hipLaunchKernelGGL(addmat_kernel, dim3((HD*HD/4+255)/256), dim3(256), 0, stream, Wr_n, Wr_r, Wcomb, HD*HD/4);
        GEMM(1,0,0,1, h_win, Wcomb, (const float*)nullptr, Zw, NW, HD, HD);

        // example target: Ze = aggC@Wl_c + b_c + h_exp@Wr_c
        hipLaunchKernelGGL(seg_mean_kernel, dim3(NE), dim3(256), 0, stream, h_exp, off_c, el_c, Abuf);
        GEMM(0,1,0,1, Abuf, Wl_c, b_c, Ze, NE, HD, HD);
        GEMM(1,0,0,1, h_exp, Wr_c, (const float*)nullptr, Ze, NE, HD, HD);

        hipLaunchKernelGGL(lrelu_scale_kernel, dim3((n4h+255)/256), dim3(256), 0, stream, Zw, h_win, 0.5f, n4h);
        hipLaunchKernelGGL(lrelu_scale_kernel, dim3((n4h+255)/256), dim3(256), 0, stream, Ze, h_exp, 1.0f, n4h);
    }

    // ---- CSRA pooling over refer edges ----
    hipLaunchKernelGGL(score_kernel, dim3((NE+3)/4), dim3(256), 0, stream, h_exp, w_pool, score);
    hipLaunchKernelGGL(pool_kernel, dim3(NW), dim3(256), 0, stream, h_exp, h_win, score, off_r, el_r, Abuf);

    // ---- final linear: out = (h_win + LAM*pooled) @ W_lin + b_lin ----
    GEMM(0,1,0,1, Abuf, W_lin, b_lin, out, NW, 100, HD);

    #undef GEMM
}

// Round 2
// 6928.479 us; speedup vs baseline: 1.1932x; 1.1932x over previous
//
#include <hip/hip_runtime.h>
#include <hip/hip_bf16.h>
#include <cstdint>
#include <cstddef>

#define NW 30000
#define NE 30000
#define EE 480000
#define HD 512
#define NL 4
#define SLOPE 0.2f
#define LAM 0.5f

typedef short short8 __attribute__((ext_vector_type(8)));
typedef float f32x4 __attribute__((ext_vector_type(4)));

static __device__ __forceinline__ float lrelu_f(float x){
    return fmaxf(x, 0.f) + SLOPE * fminf(x, 0.f);
}
static __device__ __forceinline__ short f2bf(float f){
    uint32_t u = __builtin_bit_cast(uint32_t, f);
    u += 0x7FFFu + ((u >> 16) & 1u);
    return (short)(u >> 16);
}
static __device__ __forceinline__ float bf2f(short s){
    uint32_t u = ((uint32_t)(uint16_t)s) << 16;
    return __builtin_bit_cast(float, u);
}

// ---------------- CSR build ----------------

__global__ void count_kernel(const int* __restrict__ dst, int* __restrict__ deg, int E){
    int e = blockIdx.x * 256 + threadIdx.x;
    if (e < E) atomicAdd(&deg[dst[e]], 1);
}

__global__ void scan3_kernel(const int* d0, int n0, int* o0,
                             const int* d1, int n1, int* o1,
                             const int* d2, int n2, int* o2){
    const int* deg; int n; int* off;
    if (blockIdx.x == 0){ deg=d0; n=n0; off=o0; }
    else if (blockIdx.x == 1){ deg=d1; n=n1; off=o1; }
    else { deg=d2; n=n2; off=o2; }
    __shared__ int tmp[1024];
    int t = threadIdx.x;
    int carry = 0;
    if (t == 0) off[0] = 0;
    for (int base = 0; base < n; base += 1024){
        int v = (base + t < n) ? deg[base + t] : 0;
        tmp[t] = v; __syncthreads();
        for (int d = 1; d < 1024; d <<= 1){
            int add = (t >= d) ? tmp[t - d] : 0;
            __syncthreads();
            tmp[t] += add;
            __syncthreads();
        }
        if (base + t < n) off[base + t + 1] = tmp[t] + carry;
        carry += tmp[1023];
        __syncthreads();
    }
}

__global__ void fill_kernel(const int* __restrict__ src, const int* __restrict__ dst,
                            int* __restrict__ cur, const int* __restrict__ off,
                            int* __restrict__ elist, int E){
    int e = blockIdx.x * 256 + threadIdx.x;
    if (e < E){
        int d = dst[e];
        int p = atomicAdd(&cur[d], 1);
        elist[off[d] + p] = src[e];
    }
}

// ---------------- segment mean over bf16 h ----------------

__global__ __launch_bounds__(256)
void seg_mean16_kernel(const short* __restrict__ h, const int* __restrict__ off,
                       const int* __restrict__ elist, short* __restrict__ out){
    int dst = blockIdx.x;
    int t = threadIdx.x;
    int s0 = off[dst], s1 = off[dst + 1];
    float a0 = 0.f, a1 = 0.f;
    for (int e = s0; e < s1; ++e){
        int src = elist[e];
        uint32_t v = *(const uint32_t*)(h + (size_t)src * HD + 2 * t);
        a0 += bf2f((short)(v & 0xFFFFu));
        a1 += bf2f((short)(v >> 16));
    }
    float inv = (s1 > s0) ? 1.0f / (float)(s1 - s0) : 0.0f;
    uint32_t pk = (uint32_t)(uint16_t)f2bf(a0 * inv) | ((uint32_t)(uint16_t)f2bf(a1 * inv) << 16);
    *(uint32_t*)(out + (size_t)dst * HD + 2 * t) = pk;
}

// ---------------- MFMA GEMM: C = sum_p A_p @ B_p (+bias)(act) ----------------
// A: [M,K] fp32 (AF32) or bf16; B: [K,N] bf16; N multiple of 128.
// ACT: 0 none, 1 lrelu, 2 lrelu(0.5*(x+bias))

template<int NP, int AF32, int ACT, int WF32>
__global__ __launch_bounds__(256)
void mgemm_kernel(const void* __restrict__ A0, const void* __restrict__ A1, const void* __restrict__ A2,
                  const short* __restrict__ B0, const short* __restrict__ B1, const short* __restrict__ B2,
                  const float* __restrict__ bias, short* __restrict__ C16, float* __restrict__ C32,
                  int M, int N, int K){
    __shared__ short As[4][128][8];
    __shared__ short Bs[4][128][8];
    int m0 = blockIdx.y * 128, n0 = blockIdx.x * 128;
    int t = threadIdx.x;
    int wid = t >> 6, lane = t & 63;
    int wm = (wid >> 1) * 64, wn = (wid & 1) * 64;
    int lg = lane >> 4, lr = lane & 15;
    f32x4 acc[4][4] = {};

    #pragma unroll
    for (int p = 0; p < NP; ++p){
        const void* Ap = (p == 0) ? A0 : ((p == 1) ? A1 : A2);
        const short* Bp = (p == 0) ? B0 : ((p == 1) ? B1 : B2);
        for (int k0 = 0; k0 < K; k0 += 32){
            // stage A tile [128 rows][32 k] -> As[kchunk][row][8]
            #pragma unroll
            for (int s = 0; s < 2; ++s){
                int sl = s * 256 + t;
                int row = sl >> 2, c = sl & 3;
                int gr = m0 + row, gk = k0 + c * 8;
                short8 v = {};
                if (gr < M){
                    if (AF32){
                        const float* ap = (const float*)Ap + (size_t)gr * K + gk;
                        #pragma unroll
                        for (int j = 0; j < 8; ++j){
                            float f = (gk + j < K) ? ap[j] : 0.f;
                            v[j] = f2bf(f);
                        }
                    } else {
                        const short* ap = (const short*)Ap + (size_t)gr * K + gk;
                        if (gk + 8 <= K){
                            v = *(const short8*)ap;
                        } else {
                            #pragma unroll
                            for (int j = 0; j < 8; ++j) if (gk + j < K) v[j] = ap[j];
                        }
                    }
                }
                *(short8*)&As[c][row][0] = v;
            }
            // stage B tile [32 k][128 cols] transposed -> Bs[kchunk][col][8]
            #pragma unroll
            for (int s = 0; s < 2; ++s){
                int sl = s * 256 + t;
                int col = sl & 127, kc = sl >> 7;
                short8 v = {};
                #pragma unroll
                for (int j = 0; j < 8; ++j){
                    int gk = k0 + kc * 8 + j;
                    if (gk < K) v[j] = Bp[(size_t)gk * N + n0 + col];
                }
                *(short8*)&Bs[kc][col][0] = v;
            }
            __syncthreads();
            short8 af[4], bf[4];
            #pragma unroll
            for (int f = 0; f < 4; ++f) af[f] = *(const short8*)&As[lg][wm + f * 16 + lr][0];
            #pragma unroll
            for (int f = 0; f < 4; ++f) bf[f] = *(const short8*)&Bs[lg][wn + f * 16 + lr][0];
            #pragma unroll
            for (int i = 0; i < 4; ++i)
                #pragma unroll
                for (int j = 0; j < 4; ++j)
                    acc[i][j] = __builtin_amdgcn_mfma_f32_16x16x32_bf16(af[i], bf[j], acc[i][j], 0, 0, 0);
            __syncthreads();
        }
    }
    float bv[4];
    #pragma unroll
    for (int f = 0; f < 4; ++f) bv[f] = bias ? bias[n0 + wn + f * 16 + lr] : 0.f;
    #pragma unroll
    for (int i = 0; i < 4; ++i){
        #pragma unroll
        for (int r = 0; r < 4; ++r){
            int gr = m0 + wm + i * 16 + lg * 4 + r;
            if (gr >= M) continue;
            #pragma unroll
            for (int j = 0; j < 4; ++j){
                int gc = n0 + wn + j * 16 + lr;
                float v = acc[i][j][r] + bv[j];
                if (ACT == 2) v *= 0.5f;
                if (ACT) v = lrelu_f(v);
                C16[(size_t)gr * N + gc] = f2bf(v);
                if (WF32) C32[(size_t)gr * N + gc] = v;
            }
        }
    }
}

// ---------------- fp32 tiled GEMM (final 512->100 only) ----------------

template<int ACCUM, int BIAS, int ACT>
__global__ __launch_bounds__(256)
void gemm_kernel(const float* __restrict__ A, const float* __restrict__ B,
                 const float* __restrict__ bias, float* __restrict__ C,
                 int M, int N, int K){
    const int BM = 128, BN = 64, BK = 16;
    __shared__ float As[BK][BM];
    __shared__ float Bs[BK][BN];
    int m0 = blockIdx.y * BM, n0 = blockIdx.x * BN;
    int t = threadIdx.x;
    int tx = t & 15, ty = t >> 4;
    float acc[8][4] = {};
    for (int k0 = 0; k0 < K; k0 += BK){
        #pragma unroll
        for (int i = 0; i < 2; ++i){
            int idx = i * 256 + t;
            int row = idx >> 2, kg = idx & 3;
            float4 v = make_float4(0,0,0,0);
            int gr = m0 + row, gk = k0 + kg * 4;
            if (gr < M && gk + 4 <= K)
                v = *reinterpret_cast<const float4*>(A + (size_t)gr * K + gk);
            As[kg*4+0][row] = v.x; As[kg*4+1][row] = v.y;
            As[kg*4+2][row] = v.z; As[kg*4+3][row] = v.w;
        }
        {
            int row = t >> 4, cg = t & 15;
            int gk = k0 + row, col = n0 + cg * 4;
            float4 v = make_float4(0,0,0,0);
            if (gk < K){
                if (col + 4 <= N){
                    v = *reinterpret_cast<const float4*>(B + (size_t)gk * N + col);
                } else {
                    float tp[4] = {0,0,0,0};
                    #pragma unroll
                    for (int j = 0; j < 4; ++j) if (col + j < N) tp[j] = B[(size_t)gk * N + col + j];
                    v = make_float4(tp[0], tp[1], tp[2], tp[3]);
                }
            }
            *reinterpret_cast<float4*>(&Bs[row][cg*4]) = v;
        }
        __syncthreads();
        #pragma unroll
        for (int k = 0; k < BK; ++k){
            float a[8], b[4];
            #pragma unroll
            for (int r = 0; r < 8; ++r) a[r] = As[k][ty*8 + r];
            #pragma unroll
            for (int c = 0; c < 4; ++c) b[c] = Bs[k][tx*4 + c];
            #pragma unroll
            for (int r = 0; r < 8; ++r)
                #pragma unroll
                for (int c = 0; c < 4; ++c)
                    acc[r][c] = fmaf(a[r], b[c], acc[r][c]);
        }
        __syncthreads();
    }
    #pragma unroll
    for (int r = 0; r < 8; ++r){
        int gr = m0 + ty*8 + r;
        if (gr >= M) continue;
        #pragma unroll
        for (int c = 0; c < 4; ++c){
            int gc = n0 + tx*4 + c;
            if (gc >= N) continue;
            float v = acc[r][c];
            if (BIAS) v += bias[gc];
            if (ACCUM) v += C[(size_t)gr * N + gc];
            if (ACT) v = lrelu_f(v);
            C[(size_t)gr * N + gc] = v;
        }
    }
}

// ---------------- conversion helpers ----------------

__global__ void f2bf_kernel(const float* __restrict__ a, short* __restrict__ o, int n){
    int i = blockIdx.x * 256 + threadIdx.x;
    if (i < n) o[i] = f2bf(a[i]);
}
__global__ void add_f2bf_kernel(const float* __restrict__ a, const float* __restrict__ b,
                                short* __restrict__ o, int n){
    int i = blockIdx.x * 256 + threadIdx.x;
    if (i < n) o[i] = f2bf(a[i] + b[i]);
}
__global__ void addf_kernel(const float* __restrict__ a, const float* __restrict__ b,
                            float* __restrict__ o, int n){
    int i = blockIdx.x * 256 + threadIdx.x;
    if (i < n) o[i] = a[i] + b[i];
}

// ---------------- pooling ----------------

template<int F32>
__global__ void score_kernel(const void* __restrict__ hep, const float* __restrict__ w,
                             float* __restrict__ score){
    int row = blockIdx.x * 4 + (threadIdx.x >> 6);
    int lane = threadIdx.x & 63;
    if (row >= NE) return;
    float s = 0.f;
    #pragma unroll
    for (int j = 0; j < 8; ++j){
        int idx = lane + j * 64;
        float x = F32 ? ((const float*)hep)[(size_t)row * HD + idx]
                      : bf2f(((const short*)hep)[(size_t)row * HD + idx]);
        s += x * w[idx];
    }
    #pragma unroll
    for (int off = 32; off > 0; off >>= 1) s += __shfl_down(s, off);
    if (lane == 0) score[row] = s;
}

template<int F32>
__global__ __launch_bounds__(256)
void pool_kernel(const void* __restrict__ hep, const void* __restrict__ hwp,
                 const float* __restrict__ score, const int* __restrict__ off,
                 const int* __restrict__ elist, float* __restrict__ outp){
    int dst = blockIdx.x;
    int t = threadIdx.x;
    int s0 = off[dst], s1 = off[dst + 1];
    __shared__ float red[256];
    float m = -INFINITY;
    for (int e = s0 + t; e < s1; e += 256) m = fmaxf(m, score[elist[e]]);
    red[t] = m; __syncthreads();
    for (int s = 128; s > 0; s >>= 1){
        if (t < s) red[t] = fmaxf(red[t], red[t + s]);
        __syncthreads();
    }
    float mv = red[0];
    __syncthreads();
    float z = 0.f;
    for (int e = s0 + t; e < s1; e += 256) z += expf(score[elist[e]] - mv);
    red[t] = z; __syncthreads();
    for (int s = 128; s > 0; s >>= 1){
        if (t < s) red[t] += red[t + s];
        __syncthreads();
    }
    float zinv = 1.0f / fmaxf(red[0], 1e-12f);
    float p0 = 0.f, p1 = 0.f;
    for (int e = s0; e < s1; ++e){
        int src = elist[e];
        float att = expf(score[src] - mv) * zinv;
        float v0, v1;
        if (F32){
            v0 = ((const float*)hep)[(size_t)src * HD + t];
            v1 = ((const float*)hep)[(size_t)src * HD + t + 256];
        } else {
            v0 = bf2f(((const short*)hep)[(size_t)src * HD + t]);
            v1 = bf2f(((const short*)hep)[(size_t)src * HD + t + 256]);
        }
        p0 += att * v0;
        p1 += att * v1;
    }
    float h0, h1;
    if (F32){
        h0 = ((const float*)hwp)[(size_t)dst * HD + t];
        h1 = ((const float*)hwp)[(size_t)dst * HD + t + 256];
    } else {
        h0 = bf2f(((const short*)hwp)[(size_t)dst * HD + t]);
        h1 = bf2f(((const short*)hwp)[(size_t)dst * HD + t + 256]);
    }
    size_t o = (size_t)dst * HD;
    outp[o + t]       = h0 + LAM * p0;
    outp[o + t + 256] = h1 + LAM * p1;
}

// ---------------- host ----------------

extern "C" void kernel_launch(void* const* d_in, const int* in_sizes, int n_in,
                              void* d_out, int out_size, void* d_ws, size_t ws_size,
                              hipStream_t stream){
    const float* x_window = (const float*)d_in[0];
    const float* x_example= (const float*)d_in[1];
    const int*   e_near   = (const int*)d_in[2];
    const int*   e_close  = (const int*)d_in[3];
    const int*   e_refer  = (const int*)d_in[4];
    const float* W_win    = (const float*)d_in[5];
    const float* W_exp    = (const float*)d_in[6];
    const float* W_post   = (const float*)d_in[7];
    const float* Wl_near  = (const float*)d_in[9];
    const float* Wr_near  = (const float*)d_in[10];
    const float* b_near   = (const float*)d_in[11];
    const float* Wl_close = (const float*)d_in[12];
    const float* Wr_close = (const float*)d_in[13];
    const float* b_close  = (const float*)d_in[14];
    const float* Wl_refer = (const float*)d_in[15];
    const float* Wr_refer = (const float*)d_in[16];
    const float* b_refer  = (const float*)d_in[17];
    const float* w_pool   = (const float*)d_in[18];
    const float* W_lin    = (const float*)d_in[19];
    const float* b_lin    = (const float*)d_in[20];
    float* out = (float*)d_out;
    (void)in_sizes; (void)n_in; (void)out_size;

    char* w = (char*)d_ws;
    size_t o = 0;
    auto alloc = [&](size_t bytes)->char*{
        char* p = w + o;
        o += (bytes + 255) & ~(size_t)255;
        return p;
    };
    const size_t HBF = (size_t)30000 * HD * sizeof(float);  // 61.44 MB
    const size_t HBH = (size_t)30000 * HD * sizeof(short);  // 30.72 MB
    const size_t WHH = (size_t)HD * HD;                     // 262144

    short* h16[2][2]; // [win/exp][buf]
    h16[0][0] = (short*)alloc(HBH); h16[0][1] = (short*)alloc(HBH);
    h16[1][0] = (short*)alloc(HBH); h16[1][1] = (short*)alloc(HBH);
    short* aggA = (short*)alloc(HBH);
    short* aggB = (short*)alloc(HBH);
    float* Abuf = (float*)alloc(HBF);
    short* Wwin16  = (short*)alloc((size_t)1949 * HD * 2);
    short* Wexp16  = (short*)alloc((size_t)100 * HD * 2);
    short* Wpost16 = (short*)alloc(WHH * 2);
    short* Wln16   = (short*)alloc((size_t)NL * WHH * 2);
    short* Wlr16   = (short*)alloc((size_t)NL * WHH * 2);
    short* Wlc16   = (short*)alloc((size_t)NL * WHH * 2);
    short* Wrc16   = (short*)alloc((size_t)NL * WHH * 2);
    short* Wcomb16 = (short*)alloc((size_t)NL * WHH * 2);
    float* bsum    = (float*)alloc((size_t)NL * HD * 4);
    float* score   = (float*)alloc((size_t)NE * 4);
    int* degcur = (int*)alloc((size_t)6 * 30000 * 4);
    int* deg_n = degcur, *deg_r = degcur + 30000, *deg_c = degcur + 60000;
    int* cur_n = degcur + 90000, *cur_r = degcur + 120000, *cur_c = degcur + 150000;
    int* off_n = (int*)alloc((size_t)(NW + 1) * 4);
    int* off_r = (int*)alloc((size_t)(NW + 1) * 4);
    int* off_c = (int*)alloc((size_t)(NE + 1) * 4);
    int* el_n  = (int*)alloc((size_t)EE * 4);
    int* el_r  = (int*)alloc((size_t)EE * 4);
    int* el_c  = (int*)alloc((size_t)EE * 4);
    size_t needBase = o;
    bool haveF32 = (ws_size >= needBase + 2 * HBF + 512);
    float* h_winf = nullptr; float* h_expf = nullptr;
    if (haveF32){
        h_winf = (float*)alloc(HBF);
        h_expf = (float*)alloc(HBF);
    }

    const int* src_n = e_near;  const int* dst_n = e_near + EE;
    const int* src_c = e_close; const int* dst_c = e_close + EE;
    const int* src_r = e_refer; const int* dst_r = e_refer + EE;

    // ---- CSR build ----
    hipMemsetAsync(degcur, 0, (size_t)6 * 30000 * 4, stream);
    int eg = (EE + 255) / 256;
    hipLaunchKernelGGL(count_kernel, dim3(eg), dim3(256), 0, stream, dst_n, deg_n, EE);
    hipLaunchKernelGGL(count_kernel, dim3(eg), dim3(256), 0, stream, dst_r, deg_r, EE);
    hipLaunchKernelGGL(count_kernel, dim3(eg), dim3(256), 0, stream, dst_c, deg_c, EE);
    hipLaunchKernelGGL(scan3_kernel, dim3(3), dim3(1024), 0, stream,
                       deg_n, NW, off_n, deg_r, NW, off_r, deg_c, NE, off_c);
    hipLaunchKernelGGL(fill_kernel, dim3(eg), dim3(256), 0, stream, src_n, dst_n, cur_n, off_n, el_n, EE);
    hipLaunchKernelGGL(fill_kernel, dim3(eg), dim3(256), 0, stream, src_r, dst_r, cur_r, off_r, el_r, EE);
    hipLaunchKernelGGL(fill_kernel, dim3(eg), dim3(256), 0, stream, src_c, dst_c, cur_c, off_c, el_c, EE);

    // ---- weight conversion ----
    auto cvt = [&](const float* src, short* dst, int n){
        hipLaunchKernelGGL(f2bf_kernel, dim3((n + 255) / 256), dim3(256), 0, stream, src, dst, n);
    };
    cvt(W_win, Wwin16, 1949 * HD);
    cvt(W_exp, Wexp16, 100 * HD);
    cvt(W_post, Wpost16, HD * HD);
    cvt(Wl_near, Wln16, NL * HD * HD);
    cvt(Wl_refer, Wlr16, NL * HD * HD);
    cvt(Wl_close, Wlc16, NL * HD * HD);
    cvt(Wr_close, Wrc16, NL * HD * HD);
    hipLaunchKernelGGL(add_f2bf_kernel, dim3((NL * HD * HD + 255) / 256), dim3(256), 0, stream,
                       Wr_near, Wr_refer, Wcomb16, NL * HD * HD);
    hipLaunchKernelGGL(addf_kernel, dim3((NL * HD + 255) / 256), dim3(256), 0, stream,
                       b_near, b_refer, bsum, NL * HD);

    dim3 ggrid(4, (30000 + 127) / 128);
    #define MGEMM(NP,AF32,ACT,WF32, a0,a1,a2, b0,b1,b2, bp, c16, c32, Mv,Kv) \
        hipLaunchKernelGGL((mgemm_kernel<NP,AF32,ACT,WF32>), ggrid, dim3(256), 0, stream, \
            (const void*)(a0), (const void*)(a1), (const void*)(a2), b0, b1, b2, bp, c16, c32, Mv, HD, Kv)

    // ---- feature transforms ----
    MGEMM(1,1,1,0, x_example, nullptr, nullptr, Wexp16, nullptr, nullptr,
          (const float*)nullptr, aggA, (float*)nullptr, NE, 100);
    MGEMM(1,0,1,0, aggA, nullptr, nullptr, Wpost16, nullptr, nullptr,
          (const float*)nullptr, h16[1][0], (float*)nullptr, NE, HD);
    MGEMM(1,1,1,0, x_window, nullptr, nullptr, Wwin16, nullptr, nullptr,
          (const float*)nullptr, aggA, (float*)nullptr, NW, 1949);
    MGEMM(1,0,1,0, aggA, nullptr, nullptr, Wpost16, nullptr, nullptr,
          (const float*)nullptr, h16[0][0], (float*)nullptr, NW, HD);

    // ---- layers ----
    for (int l = 0; l < NL; ++l){
        int cur = l & 1, nxt = cur ^ 1;
        const short* wl_n = Wln16 + (size_t)l * WHH;
        const short* wl_r = Wlr16 + (size_t)l * WHH;
        const short* wl_c = Wlc16 + (size_t)l * WHH;
        const short* wr_c = Wrc16 + (size_t)l * WHH;
        const short* wcb  = Wcomb16 + (size_t)l * WHH;
        const float* bs   = bsum + (size_t)l * HD;
        const float* bc   = b_close + (size_t)l * HD;

        hipLaunchKernelGGL(seg_mean16_kernel, dim3(NW), dim3(256), 0, stream,
                           h16[0][cur], off_n, el_n, aggA);
        hipLaunchKernelGGL(seg_mean16_kernel, dim3(NW), dim3(256), 0, stream,
                           h16[1][cur], off_r, el_r, aggB);
        if (l == NL - 1 && haveF32){
            MGEMM(3,0,2,1, aggA, aggB, h16[0][cur], wl_n, wl_r, wcb, bs, h16[0][nxt], h_winf, NW, HD);
        } else {
            MGEMM(3,0,2,0, aggA, aggB, h16[0][cur], wl_n, wl_r, wcb, bs, h16[0][nxt], (float*)nullptr, NW, HD);
        }
        hipLaunchKernelGGL(seg_mean16_kernel, dim3(NE), dim3(256), 0, stream,
                           h16[1][cur], off_c, el_c, aggA);
        if (l == NL - 1 && haveF32){
            MGEMM(2,0,1,1, aggA, h16[1][cur], nullptr, wl_c, wr_c, nullptr, bc, h16[1][nxt], h_expf, NE, HD);
        } else {
            MGEMM(2,0,1,0, aggA, h16[1][cur], nullptr, wl_c, wr_c, nullptr, bc, h16[1][nxt], (float*)nullptr, NE, HD);
        }
    }
    int fin = NL & 1; // buffer index holding final h
    // ---- CSRA pooling ----
    if (haveF32){
        hipLaunchKernelGGL((score_kernel<1>), dim3((NE + 3) / 4), dim3(256), 0, stream,
                           (const void*)h_expf, w_pool, score);
        hipLaunchKernelGGL((pool_kernel<1>), dim3(NW), dim3(256), 0, stream,
                           (const void*)h_expf, (const void*)h_winf, score, off_r, el_r, Abuf);
    } else {
        hipLaunchKernelGGL((score_kernel<0>), dim3((NE + 3) / 4), dim3(256), 0, stream,
                           (const void*)h16[1][fin], w_pool, score);
        hipLaunchKernelGGL((pool_kernel<0>), dim3(NW), dim3(256), 0, stream,
                           (const void*)h16[1][fin], (const void*)h16[0][fin], score, off_r, el_r, Abuf);
    }

    // ---- final linear (fp32) ----
    hipLaunchKernelGGL((gemm_kernel<0,1,0>), dim3((100 + 63) / 64, (NW + 127) / 128), dim3(256), 0, stream,
                       Abuf, W_lin, b_lin, out, NW, 100, HD);
    #undef MGEMM
}

// Round 3
// 3005.196 us; speedup vs baseline: 2.7510x; 2.3055x over previous
//
#include <hip/hip_runtime.h>
#include <hip/hip_bf16.h>
#include <cstdint>
#include <cstddef>

#define NW 30000
#define NE 30000
#define EE 480000
#define HD 512
#define NL 4
#define SLOPE 0.2f
#define LAM 0.5f
#define ROWP 30048  // 30000 padded to multiple of 128 for OOB-safe tile reads

typedef short short8 __attribute__((ext_vector_type(8)));
typedef float f32x4 __attribute__((ext_vector_type(4)));

static __device__ __forceinline__ float lrelu_f(float x){
    return fmaxf(x, 0.f) + SLOPE * fminf(x, 0.f);
}
static __device__ __forceinline__ short f2bf(float f){
    uint32_t u = __builtin_bit_cast(uint32_t, f);
    u += 0x7FFFu + ((u >> 16) & 1u);
    return (short)(u >> 16);
}
static __device__ __forceinline__ float bf2f(short s){
    uint32_t u = ((uint32_t)(uint16_t)s) << 16;
    return __builtin_bit_cast(float, u);
}

typedef const __attribute__((address_space(1))) void* gas_t;
typedef __attribute__((address_space(3))) void* las_t;
static __device__ __forceinline__ void gload16(const void* g, void* l){
    __builtin_amdgcn_global_load_lds((gas_t)g, (las_t)l, 16, 0, 0);
}

// ---------------- CSR build ----------------

__global__ void count_kernel(const int* __restrict__ dst, int* __restrict__ deg, int E){
    int e = blockIdx.x * 256 + threadIdx.x;
    if (e < E) atomicAdd(&deg[dst[e]], 1);
}

__global__ void scan3_kernel(const int* d0, int n0, int* o0,
                             const int* d1, int n1, int* o1,
                             const int* d2, int n2, int* o2){
    const int* deg; int n; int* off;
    if (blockIdx.x == 0){ deg=d0; n=n0; off=o0; }
    else if (blockIdx.x == 1){ deg=d1; n=n1; off=o1; }
    else { deg=d2; n=n2; off=o2; }
    __shared__ int tmp[1024];
    int t = threadIdx.x;
    int carry = 0;
    if (t == 0) off[0] = 0;
    for (int base = 0; base < n; base += 1024){
        int v = (base + t < n) ? deg[base + t] : 0;
        tmp[t] = v; __syncthreads();
        for (int d = 1; d < 1024; d <<= 1){
            int add = (t >= d) ? tmp[t - d] : 0;
            __syncthreads();
            tmp[t] += add;
            __syncthreads();
        }
        if (base + t < n) off[base + t + 1] = tmp[t] + carry;
        carry += tmp[1023];
        __syncthreads();
    }
}

__global__ void fill_kernel(const int* __restrict__ src, const int* __restrict__ dst,
                            int* __restrict__ cur, const int* __restrict__ off,
                            int* __restrict__ elist, int E){
    int e = blockIdx.x * 256 + threadIdx.x;
    if (e < E){
        int d = dst[e];
        int p = atomicAdd(&cur[d], 1);
        elist[off[d] + p] = src[e];
    }
}

// ---------------- weight transpose fp32[K,N] -> bf16[N,Kpad], optional A+B ----------------

template<int ADD>
__global__ __launch_bounds__(256)
void transpose_bf_kernel(const float* __restrict__ in, const float* __restrict__ in2,
                         short* __restrict__ out, int K, int N, int Kpad){
    __shared__ float tile[32][33];
    int mat = blockIdx.z;
    const float* inp  = in  + (size_t)mat * K * N;
    const float* inp2 = ADD ? (in2 + (size_t)mat * K * N) : nullptr;
    short* outp = out + (size_t)mat * N * Kpad;
    int kbase = blockIdx.y * 32, nbase = blockIdx.x * 32;
    int tx = threadIdx.x & 31, ty = threadIdx.x >> 5;  // ty 0..7
    #pragma unroll
    for (int r = 0; r < 4; ++r){
        int k = kbase + ty + r * 8;
        float v = 0.f;
        if (k < K){
            v = inp[(size_t)k * N + nbase + tx];
            if (ADD) v += inp2[(size_t)k * N + nbase + tx];
        }
        tile[ty + r * 8][tx] = v;
    }
    __syncthreads();
    #pragma unroll
    for (int r = 0; r < 4; ++r){
        int n = nbase + ty + r * 8;
        int k = kbase + tx;
        if (k < Kpad) outp[(size_t)n * Kpad + k] = f2bf(tile[tx][ty + r * 8]);
    }
}

__global__ void addf_kernel(const float* __restrict__ a, const float* __restrict__ b,
                            float* __restrict__ o, int n){
    int i = blockIdx.x * 256 + threadIdx.x;
    if (i < n) o[i] = a[i] + b[i];
}

// ---------------- segment mean: one wave per dst ----------------

__global__ __launch_bounds__(256)
void seg_mean16_kernel(const short* __restrict__ h, const int* __restrict__ off,
                       const int* __restrict__ elist, short* __restrict__ out, int ndst){
    int dst = blockIdx.x * 4 + (threadIdx.x >> 6);
    int lane = threadIdx.x & 63;
    if (dst >= ndst) return;
    int s0 = off[dst], s1 = off[dst + 1];
    float acc[8] = {};
    int e = s0;
    for (; e + 4 <= s1; e += 4){
        int i0 = elist[e], i1 = elist[e + 1], i2 = elist[e + 2], i3 = elist[e + 3];
        short8 v0 = *(const short8*)(h + (size_t)i0 * HD + lane * 8);
        short8 v1 = *(const short8*)(h + (size_t)i1 * HD + lane * 8);
        short8 v2 = *(const short8*)(h + (size_t)i2 * HD + lane * 8);
        short8 v3 = *(const short8*)(h + (size_t)i3 * HD + lane * 8);
        #pragma unroll
        for (int j = 0; j < 8; ++j)
            acc[j] += (bf2f(v0[j]) + bf2f(v1[j])) + (bf2f(v2[j]) + bf2f(v3[j]));
    }
    for (; e < s1; ++e){
        short8 v = *(const short8*)(h + (size_t)elist[e] * HD + lane * 8);
        #pragma unroll
        for (int j = 0; j < 8; ++j) acc[j] += bf2f(v[j]);
    }
    float inv = (s1 > s0) ? 1.0f / (float)(s1 - s0) : 0.0f;
    short8 o8;
    #pragma unroll
    for (int j = 0; j < 8; ++j) o8[j] = f2bf(acc[j] * inv);
    *(short8*)(out + (size_t)dst * HD + lane * 8) = o8;
}

// ---------------- MFMA GEMM: C = sum_p A_p @ B_p^T' (+bias)(act) ----------------
// A: [M,KT] bf16 (row-padded ws buffer) or [M,KACT] fp32 (AF32). BT: [N][KT] bf16.
// LDS tiles 128x32 bf16, XOR-swizzled: chunk (row,c) at byte row*64 + (c^((row>>1)&3))*16.

template<int NP, int KT, int KACT, int AF32, int ACT, int WF32>
__global__ __launch_bounds__(256)
void mgemm_kernel(const void* __restrict__ A0, const void* __restrict__ A1, const void* __restrict__ A2,
                  const short* __restrict__ B0, const short* __restrict__ B1, const short* __restrict__ B2,
                  const float* __restrict__ bias, short* __restrict__ C16, float* __restrict__ C32,
                  int M, int N){
    constexpr int KPT = KT / 32;
    constexpr int NSTEPS = NP * KPT;
    __shared__ short lds[2][2][4096];   // [buf][A/B][8KB]
    const int m0 = blockIdx.y * 128, n0 = blockIdx.x * 128;
    const int t = threadIdx.x, wid = t >> 6, lane = t & 63;
    const int wm = (wid >> 1) * 64, wn = (wid & 1) * 64;
    const int lg = lane >> 4, lr = lane & 15;
    f32x4 acc[4][4] = {};

    int rowi[2], ci[2];
    #pragma unroll
    for (int i = 0; i < 2; ++i){
        int sl = i * 256 + t;
        rowi[i] = sl >> 2;
        ci[i] = (sl & 3) ^ ((rowi[i] >> 1) & 3);
    }
    f32x4 ra[2][2];

    auto stage_load = [&](int s){
        int p = s / KPT;
        int k0 = (s - p * KPT) * 32;
        const void* Ap = (p == 0) ? A0 : ((p == 1) ? A1 : A2);
        const short* Bp = (p == 0) ? B0 : ((p == 1) ? B1 : B2);
        int bb = s & 1;
        #pragma unroll
        for (int i = 0; i < 2; ++i){
            int gr = m0 + rowi[i];
            int gk = k0 + ci[i] * 8;
            if (AF32){
                ra[i][0] = (f32x4){0,0,0,0};
                ra[i][1] = (f32x4){0,0,0,0};
                if (gr < M){
                    const float* ap = (const float*)Ap + (size_t)gr * KACT + gk;
                    if (KACT == KT || gk + 8 <= KACT){
                        ra[i][0] = *(const f32x4*)ap;
                        ra[i][1] = *(const f32x4*)(ap + 4);
                    } else {
                        #pragma unroll
                        for (int j = 0; j < 8; ++j)
                            if (gk + j < KACT) ra[i][j >> 2][j & 3] = ap[j];
                    }
                }
            } else {
                const short* ap = (const short*)Ap + (size_t)gr * KT + gk;
                gload16(ap, &lds[bb][0][(i * 256 + wid * 64) * 8]);
            }
            const short* bp = Bp + (size_t)(n0 + rowi[i]) * KT + gk;
            gload16(bp, &lds[bb][1][(i * 256 + wid * 64) * 8]);
        }
    };
    auto stage_writeA = [&](int s){
        int bb = s & 1;
        #pragma unroll
        for (int i = 0; i < 2; ++i){
            short8 v;
            #pragma unroll
            for (int j = 0; j < 8; ++j) v[j] = f2bf(ra[i][j >> 2][j & 3]);
            *(short8*)&lds[bb][0][(i * 256 + t) * 8] = v;
        }
    };
    auto compute = [&](int s){
        int bb = s & 1;
        short8 af[4], bfr[4];
        #pragma unroll
        for (int f = 0; f < 4; ++f){
            int rowA = wm + f * 16 + lr;
            af[f] = *(const short8*)((const char*)&lds[bb][0][0] + rowA * 64 + ((lg ^ ((rowA >> 1) & 3)) << 4));
            int rowB = wn + f * 16 + lr;
            bfr[f] = *(const short8*)((const char*)&lds[bb][1][0] + rowB * 64 + ((lg ^ ((rowB >> 1) & 3)) << 4));
        }
        #pragma unroll
        for (int i = 0; i < 4; ++i)
            #pragma unroll
            for (int j = 0; j < 4; ++j)
                acc[i][j] = __builtin_amdgcn_mfma_f32_16x16x32_bf16(af[i], bfr[j], acc[i][j], 0, 0, 0);
    };

    stage_load(0);
    if (AF32) stage_writeA(0);
    __syncthreads();
    for (int s = 0; s < NSTEPS; ++s){
        if (s + 1 < NSTEPS) stage_load(s + 1);
        compute(s);
        if (AF32 && s + 1 < NSTEPS) stage_writeA(s + 1);
        __syncthreads();
    }

    float bv[4];
    #pragma unroll
    for (int f = 0; f < 4; ++f) bv[f] = bias ? bias[n0 + wn + f * 16 + lr] : 0.f;
    #pragma unroll
    for (int i = 0; i < 4; ++i){
        #pragma unroll
        for (int r = 0; r < 4; ++r){
            int gr = m0 + wm + i * 16 + lg * 4 + r;
            if (gr >= M) continue;
            #pragma unroll
            for (int j = 0; j < 4; ++j){
                int gc = n0 + wn + j * 16 + lr;
                float v = acc[i][j][r] + bv[j];
                if (ACT == 2) v *= 0.5f;
                if (ACT) v = lrelu_f(v);
                C16[(size_t)gr * N + gc] = f2bf(v);
                if (WF32) C32[(size_t)gr * N + gc] = v;
            }
        }
    }
}

// ---------------- fp32 tiled GEMM (final 512->100 only) ----------------

__global__ __launch_bounds__(256)
void gemm_kernel(const float* __restrict__ A, const float* __restrict__ B,
                 const float* __restrict__ bias, float* __restrict__ C,
                 int M, int N, int K){
    const int BM = 128, BN = 64, BK = 16;
    __shared__ float As[BK][BM];
    __shared__ float Bs[BK][BN];
    int m0 = blockIdx.y * BM, n0 = blockIdx.x * BN;
    int t = threadIdx.x;
    int tx = t & 15, ty = t >> 4;
    float acc[8][4] = {};
    for (int k0 = 0; k0 < K; k0 += BK){
        #pragma unroll
        for (int i = 0; i < 2; ++i){
            int idx = i * 256 + t;
            int row = idx >> 2, kg = idx & 3;
            float4 v = make_float4(0,0,0,0);
            int gr = m0 + row, gk = k0 + kg * 4;
            if (gr < M && gk + 4 <= K)
                v = *reinterpret_cast<const float4*>(A + (size_t)gr * K + gk);
            As[kg*4+0][row] = v.x; As[kg*4+1][row] = v.y;
            As[kg*4+2][row] = v.z; As[kg*4+3][row] = v.w;
        }
        {
            int row = t >> 4, cg = t & 15;
            int gk = k0 + row, col = n0 + cg * 4;
            float4 v = make_float4(0,0,0,0);
            if (gk < K){
                if (col + 4 <= N){
                    v = *reinterpret_cast<const float4*>(B + (size_t)gk * N + col);
                } else {
                    float tp[4] = {0,0,0,0};
                    #pragma unroll
                    for (int j = 0; j < 4; ++j) if (col + j < N) tp[j] = B[(size_t)gk * N + col + j];
                    v = make_float4(tp[0], tp[1], tp[2], tp[3]);
                }
            }
            *reinterpret_cast<float4*>(&Bs[row][cg*4]) = v;
        }
        __syncthreads();
        #pragma unroll
        for (int k = 0; k < BK; ++k){
            float a[8], b[4];
            #pragma unroll
            for (int r = 0; r < 8; ++r) a[r] = As[k][ty*8 + r];
            #pragma unroll
            for (int c = 0; c < 4; ++c) b[c] = Bs[k][tx*4 + c];
            #pragma unroll
            for (int r = 0; r < 8; ++r)
                #pragma unroll
                for (int c = 0; c < 4; ++c)
                    acc[r][c] = fmaf(a[r], b[c], acc[r][c]);
        }
        __syncthreads();
    }
    #pragma unroll
    for (int r = 0; r < 8; ++r){
        int gr = m0 + ty*8 + r;
        if (gr >= M) continue;
        #pragma unroll
        for (int c = 0; c < 4; ++c){
            int gc = n0 + tx*4 + c;
            if (gc >= N) continue;
            C[(size_t)gr * N + gc] = acc[r][c] + bias[gc];
        }
    }
}

// ---------------- pooling ----------------

template<int F32>
__global__ void score_kernel(const void* __restrict__ hep, const float* __restrict__ w,
                             float* __restrict__ score){
    int row = blockIdx.x * 4 + (threadIdx.x >> 6);
    int lane = threadIdx.x & 63;
    if (row >= NE) return;
    float s = 0.f;
    #pragma unroll
    for (int j = 0; j < 8; ++j){
        int idx = lane + j * 64;
        float x = F32 ? ((const float*)hep)[(size_t)row * HD + idx]
                      : bf2f(((const short*)hep)[(size_t)row * HD + idx]);
        s += x * w[idx];
    }
    #pragma unroll
    for (int off = 32; off > 0; off >>= 1) s += __shfl_down(s, off);
    if (lane == 0) score[row] = s;
}

// one wave per dst; lane covers 8 columns
template<int F32>
__global__ __launch_bounds__(256)
void pool_kernel(const void* __restrict__ hep, const void* __restrict__ hwp,
                 const float* __restrict__ score, const int* __restrict__ off,
                 const int* __restrict__ elist, float* __restrict__ outp){
    int dst = blockIdx.x * 4 + (threadIdx.x >> 6);
    int lane = threadIdx.x & 63;
    if (dst >= NW) return;
    int s0 = off[dst], s1 = off[dst + 1];
    float m = -INFINITY;
    for (int e = s0 + lane; e < s1; e += 64) m = fmaxf(m, score[elist[e]]);
    #pragma unroll
    for (int o = 1; o < 64; o <<= 1) m = fmaxf(m, __shfl_xor(m, o));
    float z = 0.f;
    for (int e = s0 + lane; e < s1; e += 64) z += expf(score[elist[e]] - m);
    #pragma unroll
    for (int o = 1; o < 64; o <<= 1) z += __shfl_xor(z, o);
    float zinv = 1.0f / fmaxf(z, 1e-12f);

    float acc[8] = {};
    for (int eb = s0; eb < s1; eb += 64){
        int cnt = min(64, s1 - eb);
        int idx = (eb + lane < s1) ? elist[eb + lane] : 0;
        float at = (eb + lane < s1) ? expf(score[idx] - m) * zinv : 0.f;
        for (int j = 0; j < cnt; ++j){
            float a = __shfl(at, j);
            int src = __shfl(idx, j);
            if (F32){
                f32x4 v0 = *(const f32x4*)((const float*)hep + (size_t)src * HD + lane * 8);
                f32x4 v1 = *(const f32x4*)((const float*)hep + (size_t)src * HD + lane * 8 + 4);
                #pragma unroll
                for (int k = 0; k < 4; ++k){ acc[k] += a * v0[k]; acc[k+4] += a * v1[k]; }
            } else {
                short8 v = *(const short8*)((const short*)hep + (size_t)src * HD + lane * 8);
                #pragma unroll
                for (int k = 0; k < 8; ++k) acc[k] += a * bf2f(v[k]);
            }
        }
    }
    float hw[8];
    if (F32){
        f32x4 v0 = *(const f32x4*)((const float*)hwp + (size_t)dst * HD + lane * 8);
        f32x4 v1 = *(const f32x4*)((const float*)hwp + (size_t)dst * HD + lane * 8 + 4);
        #pragma unroll
        for (int k = 0; k < 4; ++k){ hw[k] = v0[k]; hw[k+4] = v1[k]; }
    } else {
        short8 v = *(const short8*)((const short*)hwp + (size_t)dst * HD + lane * 8);
        #pragma unroll
        for (int k = 0; k < 8; ++k) hw[k] = bf2f(v[k]);
    }
    f32x4 o0, o1;
    #pragma unroll
    for (int k = 0; k < 4; ++k){ o0[k] = hw[k] + LAM * acc[k]; o1[k] = hw[k+4] + LAM * acc[k+4]; }
    *(f32x4*)(outp + (size_t)dst * HD + lane * 8) = o0;
    *(f32x4*)(outp + (size_t)dst * HD + lane * 8 + 4) = o1;
}

// ---------------- host ----------------

extern "C" void kernel_launch(void* const* d_in, const int* in_sizes, int n_in,
                              void* d_out, int out_size, void* d_ws, size_t ws_size,
                              hipStream_t stream){
    const float* x_window = (const float*)d_in[0];
    const float* x_example= (const float*)d_in[1];
    const int*   e_near   = (const int*)d_in[2];
    const int*   e_close  = (const int*)d_in[3];
    const int*   e_refer  = (const int*)d_in[4];
    const float* W_win    = (const float*)d_in[5];
    const float* W_exp    = (const float*)d_in[6];
    const float* W_post   = (const float*)d_in[7];
    const float* Wl_near  = (const float*)d_in[9];
    const float* Wr_near  = (const float*)d_in[10];
    const float* b_near   = (const float*)d_in[11];
    const float* Wl_close = (const float*)d_in[12];
    const float* Wr_close = (const float*)d_in[13];
    const float* b_close  = (const float*)d_in[14];
    const float* Wl_refer = (const float*)d_in[15];
    const float* Wr_refer = (const float*)d_in[16];
    const float* b_refer  = (const float*)d_in[17];
    const float* w_pool   = (const float*)d_in[18];
    const float* W_lin    = (const float*)d_in[19];
    const float* b_lin    = (const float*)d_in[20];
    float* out = (float*)d_out;
    (void)in_sizes; (void)n_in; (void)out_size;

    char* w = (char*)d_ws;
    size_t o = 0;
    auto alloc = [&](size_t bytes)->char*{
        char* p = w + o;
        o += (bytes + 255) & ~(size_t)255;
        return p;
    };
    const size_t HBH = (size_t)ROWP * HD * 2;   // bf16 row-padded
    const size_t WHH = (size_t)HD * HD;

    short* h16[2][2];
    h16[0][0] = (short*)alloc(HBH); h16[0][1] = (short*)alloc(HBH);
    h16[1][0] = (short*)alloc(HBH); h16[1][1] = (short*)alloc(HBH);
    short* aggA = (short*)alloc(HBH);
    short* aggB = (short*)alloc(HBH);
    float* hwf  = (float*)alloc((size_t)NW * HD * 4);  // fp32 window h / pooled (in-place)
    short* WwinT  = (short*)alloc((size_t)HD * 1952 * 2);
    short* WexpT  = (short*)alloc((size_t)HD * 128 * 2);
    short* WpostT = (short*)alloc(WHH * 2);
    short* WlnT   = (short*)alloc((size_t)NL * WHH * 2);
    short* WlrT   = (short*)alloc((size_t)NL * WHH * 2);
    short* WlcT   = (short*)alloc((size_t)NL * WHH * 2);
    short* WrcT   = (short*)alloc((size_t)NL * WHH * 2);
    short* WcbT   = (short*)alloc((size_t)NL * WHH * 2);
    float* bsum   = (float*)alloc((size_t)NL * HD * 4);
    float* score  = (float*)alloc((size_t)NE * 4);
    int* degcur = (int*)alloc((size_t)6 * 30000 * 4);
    int* deg_n = degcur, *deg_r = degcur + 30000, *deg_c = degcur + 60000;
    int* cur_n = degcur + 90000, *cur_r = degcur + 120000, *cur_c = degcur + 150000;
    int* off_n = (int*)alloc((size_t)(NW + 1) * 4);
    int* off_r = (int*)alloc((size_t)(NW + 1) * 4);
    int* off_c = (int*)alloc((size_t)(NE + 1) * 4);
    int* el_n  = (int*)alloc((size_t)EE * 4);
    int* el_r  = (int*)alloc((size_t)EE * 4);
    int* el_c  = (int*)alloc((size_t)EE * 4);
    bool haveF32 = (ws_size >= o + (size_t)NE * HD * 4 + 512);
    float* hef = haveF32 ? (float*)alloc((size_t)NE * HD * 4) : nullptr;

    const int* src_n = e_near;  const int* dst_n = e_near + EE;
    const int* src_c = e_close; const int* dst_c = e_close + EE;
    const int* src_r = e_refer; const int* dst_r = e_refer + EE;

    // ---- CSR build ----
    hipMemsetAsync(degcur, 0, (size_t)6 * 30000 * 4, stream);
    int eg = (EE + 255) / 256;
    hipLaunchKernelGGL(count_kernel, dim3(eg), dim3(256), 0, stream, dst_n, deg_n, EE);
    hipLaunchKernelGGL(count_kernel, dim3(eg), dim3(256), 0, stream, dst_r, deg_r, EE);
    hipLaunchKernelGGL(count_kernel, dim3(eg), dim3(256), 0, stream, dst_c, deg_c, EE);
    hipLaunchKernelGGL(scan3_kernel, dim3(3), dim3(1024), 0, stream,
                       deg_n, NW, off_n, deg_r, NW, off_r, deg_c, NE, off_c);
    hipLaunchKernelGGL(fill_kernel, dim3(eg), dim3(256), 0, stream, src_n, dst_n, cur_n, off_n, el_n, EE);
    hipLaunchKernelGGL(fill_kernel, dim3(eg), dim3(256), 0, stream, src_r, dst_r, cur_r, off_r, el_r, EE);
    hipLaunchKernelGGL(fill_kernel, dim3(eg), dim3(256), 0, stream, src_c, dst_c, cur_c, off_c, el_c, EE);

    // ---- weight transposes (fp32 [K,N] -> bf16 [N,Kpad]) ----
    hipLaunchKernelGGL((transpose_bf_kernel<0>), dim3(16, 61, 1), dim3(256), 0, stream,
                       W_win, (const float*)nullptr, WwinT, 1949, HD, 1952);
    hipLaunchKernelGGL((transpose_bf_kernel<0>), dim3(16, 4, 1), dim3(256), 0, stream,
                       W_exp, (const float*)nullptr, WexpT, 100, HD, 128);
    hipLaunchKernelGGL((transpose_bf_kernel<0>), dim3(16, 16, 1), dim3(256), 0, stream,
                       W_post, (const float*)nullptr, WpostT, HD, HD, HD);
    hipLaunchKernelGGL((transpose_bf_kernel<0>), dim3(16, 16, NL), dim3(256), 0, stream,
                       Wl_near, (const float*)nullptr, WlnT, HD, HD, HD);
    hipLaunchKernelGGL((transpose_bf_kernel<0>), dim3(16, 16, NL), dim3(256), 0, stream,
                       Wl_refer, (const float*)nullptr, WlrT, HD, HD, HD);
    hipLaunchKernelGGL((transpose_bf_kernel<0>), dim3(16, 16, NL), dim3(256), 0, stream,
                       Wl_close, (const float*)nullptr, WlcT, HD, HD, HD);
    hipLaunchKernelGGL((transpose_bf_kernel<0>), dim3(16, 16, NL), dim3(256), 0, stream,
                       Wr_close, (const float*)nullptr, WrcT, HD, HD, HD);
    hipLaunchKernelGGL((transpose_bf_kernel<1>), dim3(16, 16, NL), dim3(256), 0, stream,
                       Wr_near, Wr_refer, WcbT, HD, HD, HD);
    hipLaunchKernelGGL(addf_kernel, dim3((NL * HD + 255) / 256), dim3(256), 0, stream,
                       b_near, b_refer, bsum, NL * HD);

    dim3 ggrid(4, (30000 + 127) / 128);
    #define MGEMM(NP,KT,KACT,AF32,ACT,WF32, a0,a1,a2, b0,b1,b2, bp, c16, c32, Mv) \
        hipLaunchKernelGGL((mgemm_kernel<NP,KT,KACT,AF32,ACT,WF32>), ggrid, dim3(256), 0, stream, \
            (const void*)(a0), (const void*)(a1), (const void*)(a2), b0, b1, b2, bp, c16, c32, Mv, HD)

    // ---- feature transforms ----
    MGEMM(1,128,100,1,1,0, x_example, nullptr, nullptr, WexpT, nullptr, nullptr,
          (const float*)nullptr, aggA, (float*)nullptr, NE);
    MGEMM(1,512,512,0,1,0, aggA, nullptr, nullptr, WpostT, nullptr, nullptr,
          (const float*)nullptr, h16[1][0], (float*)nullptr, NE);
    MGEMM(1,1952,1949,1,1,0, x_window, nullptr, nullptr, WwinT, nullptr, nullptr,
          (const float*)nullptr, aggA, (float*)nullptr, NW);
    MGEMM(1,512,512,0,1,0, aggA, nullptr, nullptr, WpostT, nullptr, nullptr,
          (const float*)nullptr, h16[0][0], (float*)nullptr, NW);

    // ---- layers ----
    for (int l = 0; l < NL; ++l){
        int cur = l & 1, nxt = cur ^ 1;
        const short* wl_n = WlnT + (size_t)l * WHH;
        const short* wl_r = WlrT + (size_t)l * WHH;
        const short* wl_c = WlcT + (size_t)l * WHH;
        const short* wr_c = WrcT + (size_t)l * WHH;
        const short* wcb  = WcbT + (size_t)l * WHH;
        const float* bs   = bsum + (size_t)l * HD;
        const float* bc   = b_close + (size_t)l * HD;
        bool last = (l == NL - 1);

        hipLaunchKernelGGL(seg_mean16_kernel, dim3((NW + 3) / 4), dim3(256), 0, stream,
                           h16[0][cur], off_n, el_n, aggA, NW);
        hipLaunchKernelGGL(seg_mean16_kernel, dim3((NW + 3) / 4), dim3(256), 0, stream,
                           h16[1][cur], off_r, el_r, aggB, NW);
        if (last){
            MGEMM(3,512,512,0,2,1, aggA, aggB, h16[0][cur], wl_n, wl_r, wcb, bs, h16[0][nxt], hwf, NW);
        } else {
            MGEMM(3,512,512,0,2,0, aggA, aggB, h16[0][cur], wl_n, wl_r, wcb, bs, h16[0][nxt], (float*)nullptr, NW);
        }
        hipLaunchKernelGGL(seg_mean16_kernel, dim3((NE + 3) / 4), dim3(256), 0, stream,
                           h16[1][cur], off_c, el_c, aggA, NE);
        if (last && haveF32){
            MGEMM(2,512,512,0,1,1, aggA, h16[1][cur], nullptr, wl_c, wr_c, nullptr, bc, h16[1][nxt], hef, NE);
        } else {
            MGEMM(2,512,512,0,1,0, aggA, h16[1][cur], nullptr, wl_c, wr_c, nullptr, bc, h16[1][nxt], (float*)nullptr, NE);
        }
    }
    int fin = NL & 1;

    // ---- CSRA pooling (writes hwf in-place: hwf = hwf + LAM*pooled) ----
    if (haveF32){
        hipLaunchKernelGGL((score_kernel<1>), dim3((NE + 3) / 4), dim3(256), 0, stream,
                           (const void*)hef, w_pool, score);
        hipLaunchKernelGGL((pool_kernel<1>), dim3((NW + 3) / 4), dim3(256), 0, stream,
                           (const void*)hef, (const void*)hwf, score, off_r, el_r, hwf);
    } else {
        hipLaunchKernelGGL((score_kernel<0>), dim3((NE + 3) / 4), dim3(256), 0, stream,
                           (const void*)h16[1][fin], w_pool, score);
        hipLaunchKernelGGL((pool_kernel<0>), dim3((NW + 3) / 4), dim3(256), 0, stream,
                           (const void*)h16[1][fin], (const void*)hwf, score, off_r, el_r, hwf);
    }

    // ---- final linear (fp32) ----
    hipLaunchKernelGGL(gemm_kernel, dim3(2, (NW + 127) / 128), dim3(256), 0, stream,
                       hwf, W_lin, b_lin, out, NW, 100, HD);
    #undef MGEMM
}

// Round 4
// 2809.473 us; speedup vs baseline: 2.9427x; 1.0697x over previous
//
#include <hip/hip_runtime.h>
#include <hip/hip_bf16.h>
#include <cstdint>
#include <cstddef>

#define NW 30000
#define NE 30000
#define EE 480000
#define HD 512
#define NL 4
#define SLOPE 0.2f
#define LAM 0.5f
#define ROWP 30080  // 30000 padded to multiple of 128 (and 64) for OOB-safe tile reads
#define WHH ((size_t)HD * HD)

typedef short short8 __attribute__((ext_vector_type(8)));
typedef float f32x4 __attribute__((ext_vector_type(4)));

static __device__ __forceinline__ float lrelu_f(float x){
    return fmaxf(x, 0.f) + SLOPE * fminf(x, 0.f);
}
static __device__ __forceinline__ short f2bf(float f){
    uint32_t u = __builtin_bit_cast(uint32_t, f);
    u += 0x7FFFu + ((u >> 16) & 1u);
    return (short)(u >> 16);
}
static __device__ __forceinline__ float bf2f(short s){
    uint32_t u = ((uint32_t)(uint16_t)s) << 16;
    return __builtin_bit_cast(float, u);
}

typedef const __attribute__((address_space(1))) void* gas_t;
typedef __attribute__((address_space(3))) void* las_t;
static __device__ __forceinline__ void gload16(const void* g, void* l){
    __builtin_amdgcn_global_load_lds((gas_t)g, (las_t)l, 16, 0, 0);
}

// ---------------- CSR build ----------------

__global__ void count_kernel(const int* __restrict__ dst, int* __restrict__ deg, int E){
    int e = blockIdx.x * 256 + threadIdx.x;
    if (e < E) atomicAdd(&deg[dst[e]], 1);
}

__global__ void scan3_kernel(const int* d0, int n0, int* o0,
                             const int* d1, int n1, int* o1,
                             const int* d2, int n2, int* o2){
    const int* deg; int n; int* off;
    if (blockIdx.x == 0){ deg=d0; n=n0; off=o0; }
    else if (blockIdx.x == 1){ deg=d1; n=n1; off=o1; }
    else { deg=d2; n=n2; off=o2; }
    __shared__ int tmp[1024];
    int t = threadIdx.x;
    int carry = 0;
    if (t == 0) off[0] = 0;
    for (int base = 0; base < n; base += 1024){
        int v = (base + t < n) ? deg[base + t] : 0;
        tmp[t] = v; __syncthreads();
        for (int d = 1; d < 1024; d <<= 1){
            int add = (t >= d) ? tmp[t - d] : 0;
            __syncthreads();
            tmp[t] += add;
            __syncthreads();
        }
        if (base + t < n) off[base + t + 1] = tmp[t] + carry;
        carry += tmp[1023];
        __syncthreads();
    }
}

__global__ void fill_kernel(const int* __restrict__ src, const int* __restrict__ dst,
                            int* __restrict__ cur, const int* __restrict__ off,
                            int* __restrict__ elist, int E){
    int e = blockIdx.x * 256 + threadIdx.x;
    if (e < E){
        int d = dst[e];
        int p = atomicAdd(&cur[d], 1);
        elist[off[d] + p] = src[e];
    }
}

// ---------------- weight transpose fp32[K,N] -> bf16[N,Kpad] (W_win / W_exp) ----------------

__global__ __launch_bounds__(256)
void transpose_bf_kernel(const float* __restrict__ in, short* __restrict__ out,
                         int K, int N, int Kpad){
    __shared__ float tile[32][33];
    int kbase = blockIdx.y * 32, nbase = blockIdx.x * 32;
    int tx = threadIdx.x & 31, ty = threadIdx.x >> 5;
    #pragma unroll
    for (int r = 0; r < 4; ++r){
        int k = kbase + ty + r * 8;
        float v = 0.f;
        if (k < K) v = in[(size_t)k * N + nbase + tx];
        tile[ty + r * 8][tx] = v;
    }
    __syncthreads();
    #pragma unroll
    for (int r = 0; r < 4; ++r){
        int n = nbase + ty + r * 8;
        int k = kbase + tx;
        if (k < Kpad) out[(size_t)n * Kpad + k] = f2bf(tile[tx][ty + r * 8]);
    }
}

// ---------------- all 21 HxH transposes in one dispatch ----------------
// z: 0-3 Wl_near, 4-7 Wl_refer, 8-11 Wl_close, 12-15 Wr_close, 16-19 Wr_near+Wr_refer, 20 W_post

__global__ __launch_bounds__(256)
void transpose_all_kernel(const float* __restrict__ Wln, const float* __restrict__ Wlr,
                          const float* __restrict__ Wlc, const float* __restrict__ Wrc,
                          const float* __restrict__ Wrn, const float* __restrict__ Wrr,
                          const float* __restrict__ Wpost, short* __restrict__ outT){
    __shared__ float tile[32][33];
    int z = blockIdx.z;
    const float* a; const float* b = nullptr;
    if (z < 4) a = Wln + (size_t)z * WHH;
    else if (z < 8) a = Wlr + (size_t)(z - 4) * WHH;
    else if (z < 12) a = Wlc + (size_t)(z - 8) * WHH;
    else if (z < 16) a = Wrc + (size_t)(z - 12) * WHH;
    else if (z < 20){ a = Wrn + (size_t)(z - 16) * WHH; b = Wrr + (size_t)(z - 16) * WHH; }
    else a = Wpost;
    short* outp = outT + (size_t)z * WHH;
    int kbase = blockIdx.y * 32, nbase = blockIdx.x * 32;
    int tx = threadIdx.x & 31, ty = threadIdx.x >> 5;
    #pragma unroll
    for (int r = 0; r < 4; ++r){
        int k = kbase + ty + r * 8;
        float v = a[(size_t)k * HD + nbase + tx];
        if (b) v += b[(size_t)k * HD + nbase + tx];
        tile[ty + r * 8][tx] = v;
    }
    __syncthreads();
    #pragma unroll
    for (int r = 0; r < 4; ++r){
        int n = nbase + ty + r * 8;
        outp[(size_t)n * HD + kbase + tx] = f2bf(tile[tx][ty + r * 8]);
    }
}

__global__ void addf_kernel(const float* __restrict__ a, const float* __restrict__ b,
                            float* __restrict__ o, int n){
    int i = blockIdx.x * 256 + threadIdx.x;
    if (i < n) o[i] = a[i] + b[i];
}

// ---------------- x_window fp32 -> bf16 [ROWP][1952] ----------------

__global__ __launch_bounds__(256)
void conv_xw_kernel(const float* __restrict__ x, short* __restrict__ o){
    int idx = blockIdx.x * 256 + threadIdx.x;           // over 30000*244 chunks
    if (idx >= 30000 * 244) return;
    int row = idx / 244, c8 = idx - row * 244;
    int base = c8 * 8;
    short8 v = {};
    const float* xp = x + (size_t)row * 1949 + base;
    if (base + 8 <= 1949){
        f32x4 a = *(const f32x4*)xp;
        f32x4 bq = *(const f32x4*)(xp + 4);
        #pragma unroll
        for (int j = 0; j < 4; ++j){ v[j] = f2bf(a[j]); v[j + 4] = f2bf(bq[j]); }
    } else {
        #pragma unroll
        for (int j = 0; j < 8; ++j) if (base + j < 1949) v[j] = f2bf(xp[j]);
    }
    *(short8*)(o + (size_t)row * 1952 + base) = v;
}

// ---------------- segment mean: one wave per dst, unroll 8 ----------------

__global__ __launch_bounds__(256)
void seg_mean16_kernel(const short* __restrict__ h, const int* __restrict__ off,
                       const int* __restrict__ elist, short* __restrict__ out, int ndst){
    int dst = blockIdx.x * 4 + (threadIdx.x >> 6);
    int lane = threadIdx.x & 63;
    if (dst >= ndst) return;
    int s0 = off[dst], s1 = off[dst + 1];
    float acc[8] = {};
    int e = s0;
    for (; e + 8 <= s1; e += 8){
        int idx[8];
        #pragma unroll
        for (int u = 0; u < 8; ++u) idx[u] = elist[e + u];
        short8 v[8];
        #pragma unroll
        for (int u = 0; u < 8; ++u) v[u] = *(const short8*)(h + (size_t)idx[u] * HD + lane * 8);
        #pragma unroll
        for (int u = 0; u < 8; ++u)
            #pragma unroll
            for (int j = 0; j < 8; ++j) acc[j] += bf2f(v[u][j]);
    }
    for (; e < s1; ++e){
        short8 v = *(const short8*)(h + (size_t)elist[e] * HD + lane * 8);
        #pragma unroll
        for (int j = 0; j < 8; ++j) acc[j] += bf2f(v[j]);
    }
    float inv = (s1 > s0) ? 1.0f / (float)(s1 - s0) : 0.0f;
    short8 o8;
    #pragma unroll
    for (int j = 0; j < 8; ++j) o8[j] = f2bf(acc[j] * inv);
    *(short8*)(out + (size_t)dst * HD + lane * 8) = o8;
}

// ---------------- MFMA GEMM: 64x128 tile, 128 threads (2 waves), XCD-swizzled ----------------
// A: [*,KT] bf16 row-padded (>= grid_rows*64 rows) or [M,KACT] fp32 (AF32). BT: [512][KT] bf16.
// C columns fixed at N=512. LDS 32-K tiles, XOR-swizzled 16B slots.

template<int NP, int KT, int KACT, int AF32, int ACT, int WF32>
__global__ __launch_bounds__(128)
void mgemm_kernel(const void* __restrict__ A0, const void* __restrict__ A1, const void* __restrict__ A2,
                  const short* __restrict__ B0, const short* __restrict__ B1, const short* __restrict__ B2,
                  const float* __restrict__ bias, short* __restrict__ C16, float* __restrict__ C32,
                  int M){
    constexpr int KPT = KT / 32;
    constexpr int NSTEPS = NP * KPT;
    constexpr int N = 512;
    __shared__ short ldsA[2][2048];   // 64x32
    __shared__ short ldsB[2][4096];   // 128x32
    // bijective XCD-chunked swizzle (m204)
    int nwg = gridDim.x;
    int orig = blockIdx.x;
    int q = nwg >> 3, r = nwg & 7;
    int xcd = orig & 7, lid = orig >> 3;
    int logical = (xcd < r ? xcd * (q + 1) : r * (q + 1) + (xcd - r) * q) + lid;
    const int m0 = (logical >> 2) * 64, n0 = (logical & 3) * 128;
    const int t = threadIdx.x, wid = t >> 6, lane = t & 63;
    const int wn = wid * 64;
    const int lg = lane >> 4, lr = lane & 15;
    f32x4 acc[4][4] = {};

    int rowiA[2], ciA[2];
    #pragma unroll
    for (int i = 0; i < 2; ++i){
        int sl = i * 128 + t;
        rowiA[i] = sl >> 2;
        ciA[i] = (sl & 3) ^ ((rowiA[i] >> 1) & 3);
    }
    int rowiB[4], ciB[4];
    #pragma unroll
    for (int i = 0; i < 4; ++i){
        int sl = i * 128 + t;
        rowiB[i] = sl >> 2;
        ciB[i] = (sl & 3) ^ ((rowiB[i] >> 1) & 3);
    }
    f32x4 ra[2][2];

    auto stage_load = [&](int s){
        int p = s / KPT;
        int k0 = (s - p * KPT) * 32;
        const void* Ap = (p == 0) ? A0 : ((p == 1) ? A1 : A2);
        const short* Bp = (p == 0) ? B0 : ((p == 1) ? B1 : B2);
        int bb = s & 1;
        #pragma unroll
        for (int i = 0; i < 2; ++i){
            int gr = m0 + rowiA[i];
            int gk = k0 + ciA[i] * 8;
            if (AF32){
                ra[i][0] = (f32x4){0,0,0,0};
                ra[i][1] = (f32x4){0,0,0,0};
                if (gr < M){
                    const float* ap = (const float*)Ap + (size_t)gr * KACT + gk;
                    if (KACT == KT || gk + 8 <= KACT){
                        ra[i][0] = *(const f32x4*)ap;
                        ra[i][1] = *(const f32x4*)(ap + 4);
                    } else {
                        #pragma unroll
                        for (int j = 0; j < 8; ++j)
                            if (gk + j < KACT) ra[i][j >> 2][j & 3] = ap[j];
                    }
                }
            } else {
                const short* ap = (const short*)Ap + (size_t)gr * KT + gk;
                gload16(ap, &ldsA[bb][(i * 128 + wid * 64) * 8]);
            }
        }
        #pragma unroll
        for (int i = 0; i < 4; ++i){
            const short* bp = Bp + (size_t)(n0 + rowiB[i]) * KT + k0 + ciB[i] * 8;
            gload16(bp, &ldsB[bb][(i * 128 + wid * 64) * 8]);
        }
    };
    auto stage_writeA = [&](int s){
        int bb = s & 1;
        #pragma unroll
        for (int i = 0; i < 2; ++i){
            short8 v;
            #pragma unroll
            for (int j = 0; j < 8; ++j) v[j] = f2bf(ra[i][j >> 2][j & 3]);
            *(short8*)&ldsA[bb][(i * 128 + t) * 8] = v;
        }
    };
    auto compute = [&](int s){
        int bb = s & 1;
        short8 af[4], bfr[4];
        #pragma unroll
        for (int f = 0; f < 4; ++f){
            int rowA = f * 16 + lr;
            af[f] = *(const short8*)((const char*)&ldsA[bb][0] + rowA * 64 + ((lg ^ ((rowA >> 1) & 3)) << 4));
            int rowB = wn + f * 16 + lr;
            bfr[f] = *(const short8*)((const char*)&ldsB[bb][0] + rowB * 64 + ((lg ^ ((rowB >> 1) & 3)) << 4));
        }
        #pragma unroll
        for (int i = 0; i < 4; ++i)
            #pragma unroll
            for (int j = 0; j < 4; ++j)
                acc[i][j] = __builtin_amdgcn_mfma_f32_16x16x32_bf16(af[i], bfr[j], acc[i][j], 0, 0, 0);
    };

    stage_load(0);
    if (AF32) stage_writeA(0);
    __syncthreads();
    for (int s = 0; s < NSTEPS; ++s){
        if (s + 1 < NSTEPS) stage_load(s + 1);
        compute(s);
        if (AF32 && s + 1 < NSTEPS) stage_writeA(s + 1);
        __syncthreads();
    }

    float bv[4];
    #pragma unroll
    for (int f = 0; f < 4; ++f) bv[f] = bias ? bias[n0 + wn + f * 16 + lr] : 0.f;
    #pragma unroll
    for (int i = 0; i < 4; ++i){
        #pragma unroll
        for (int r2 = 0; r2 < 4; ++r2){
            int gr = m0 + i * 16 + lg * 4 + r2;
            if (gr >= M) continue;
            #pragma unroll
            for (int j = 0; j < 4; ++j){
                int gc = n0 + wn + j * 16 + lr;
                float v = acc[i][j][r2] + bv[j];
                if (ACT == 2) v *= 0.5f;
                if (ACT) v = lrelu_f(v);
                C16[(size_t)gr * N + gc] = f2bf(v);
                if (WF32) C32[(size_t)gr * N + gc] = v;
            }
        }
    }
}

// ---------------- fp32 tiled GEMM (final 512->100 only) ----------------

__global__ __launch_bounds__(256)
void gemm_kernel(const float* __restrict__ A, const float* __restrict__ B,
                 const float* __restrict__ bias, float* __restrict__ C,
                 int M, int N, int K){
    const int BM = 128, BN = 64, BK = 16;
    __shared__ float As[BK][BM];
    __shared__ float Bs[BK][BN];
    int m0 = blockIdx.y * BM, n0 = blockIdx.x * BN;
    int t = threadIdx.x;
    int tx = t & 15, ty = t >> 4;
    float acc[8][4] = {};
    for (int k0 = 0; k0 < K; k0 += BK){
        #pragma unroll
        for (int i = 0; i < 2; ++i){
            int idx = i * 256 + t;
            int row = idx >> 2, kg = idx & 3;
            float4 v = make_float4(0,0,0,0);
            int gr = m0 + row, gk = k0 + kg * 4;
            if (gr < M && gk + 4 <= K)
                v = *reinterpret_cast<const float4*>(A + (size_t)gr * K + gk);
            As[kg*4+0][row] = v.x; As[kg*4+1][row] = v.y;
            As[kg*4+2][row] = v.z; As[kg*4+3][row] = v.w;
        }
        {
            int row = t >> 4, cg = t & 15;
            int gk = k0 + row, col = n0 + cg * 4;
            float4 v = make_float4(0,0,0,0);
            if (gk < K){
                if (col + 4 <= N){
                    v = *reinterpret_cast<const float4*>(B + (size_t)gk * N + col);
                } else {
                    float tp[4] = {0,0,0,0};
                    #pragma unroll
                    for (int j = 0; j < 4; ++j) if (col + j < N) tp[j] = B[(size_t)gk * N + col + j];
                    v = make_float4(tp[0], tp[1], tp[2], tp[3]);
                }
            }
            *reinterpret_cast<float4*>(&Bs[row][cg*4]) = v;
        }
        __syncthreads();
        #pragma unroll
        for (int k = 0; k < BK; ++k){
            float a[8], b[4];
            #pragma unroll
            for (int r = 0; r < 8; ++r) a[r] = As[k][ty*8 + r];
            #pragma unroll
            for (int c = 0; c < 4; ++c) b[c] = Bs[k][tx*4 + c];
            #pragma unroll
            for (int r = 0; r < 8; ++r)
                #pragma unroll
                for (int c = 0; c < 4; ++c)
                    acc[r][c] = fmaf(a[r], b[c], acc[r][c]);
        }
        __syncthreads();
    }
    #pragma unroll
    for (int r = 0; r < 8; ++r){
        int gr = m0 + ty*8 + r;
        if (gr >= M) continue;
        #pragma unroll
        for (int c = 0; c < 4; ++c){
            int gc = n0 + tx*4 + c;
            if (gc >= N) continue;
            C[(size_t)gr * N + gc] = acc[r][c] + bias[gc];
        }
    }
}

// ---------------- pooling ----------------

template<int F32>
__global__ void score_kernel(const void* __restrict__ hep, const float* __restrict__ w,
                             float* __restrict__ score){
    int row = blockIdx.x * 4 + (threadIdx.x >> 6);
    int lane = threadIdx.x & 63;
    if (row >= NE) return;
    float s = 0.f;
    #pragma unroll
    for (int j = 0; j < 8; ++j){
        int idx = lane + j * 64;
        float x = F32 ? ((const float*)hep)[(size_t)row * HD + idx]
                      : bf2f(((const short*)hep)[(size_t)row * HD + idx]);
        s += x * w[idx];
    }
    #pragma unroll
    for (int off = 32; off > 0; off >>= 1) s += __shfl_down(s, off);
    if (lane == 0) score[row] = s;
}

// one wave per dst; seg_mean-style weighted gather
template<int F32>
__global__ __launch_bounds__(256)
void pool_kernel(const void* __restrict__ hep, const void* __restrict__ hwp,
                 const float* __restrict__ score, const int* __restrict__ off,
                 const int* __restrict__ elist, float* __restrict__ outp){
    int dst = blockIdx.x * 4 + (threadIdx.x >> 6);
    int lane = threadIdx.x & 63;
    if (dst >= NW) return;
    int s0 = off[dst], s1 = off[dst + 1];
    float m = -INFINITY;
    for (int e = s0 + lane; e < s1; e += 64) m = fmaxf(m, score[elist[e]]);
    #pragma unroll
    for (int o = 1; o < 64; o <<= 1) m = fmaxf(m, __shfl_xor(m, o));
    float z = 0.f;
    for (int e = s0 + lane; e < s1; e += 64) z += expf(score[elist[e]] - m);
    #pragma unroll
    for (int o = 1; o < 64; o <<= 1) z += __shfl_xor(z, o);
    float zinv = 1.0f / fmaxf(z, 1e-12f);

    float acc[8] = {};
    int e = s0;
    for (; e + 4 <= s1; e += 4){
        int idx[4]; float at[4];
        #pragma unroll
        for (int u = 0; u < 4; ++u) idx[u] = elist[e + u];
        #pragma unroll
        for (int u = 0; u < 4; ++u) at[u] = expf(score[idx[u]] - m) * zinv;
        #pragma unroll
        for (int u = 0; u < 4; ++u){
            if (F32){
                f32x4 v0 = *(const f32x4*)((const float*)hep + (size_t)idx[u] * HD + lane * 8);
                f32x4 v1 = *(const f32x4*)((const float*)hep + (size_t)idx[u] * HD + lane * 8 + 4);
                #pragma unroll
                for (int k = 0; k < 4; ++k){ acc[k] += at[u] * v0[k]; acc[k+4] += at[u] * v1[k]; }
            } else {
                short8 v = *(const short8*)((const short*)hep + (size_t)idx[u] * HD + lane * 8);
                #pragma unroll
                for (int k = 0; k < 8; ++k) acc[k] += at[u] * bf2f(v[k]);
            }
        }
    }
    for (; e < s1; ++e){
        int src = elist[e];
        float at = expf(score[src] - m) * zinv;
        if (F32){
            f32x4 v0 = *(const f32x4*)((const float*)hep + (size_t)src * HD + lane * 8);
            f32x4 v1 = *(const f32x4*)((const float*)hep + (size_t)src * HD + lane * 8 + 4);
            #pragma unroll
            for (int k = 0; k < 4; ++k){ acc[k] += at * v0[k]; acc[k+4] += at * v1[k]; }
        } else {
            short8 v = *(const short8*)((const short*)hep + (size_t)src * HD + lane * 8);
            #pragma unroll
            for (int k = 0; k < 8; ++k) acc[k] += at * bf2f(v[k]);
        }
    }
    float hw[8];
    if (F32){
        f32x4 v0 = *(const f32x4*)((const float*)hwp + (size_t)dst * HD + lane * 8);
        f32x4 v1 = *(const f32x4*)((const float*)hwp + (size_t)dst * HD + lane * 8 + 4);
        #pragma unroll
        for (int k = 0; k < 4; ++k){ hw[k] = v0[k]; hw[k+4] = v1[k]; }
    } else {
        short8 v = *(const short8*)((const short*)hwp + (size_t)dst * HD + lane * 8);
        #pragma unroll
        for (int k = 0; k < 8; ++k) hw[k] = bf2f(v[k]);
    }
    f32x4 o0, o1;
    #pragma unroll
    for (int k = 0; k < 4; ++k){ o0[k] = hw[k] + LAM * acc[k]; o1[k] = hw[k+4] + LAM * acc[k+4]; }
    *(f32x4*)(outp + (size_t)dst * HD + lane * 8) = o0;
    *(f32x4*)(outp + (size_t)dst * HD + lane * 8 + 4) = o1;
}

// ---------------- host ----------------

extern "C" void kernel_launch(void* const* d_in, const int* in_sizes, int n_in,
                              void* d_out, int out_size, void* d_ws, size_t ws_size,
                              hipStream_t stream){
    const float* x_window = (const float*)d_in[0];
    const float* x_example= (const float*)d_in[1];
    const int*   e_near   = (const int*)d_in[2];
    const int*   e_close  = (const int*)d_in[3];
    const int*   e_refer  = (const int*)d_in[4];
    const float* W_win    = (const float*)d_in[5];
    const float* W_exp    = (const float*)d_in[6];
    const float* W_post   = (const float*)d_in[7];
    const float* Wl_near  = (const float*)d_in[9];
    const float* Wr_near  = (const float*)d_in[10];
    const float* b_near   = (const float*)d_in[11];
    const float* Wl_close = (const float*)d_in[12];
    const float* Wr_close = (const float*)d_in[13];
    const float* b_close  = (const float*)d_in[14];
    const float* Wl_refer = (const float*)d_in[15];
    const float* Wr_refer = (const float*)d_in[16];
    const float* b_refer  = (const float*)d_in[17];
    const float* w_pool   = (const float*)d_in[18];
    const float* W_lin    = (const float*)d_in[19];
    const float* b_lin    = (const float*)d_in[20];
    float* out = (float*)d_out;
    (void)in_sizes; (void)n_in; (void)out_size;

    char* w = (char*)d_ws;
    size_t o = 0;
    auto alloc = [&](size_t bytes)->char*{
        char* p = w + o;
        o += (bytes + 255) & ~(size_t)255;
        return p;
    };
    const size_t HBH = (size_t)ROWP * HD * 2;   // bf16 row-padded

    short* h16[2][2];
    h16[0][0] = (short*)alloc(HBH); h16[0][1] = (short*)alloc(HBH);
    h16[1][0] = (short*)alloc(HBH); h16[1][1] = (short*)alloc(HBH);
    short* aggA = (short*)alloc(HBH);
    short* aggB = (short*)alloc(HBH);
    float* hwf  = (float*)alloc((size_t)NW * HD * 4);  // fp32 window h / pooled (in-place)
    short* WwinT  = (short*)alloc((size_t)HD * 1952 * 2);
    short* WexpT  = (short*)alloc((size_t)HD * 128 * 2);
    short* WT     = (short*)alloc((size_t)21 * WHH * 2);
    short* WlnT = WT;
    short* WlrT = WT + 4 * WHH;
    short* WlcT = WT + 8 * WHH;
    short* WrcT = WT + 12 * WHH;
    short* WcbT = WT + 16 * WHH;
    short* WpostT = WT + 20 * WHH;
    float* bsum   = (float*)alloc((size_t)NL * HD * 4);
    float* score  = (float*)alloc((size_t)NE * 4);
    int* degcur = (int*)alloc((size_t)6 * 30000 * 4);
    int* deg_n = degcur, *deg_r = degcur + 30000, *deg_c = degcur + 60000;
    int* cur_n = degcur + 90000, *cur_r = degcur + 120000, *cur_c = degcur + 150000;
    int* off_n = (int*)alloc((size_t)(NW + 1) * 4);
    int* off_r = (int*)alloc((size_t)(NW + 1) * 4);
    int* off_c = (int*)alloc((size_t)(NE + 1) * 4);
    int* el_n  = (int*)alloc((size_t)EE * 4);
    int* el_r  = (int*)alloc((size_t)EE * 4);
    int* el_c  = (int*)alloc((size_t)EE * 4);

    // optional region: xw16 (bf16 x_window, early-life) aliased with hef (fp32 h_exp, late-life)
    const size_t XWB = (size_t)ROWP * 1952 * 2;       // 117.4 MB
    const size_t HEB = (size_t)NE * HD * 4;           // 61.4 MB
    bool haveXW16 = false, haveF32 = false;
    short* xw16 = nullptr; float* hef = nullptr;
    size_t rem = (ws_size > o) ? ws_size - o : 0;
    if (rem >= XWB + 256){
        char* p = alloc(XWB);
        xw16 = (short*)p; hef = (float*)p;
        haveXW16 = haveF32 = true;
    } else if (rem >= HEB + 256){
        hef = (float*)alloc(HEB);
        haveF32 = true;
    }

    const int* src_n = e_near;  const int* dst_n = e_near + EE;
    const int* src_c = e_close; const int* dst_c = e_close + EE;
    const int* src_r = e_refer; const int* dst_r = e_refer + EE;

    // ---- CSR build ----
    hipMemsetAsync(degcur, 0, (size_t)6 * 30000 * 4, stream);
    int eg = (EE + 255) / 256;
    hipLaunchKernelGGL(count_kernel, dim3(eg), dim3(256), 0, stream, dst_n, deg_n, EE);
    hipLaunchKernelGGL(count_kernel, dim3(eg), dim3(256), 0, stream, dst_r, deg_r, EE);
    hipLaunchKernelGGL(count_kernel, dim3(eg), dim3(256), 0, stream, dst_c, deg_c, EE);
    hipLaunchKernelGGL(scan3_kernel, dim3(3), dim3(1024), 0, stream,
                       deg_n, NW, off_n, deg_r, NW, off_r, deg_c, NE, off_c);
    hipLaunchKernelGGL(fill_kernel, dim3(eg), dim3(256), 0, stream, src_n, dst_n, cur_n, off_n, el_n, EE);
    hipLaunchKernelGGL(fill_kernel, dim3(eg), dim3(256), 0, stream, src_r, dst_r, cur_r, off_r, el_r, EE);
    hipLaunchKernelGGL(fill_kernel, dim3(eg), dim3(256), 0, stream, src_c, dst_c, cur_c, off_c, el_c, EE);

    // ---- weight transposes ----
    hipLaunchKernelGGL(transpose_bf_kernel, dim3(16, 61, 1), dim3(256), 0, stream,
                       W_win, WwinT, 1949, HD, 1952);
    hipLaunchKernelGGL(transpose_bf_kernel, dim3(16, 4, 1), dim3(256), 0, stream,
                       W_exp, WexpT, 100, HD, 128);
    hipLaunchKernelGGL(transpose_all_kernel, dim3(16, 16, 21), dim3(256), 0, stream,
                       Wl_near, Wl_refer, Wl_close, Wr_close, Wr_near, Wr_refer, W_post, WT);
    hipLaunchKernelGGL(addf_kernel, dim3((NL * HD + 255) / 256), dim3(256), 0, stream,
                       b_near, b_refer, bsum, NL * HD);
    if (haveXW16)
        hipLaunchKernelGGL(conv_xw_kernel, dim3((30000 * 244 + 255) / 256), dim3(256), 0, stream,
                           x_window, xw16);

    #define MGEMM(NP,KT,KACT,AF32,ACT,WF32, a0,a1,a2, b0,b1,b2, bp, c16, c32, Mv) \
        hipLaunchKernelGGL((mgemm_kernel<NP,KT,KACT,AF32,ACT,WF32>), \
            dim3(4 * (((Mv) + 63) / 64)), dim3(128), 0, stream, \
            (const void*)(a0), (const void*)(a1), (const void*)(a2), b0, b1, b2, bp, c16, c32, Mv)

    // ---- feature transforms ----
    MGEMM(1,128,100,1,1,0, x_example, nullptr, nullptr, WexpT, nullptr, nullptr,
          (const float*)nullptr, aggA, (float*)nullptr, NE);
    MGEMM(1,512,512,0,1,0, aggA, nullptr, nullptr, WpostT, nullptr, nullptr,
          (const float*)nullptr, h16[1][0], (float*)nullptr, NE);
    if (haveXW16){
        MGEMM(1,1952,1952,0,1,0, xw16, nullptr, nullptr, WwinT, nullptr, nullptr,
              (const float*)nullptr, aggA, (float*)nullptr, NW);
    } else {
        MGEMM(1,1952,1949,1,1,0, x_window, nullptr, nullptr, WwinT, nullptr, nullptr,
              (const float*)nullptr, aggA, (float*)nullptr, NW);
    }
    MGEMM(1,512,512,0,1,0, aggA, nullptr, nullptr, WpostT, nullptr, nullptr,
          (const float*)nullptr, h16[0][0], (float*)nullptr, NW);

    // ---- layers ----
    for (int l = 0; l < NL; ++l){
        int cur = l & 1, nxt = cur ^ 1;
        const short* wl_n = WlnT + (size_t)l * WHH;
        const short* wl_r = WlrT + (size_t)l * WHH;
        const short* wl_c = WlcT + (size_t)l * WHH;
        const short* wr_c = WrcT + (size_t)l * WHH;
        const short* wcb  = WcbT + (size_t)l * WHH;
        const float* bs   = bsum + (size_t)l * HD;
        const float* bc   = b_close + (size_t)l * HD;
        bool last = (l == NL - 1);

        hipLaunchKernelGGL(seg_mean16_kernel, dim3((NW + 3) / 4), dim3(256), 0, stream,
                           h16[0][cur], off_n, el_n, aggA, NW);
        hipLaunchKernelGGL(seg_mean16_kernel, dim3((NW + 3) / 4), dim3(256), 0, stream,
                           h16[1][cur], off_r, el_r, aggB, NW);
        if (last){
            MGEMM(3,512,512,0,2,1, aggA, aggB, h16[0][cur], wl_n, wl_r, wcb, bs, h16[0][nxt], hwf, NW);
        } else {
            MGEMM(3,512,512,0,2,0, aggA, aggB, h16[0][cur], wl_n, wl_r, wcb, bs, h16[0][nxt], (float*)nullptr, NW);
        }
        hipLaunchKernelGGL(seg_mean16_kernel, dim3((NE + 3) / 4), dim3(256), 0, stream,
                           h16[1][cur], off_c, el_c, aggA, NE);
        if (last && haveF32){
            MGEMM(2,512,512,0,1,1, aggA, h16[1][cur], nullptr, wl_c, wr_c, nullptr, bc, h16[1][nxt], hef, NE);
        } else {
            MGEMM(2,512,512,0,1,0, aggA, h16[1][cur], nullptr, wl_c, wr_c, nullptr, bc, h16[1][nxt], (float*)nullptr, NE);
        }
    }
    int fin = NL & 1;

    // ---- CSRA pooling (hwf = hwf + LAM*pooled, in place) ----
    if (haveF32){
        hipLaunchKernelGGL((score_kernel<1>), dim3((NE + 3) / 4), dim3(256), 0, stream,
                           (const void*)hef, w_pool, score);
        hipLaunchKernelGGL((pool_kernel<1>), dim3((NW + 3) / 4), dim3(256), 0, stream,
                           (const void*)hef, (const void*)hwf, score, off_r, el_r, hwf);
    } else {
        hipLaunchKernelGGL((score_kernel<0>), dim3((NE + 3) / 4), dim3(256), 0, stream,
                           (const void*)h16[1][fin], w_pool, score);
        hipLaunchKernelGGL((pool_kernel<0>), dim3((NW + 3) / 4), dim3(256), 0, stream,
                           (const void*)h16[1][fin], (const void*)hwf, score, off_r, el_r, hwf);
    }

    // ---- final linear (fp32) ----
    hipLaunchKernelGGL(gemm_kernel, dim3(2, (NW + 127) / 128), dim3(256), 0, stream,
                       hwf, W_lin, b_lin, out, NW, 100, HD);
    #undef MGEMM
}

// Round 5
// 2485.932 us; speedup vs baseline: 3.3257x; 1.1301x over previous
//
#include <hip/hip_runtime.h>
#include <hip/hip_bf16.h>
#include <cstdint>
#include <cstddef>

#define NW 30000
#define NE 30000
#define EE 480000
#define HD 512
#define NL 4
#define SLOPE 0.2f
#define LAM 0.5f
#define ROWP 30080  // rows padded to multiple of 64/128 for OOB-safe tile reads
#define WHH ((size_t)HD * HD)

typedef short short8 __attribute__((ext_vector_type(8)));
typedef float f32x4 __attribute__((ext_vector_type(4)));

static __device__ __forceinline__ float lrelu_f(float x){
    return fmaxf(x, 0.f) + SLOPE * fminf(x, 0.f);
}
static __device__ __forceinline__ short f2bf(float f){
    uint32_t u = __builtin_bit_cast(uint32_t, f);
    u += 0x7FFFu + ((u >> 16) & 1u);
    return (short)(u >> 16);
}
static __device__ __forceinline__ float bf2f(short s){
    uint32_t u = ((uint32_t)(uint16_t)s) << 16;
    return __builtin_bit_cast(float, u);
}

typedef const __attribute__((address_space(1))) void* gas_t;
typedef __attribute__((address_space(3))) void* las_t;
static __device__ __forceinline__ void gload16(const void* g, void* l){
    __builtin_amdgcn_global_load_lds((gas_t)g, (las_t)l, 16, 0, 0);
}

// ---------------- CSR build ----------------

__global__ void count_kernel(const int* __restrict__ dst, int* __restrict__ deg, int E){
    int e = blockIdx.x * 256 + threadIdx.x;
    if (e < E) atomicAdd(&deg[dst[e]], 1);
}

__global__ void scan3_kernel(const int* d0, int n0, int* o0,
                             const int* d1, int n1, int* o1,
                             const int* d2, int n2, int* o2){
    const int* deg; int n; int* off;
    if (blockIdx.x == 0){ deg=d0; n=n0; off=o0; }
    else if (blockIdx.x == 1){ deg=d1; n=n1; off=o1; }
    else { deg=d2; n=n2; off=o2; }
    __shared__ int tmp[1024];
    int t = threadIdx.x;
    int carry = 0;
    if (t == 0) off[0] = 0;
    for (int base = 0; base < n; base += 1024){
        int v = (base + t < n) ? deg[base + t] : 0;
        tmp[t] = v; __syncthreads();
        for (int d = 1; d < 1024; d <<= 1){
            int add = (t >= d) ? tmp[t - d] : 0;
            __syncthreads();
            tmp[t] += add;
            __syncthreads();
        }
        if (base + t < n) off[base + t + 1] = tmp[t] + carry;
        carry += tmp[1023];
        __syncthreads();
    }
}

__global__ void fill_kernel(const int* __restrict__ src, const int* __restrict__ dst,
                            int* __restrict__ cur, const int* __restrict__ off,
                            int* __restrict__ elist, int E){
    int e = blockIdx.x * 256 + threadIdx.x;
    if (e < E){
        int d = dst[e];
        int p = atomicAdd(&cur[d], 1);
        elist[off[d] + p] = src[e];
    }
}

// ---------------- weight transpose fp32[K,N] -> bf16[N,Kpad] ----------------

__global__ __launch_bounds__(256)
void transpose_bf_kernel(const float* __restrict__ in, short* __restrict__ out,
                         int K, int N, int Kpad){
    __shared__ float tile[32][33];
    int kbase = blockIdx.y * 32, nbase = blockIdx.x * 32;
    int tx = threadIdx.x & 31, ty = threadIdx.x >> 5;
    #pragma unroll
    for (int r = 0; r < 4; ++r){
        int k = kbase + ty + r * 8;
        float v = 0.f;
        if (k < K) v = in[(size_t)k * N + nbase + tx];
        tile[ty + r * 8][tx] = v;
    }
    __syncthreads();
    #pragma unroll
    for (int r = 0; r < 4; ++r){
        int n = nbase + ty + r * 8;
        int k = kbase + tx;
        if (k < Kpad) out[(size_t)n * Kpad + k] = f2bf(tile[tx][ty + r * 8]);
    }
}

// ---------------- all 21 HxH transposes in one dispatch ----------------

__global__ __launch_bounds__(256)
void transpose_all_kernel(const float* __restrict__ Wln, const float* __restrict__ Wlr,
                          const float* __restrict__ Wlc, const float* __restrict__ Wrc,
                          const float* __restrict__ Wrn, const float* __restrict__ Wrr,
                          const float* __restrict__ Wpost, short* __restrict__ outT){
    __shared__ float tile[32][33];
    int z = blockIdx.z;
    const float* a; const float* b = nullptr;
    if (z < 4) a = Wln + (size_t)z * WHH;
    else if (z < 8) a = Wlr + (size_t)(z - 4) * WHH;
    else if (z < 12) a = Wlc + (size_t)(z - 8) * WHH;
    else if (z < 16) a = Wrc + (size_t)(z - 12) * WHH;
    else if (z < 20){ a = Wrn + (size_t)(z - 16) * WHH; b = Wrr + (size_t)(z - 16) * WHH; }
    else a = Wpost;
    short* outp = outT + (size_t)z * WHH;
    int kbase = blockIdx.y * 32, nbase = blockIdx.x * 32;
    int tx = threadIdx.x & 31, ty = threadIdx.x >> 5;
    #pragma unroll
    for (int r = 0; r < 4; ++r){
        int k = kbase + ty + r * 8;
        float v = a[(size_t)k * HD + nbase + tx];
        if (b) v += b[(size_t)k * HD + nbase + tx];
        tile[ty + r * 8][tx] = v;
    }
    __syncthreads();
    #pragma unroll
    for (int r = 0; r < 4; ++r){
        int n = nbase + ty + r * 8;
        outp[(size_t)n * HD + kbase + tx] = f2bf(tile[tx][ty + r * 8]);
    }
}

__global__ void addf_kernel(const float* __restrict__ a, const float* __restrict__ b,
                            float* __restrict__ o, int n){
    int i = blockIdx.x * 256 + threadIdx.x;
    if (i < n) o[i] = a[i] + b[i];
}

// ---------------- x_window fp32 -> bf16 [ROWP][1952] ----------------

__global__ __launch_bounds__(256)
void conv_xw_kernel(const float* __restrict__ x, short* __restrict__ o){
    int idx = blockIdx.x * 256 + threadIdx.x;
    if (idx >= 30000 * 244) return;
    int row = idx / 244, c8 = idx - row * 244;
    int base = c8 * 8;
    short8 v = {};
    const float* xp = x + (size_t)row * 1949 + base;
    if (base + 8 <= 1949){
        f32x4 a = *(const f32x4*)xp;
        f32x4 bq = *(const f32x4*)(xp + 4);
        #pragma unroll
        for (int j = 0; j < 4; ++j){ v[j] = f2bf(a[j]); v[j + 4] = f2bf(bq[j]); }
    } else {
        #pragma unroll
        for (int j = 0; j < 8; ++j) if (base + j < 1949) v[j] = f2bf(xp[j]);
    }
    *(short8*)(o + (size_t)row * 1952 + base) = v;
}

// ---------------- x_example fp32[30000][100] -> bf16 [ROWP][128] (zero-padded) ----------------

__global__ __launch_bounds__(256)
void conv_xe_kernel(const float* __restrict__ x, short* __restrict__ o){
    int idx = blockIdx.x * 256 + threadIdx.x;            // ROWP*16 chunks
    if (idx >= ROWP * 16) return;
    int row = idx >> 4, c8 = idx & 15;
    int base = c8 * 8;
    short8 v = {};
    if (row < 30000){
        const float* xp = x + (size_t)row * 100 + base;
        #pragma unroll
        for (int j = 0; j < 8; ++j) if (base + j < 100) v[j] = f2bf(xp[j]);
    }
    *(short8*)(o + (size_t)row * 128 + base) = v;
}

// ---------------- segment mean: one wave per dst, unroll 8 ----------------

__global__ __launch_bounds__(256)
void seg_mean16_kernel(const short* __restrict__ h, const int* __restrict__ off,
                       const int* __restrict__ elist, short* __restrict__ out, int ndst){
    int dst = blockIdx.x * 4 + (threadIdx.x >> 6);
    int lane = threadIdx.x & 63;
    if (dst >= ndst) return;
    int s0 = off[dst], s1 = off[dst + 1];
    float acc[8] = {};
    int e = s0;
    for (; e + 8 <= s1; e += 8){
        int idx[8];
        #pragma unroll
        for (int u = 0; u < 8; ++u) idx[u] = elist[e + u];
        short8 v[8];
        #pragma unroll
        for (int u = 0; u < 8; ++u) v[u] = *(const short8*)(h + (size_t)idx[u] * HD + lane * 8);
        #pragma unroll
        for (int u = 0; u < 8; ++u)
            #pragma unroll
            for (int j = 0; j < 8; ++j) acc[j] += bf2f(v[u][j]);
    }
    for (; e < s1; ++e){
        short8 v = *(const short8*)(h + (size_t)elist[e] * HD + lane * 8);
        #pragma unroll
        for (int j = 0; j < 8; ++j) acc[j] += bf2f(v[j]);
    }
    float inv = (s1 > s0) ? 1.0f / (float)(s1 - s0) : 0.0f;
    short8 o8;
    #pragma unroll
    for (int j = 0; j < 8; ++j) o8[j] = f2bf(acc[j] * inv);
    *(short8*)(out + (size_t)dst * HD + lane * 8) = o8;
}

// ---------------- MFMA GEMM, counted-vmcnt pipeline ----------------
// All-bf16: A [*,KT] row-padded, BT [512][KT]. 64x128 tile, 128 threads (2 waves).
// Per step: stage(s+1) [6 global_load_lds] -> vmcnt(6) -> s_barrier -> ds_read+MFMA
// -> lgkmcnt(0) -> s_barrier.  Next-step loads stay in flight across barriers (T4).

template<int NP, int KT, int ACT, int WF32>
__global__ __launch_bounds__(128)
void mgemm_kernel(const short* __restrict__ A0, const short* __restrict__ A1, const short* __restrict__ A2,
                  const short* __restrict__ B0, const short* __restrict__ B1, const short* __restrict__ B2,
                  const float* __restrict__ bias, short* __restrict__ C16, float* __restrict__ C32,
                  int M){
    constexpr int KPT = KT / 32;
    constexpr int NSTEPS = NP * KPT;
    constexpr int N = 512;
    __shared__ short ldsA[2][2048];   // 64 x 32
    __shared__ short ldsB[2][4096];   // 128 x 32
    // bijective XCD-chunked swizzle (m204)
    int nwg = gridDim.x;
    int orig = blockIdx.x;
    int q = nwg >> 3, r = nwg & 7;
    int xcd = orig & 7, lid = orig >> 3;
    int logical = (xcd < r ? xcd * (q + 1) : r * (q + 1) + (xcd - r) * q) + lid;
    const int m0 = (logical >> 2) * 64, n0 = (logical & 3) * 128;
    const int t = threadIdx.x, wid = t >> 6, lane = t & 63;
    const int wn = wid * 64;
    const int lg = lane >> 4, lr = lane & 15;
    f32x4 acc[4][4] = {};

    int rowiA[2], ciA[2];
    #pragma unroll
    for (int i = 0; i < 2; ++i){
        int sl = i * 128 + t;
        rowiA[i] = sl >> 2;
        ciA[i] = (sl & 3) ^ ((rowiA[i] >> 1) & 3);
    }
    int rowiB[4], ciB[4];
    #pragma unroll
    for (int i = 0; i < 4; ++i){
        int sl = i * 128 + t;
        rowiB[i] = sl >> 2;
        ciB[i] = (sl & 3) ^ ((rowiB[i] >> 1) & 3);
    }

    auto stage = [&](int s){
        int p = (NP > 1 && s >= KPT) ? ((NP > 2 && s >= 2 * KPT) ? 2 : 1) : 0;
        int k0 = (s - p * KPT) * 32;
        const short* Ap = (p == 0) ? A0 : ((p == 1) ? A1 : A2);
        const short* Bp = (p == 0) ? B0 : ((p == 1) ? B1 : B2);
        int bb = s & 1;
        #pragma unroll
        for (int i = 0; i < 2; ++i)
            gload16(Ap + (size_t)(m0 + rowiA[i]) * KT + k0 + ciA[i] * 8,
                    &ldsA[bb][(i * 128 + wid * 64) * 8]);
        #pragma unroll
        for (int i = 0; i < 4; ++i)
            gload16(Bp + (size_t)(n0 + rowiB[i]) * KT + k0 + ciB[i] * 8,
                    &ldsB[bb][(i * 128 + wid * 64) * 8]);
    };
    auto compute = [&](int s){
        int bb = s & 1;
        short8 af[4], bfr[4];
        #pragma unroll
        for (int f = 0; f < 4; ++f){
            int rowA = f * 16 + lr;
            af[f] = *(const short8*)((const char*)&ldsA[bb][0] + rowA * 64 + ((lg ^ ((rowA >> 1) & 3)) << 4));
            int rowB = wn + f * 16 + lr;
            bfr[f] = *(const short8*)((const char*)&ldsB[bb][0] + rowB * 64 + ((lg ^ ((rowB >> 1) & 3)) << 4));
        }
        #pragma unroll
        for (int i = 0; i < 4; ++i)
            #pragma unroll
            for (int j = 0; j < 4; ++j)
                acc[i][j] = __builtin_amdgcn_mfma_f32_16x16x32_bf16(af[i], bfr[j], acc[i][j], 0, 0, 0);
    };

    stage(0);
    for (int s = 0; s < NSTEPS; ++s){
        if (s + 1 < NSTEPS){
            stage(s + 1);
            asm volatile("s_waitcnt vmcnt(6)" ::: "memory");   // step-s loads done; s+1 in flight
        } else {
            asm volatile("s_waitcnt vmcnt(0)" ::: "memory");
        }
        __builtin_amdgcn_s_barrier();                          // all waves' step-s data in LDS
        __builtin_amdgcn_sched_barrier(0);
        compute(s);
        asm volatile("s_waitcnt lgkmcnt(0)" ::: "memory");     // all ds_reads of buf[s&1] done
        __builtin_amdgcn_sched_barrier(0);
        __builtin_amdgcn_s_barrier();                          // safe to overwrite buf[s&1] next iter
    }

    float bv[4];
    #pragma unroll
    for (int f = 0; f < 4; ++f) bv[f] = bias ? bias[n0 + wn + f * 16 + lr] : 0.f;
    #pragma unroll
    for (int i = 0; i < 4; ++i){
        #pragma unroll
        for (int r2 = 0; r2 < 4; ++r2){
            int gr = m0 + i * 16 + lg * 4 + r2;
            if (gr >= M) continue;
            #pragma unroll
            for (int j = 0; j < 4; ++j){
                int gc = n0 + wn + j * 16 + lr;
                float v = acc[i][j][r2] + bv[j];
                if (ACT == 2) v *= 0.5f;
                if (ACT) v = lrelu_f(v);
                C16[(size_t)gr * N + gc] = f2bf(v);
                if (WF32) C32[(size_t)gr * N + gc] = v;
            }
        }
    }
}

// ---------------- AF32 fallback mgemm (x_window only, if ws too small) ----------------

__global__ __launch_bounds__(128)
void mgemm_af32_kernel(const float* __restrict__ A0, const short* __restrict__ B0,
                       short* __restrict__ C16, int M){
    constexpr int KT = 1952, KACT = 1949, KPT = KT / 32, NSTEPS = KPT, N = 512;
    __shared__ short ldsA[2][2048];
    __shared__ short ldsB[2][4096];
    int nwg = gridDim.x;
    int orig = blockIdx.x;
    int q = nwg >> 3, r = nwg & 7;
    int xcd = orig & 7, lid = orig >> 3;
    int logical = (xcd < r ? xcd * (q + 1) : r * (q + 1) + (xcd - r) * q) + lid;
    const int m0 = (logical >> 2) * 64, n0 = (logical & 3) * 128;
    const int t = threadIdx.x, wid = t >> 6, lane = t & 63;
    const int wn = wid * 64;
    const int lg = lane >> 4, lr = lane & 15;
    f32x4 acc[4][4] = {};
    int rowiA[2], ciA[2];
    #pragma unroll
    for (int i = 0; i < 2; ++i){
        int sl = i * 128 + t;
        rowiA[i] = sl >> 2;
        ciA[i] = (sl & 3) ^ ((rowiA[i] >> 1) & 3);
    }
    int rowiB[4], ciB[4];
    #pragma unroll
    for (int i = 0; i < 4; ++i){
        int sl = i * 128 + t;
        rowiB[i] = sl >> 2;
        ciB[i] = (sl & 3) ^ ((rowiB[i] >> 1) & 3);
    }
    f32x4 ra[2][2];
    auto stage_load = [&](int s){
        int k0 = s * 32;
        int bb = s & 1;
        #pragma unroll
        for (int i = 0; i < 2; ++i){
            int gr = m0 + rowiA[i];
            int gk = k0 + ciA[i] * 8;
            ra[i][0] = (f32x4){0,0,0,0};
            ra[i][1] = (f32x4){0,0,0,0};
            if (gr < M){
                const float* ap = A0 + (size_t)gr * KACT + gk;
                if (gk + 8 <= KACT){
                    ra[i][0] = *(const f32x4*)ap;
                    ra[i][1] = *(const f32x4*)(ap + 4);
                } else {
                    #pragma unroll
                    for (int j = 0; j < 8; ++j)
                        if (gk + j < KACT) ra[i][j >> 2][j & 3] = ap[j];
                }
            }
        }
        #pragma unroll
        for (int i = 0; i < 4; ++i)
            gload16(B0 + (size_t)(n0 + rowiB[i]) * KT + k0 + ciB[i] * 8,
                    &ldsB[bb][(i * 128 + wid * 64) * 8]);
    };
    auto stage_writeA = [&](int s){
        int bb = s & 1;
        #pragma unroll
        for (int i = 0; i < 2; ++i){
            short8 v;
            #pragma unroll
            for (int j = 0; j < 8; ++j) v[j] = f2bf(ra[i][j >> 2][j & 3]);
            *(short8*)&ldsA[bb][(i * 128 + t) * 8] = v;
        }
    };
    auto compute = [&](int s){
        int bb = s & 1;
        short8 af[4], bfr[4];
        #pragma unroll
        for (int f = 0; f < 4; ++f){
            int rowA = f * 16 + lr;
            af[f] = *(const short8*)((const char*)&ldsA[bb][0] + rowA * 64 + ((lg ^ ((rowA >> 1) & 3)) << 4));
            int rowB = wn + f * 16 + lr;
            bfr[f] = *(const short8*)((const char*)&ldsB[bb][0] + rowB * 64 + ((lg ^ ((rowB >> 1) & 3)) << 4));
        }
        #pragma unroll
        for (int i = 0; i < 4; ++i)
            #pragma unroll
            for (int j = 0; j < 4; ++j)
                acc[i][j] = __builtin_amdgcn_mfma_f32_16x16x32_bf16(af[i], bfr[j], acc[i][j], 0, 0, 0);
    };
    stage_load(0);
    stage_writeA(0);
    __syncthreads();
    for (int s = 0; s < NSTEPS; ++s){
        if (s + 1 < NSTEPS) stage_load(s + 1);
        compute(s);
        if (s + 1 < NSTEPS) stage_writeA(s + 1);
        __syncthreads();
    }
    #pragma unroll
    for (int i = 0; i < 4; ++i){
        #pragma unroll
        for (int r2 = 0; r2 < 4; ++r2){
            int gr = m0 + i * 16 + lg * 4 + r2;
            if (gr >= M) continue;
            #pragma unroll
            for (int j = 0; j < 4; ++j){
                int gc = n0 + wn + j * 16 + lr;
                C16[(size_t)gr * N + gc] = f2bf(lrelu_f(acc[i][j][r2]));
            }
        }
    }
}

// ---------------- fp32 tiled GEMM (final 512->100 only) ----------------

__global__ __launch_bounds__(256)
void gemm_kernel(const float* __restrict__ A, const float* __restrict__ B,
                 const float* __restrict__ bias, float* __restrict__ C,
                 int M, int N, int K){
    const int BM = 128, BN = 64, BK = 16;
    __shared__ float As[BK][BM];
    __shared__ float Bs[BK][BN];
    int m0 = blockIdx.y * BM, n0 = blockIdx.x * BN;
    int t = threadIdx.x;
    int tx = t & 15, ty = t >> 4;
    float acc[8][4] = {};
    for (int k0 = 0; k0 < K; k0 += BK){
        #pragma unroll
        for (int i = 0; i < 2; ++i){
            int idx = i * 256 + t;
            int row = idx >> 2, kg = idx & 3;
            float4 v = make_float4(0,0,0,0);
            int gr = m0 + row, gk = k0 + kg * 4;
            if (gr < M && gk + 4 <= K)
                v = *reinterpret_cast<const float4*>(A + (size_t)gr * K + gk);
            As[kg*4+0][row] = v.x; As[kg*4+1][row] = v.y;
            As[kg*4+2][row] = v.z; As[kg*4+3][row] = v.w;
        }
        {
            int row = t >> 4, cg = t & 15;
            int gk = k0 + row, col = n0 + cg * 4;
            float4 v = make_float4(0,0,0,0);
            if (gk < K){
                if (col + 4 <= N){
                    v = *reinterpret_cast<const float4*>(B + (size_t)gk * N + col);
                } else {
                    float tp[4] = {0,0,0,0};
                    #pragma unroll
                    for (int j = 0; j < 4; ++j) if (col + j < N) tp[j] = B[(size_t)gk * N + col + j];
                    v = make_float4(tp[0], tp[1], tp[2], tp[3]);
                }
            }
            *reinterpret_cast<float4*>(&Bs[row][cg*4]) = v;
        }
        __syncthreads();
        #pragma unroll
        for (int k = 0; k < BK; ++k){
            float a[8], b[4];
            #pragma unroll
            for (int r = 0; r < 8; ++r) a[r] = As[k][ty*8 + r];
            #pragma unroll
            for (int c = 0; c < 4; ++c) b[c] = Bs[k][tx*4 + c];
            #pragma unroll
            for (int r = 0; r < 8; ++r)
                #pragma unroll
                for (int c = 0; c < 4; ++c)
                    acc[r][c] = fmaf(a[r], b[c], acc[r][c]);
        }
        __syncthreads();
    }
    #pragma unroll
    for (int r = 0; r < 8; ++r){
        int gr = m0 + ty*8 + r;
        if (gr >= M) continue;
        #pragma unroll
        for (int c = 0; c < 4; ++c){
            int gc = n0 + tx*4 + c;
            if (gc >= N) continue;
            C[(size_t)gr * N + gc] = acc[r][c] + bias[gc];
        }
    }
}

// ---------------- pooling ----------------

template<int F32>
__global__ void score_kernel(const void* __restrict__ hep, const float* __restrict__ w,
                             float* __restrict__ score){
    int row = blockIdx.x * 4 + (threadIdx.x >> 6);
    int lane = threadIdx.x & 63;
    if (row >= NE) return;
    float s = 0.f;
    #pragma unroll
    for (int j = 0; j < 8; ++j){
        int idx = lane + j * 64;
        float x = F32 ? ((const float*)hep)[(size_t)row * HD + idx]
                      : bf2f(((const short*)hep)[(size_t)row * HD + idx]);
        s += x * w[idx];
    }
    #pragma unroll
    for (int off = 32; off > 0; off >>= 1) s += __shfl_down(s, off);
    if (lane == 0) score[row] = s;
}

template<int F32>
__global__ __launch_bounds__(256)
void pool_kernel(const void* __restrict__ hep, const void* __restrict__ hwp,
                 const float* __restrict__ score, const int* __restrict__ off,
                 const int* __restrict__ elist, float* __restrict__ outp){
    int dst = blockIdx.x * 4 + (threadIdx.x >> 6);
    int lane = threadIdx.x & 63;
    if (dst >= NW) return;
    int s0 = off[dst], s1 = off[dst + 1];
    float m = -INFINITY;
    for (int e = s0 + lane; e < s1; e += 64) m = fmaxf(m, score[elist[e]]);
    #pragma unroll
    for (int o = 1; o < 64; o <<= 1) m = fmaxf(m, __shfl_xor(m, o));
    float z = 0.f;
    for (int e = s0 + lane; e < s1; e += 64) z += expf(score[elist[e]] - m);
    #pragma unroll
    for (int o = 1; o < 64; o <<= 1) z += __shfl_xor(z, o);
    float zinv = 1.0f / fmaxf(z, 1e-12f);

    float acc[8] = {};
    int e = s0;
    for (; e + 4 <= s1; e += 4){
        int idx[4]; float at[4];
        #pragma unroll
        for (int u = 0; u < 4; ++u) idx[u] = elist[e + u];
        #pragma unroll
        for (int u = 0; u < 4; ++u) at[u] = expf(score[idx[u]] - m) * zinv;
        #pragma unroll
        for (int u = 0; u < 4; ++u){
            if (F32){
                f32x4 v0 = *(const f32x4*)((const float*)hep + (size_t)idx[u] * HD + lane * 8);
                f32x4 v1 = *(const f32x4*)((const float*)hep + (size_t)idx[u] * HD + lane * 8 + 4);
                #pragma unroll
                for (int k = 0; k < 4; ++k){ acc[k] += at[u] * v0[k]; acc[k+4] += at[u] * v1[k]; }
            } else {
                short8 v = *(const short8*)((const short*)hep + (size_t)idx[u] * HD + lane * 8);
                #pragma unroll
                for (int k = 0; k < 8; ++k) acc[k] += at[u] * bf2f(v[k]);
            }
        }
    }
    for (; e < s1; ++e){
        int src = elist[e];
        float at = expf(score[src] - m) * zinv;
        if (F32){
            f32x4 v0 = *(const f32x4*)((const float*)hep + (size_t)src * HD + lane * 8);
            f32x4 v1 = *(const f32x4*)((const float*)hep + (size_t)src * HD + lane * 8 + 4);
            #pragma unroll
            for (int k = 0; k < 4; ++k){ acc[k] += at * v0[k]; acc[k+4] += at * v1[k]; }
        } else {
            short8 v = *(const short8*)((const short*)hep + (size_t)src * HD + lane * 8);
            #pragma unroll
            for (int k = 0; k < 8; ++k) acc[k] += at * bf2f(v[k]);
        }
    }
    float hw[8];
    if (F32){
        f32x4 v0 = *(const f32x4*)((const float*)hwp + (size_t)dst * HD + lane * 8);
        f32x4 v1 = *(const f32x4*)((const float*)hwp + (size_t)dst * HD + lane * 8 + 4);
        #pragma unroll
        for (int k = 0; k < 4; ++k){ hw[k] = v0[k]; hw[k+4] = v1[k]; }
    } else {
        short8 v = *(const short8*)((const short*)hwp + (size_t)dst * HD + lane * 8);
        #pragma unroll
        for (int k = 0; k < 8; ++k) hw[k] = bf2f(v[k]);
    }
    f32x4 o0, o1;
    #pragma unroll
    for (int k = 0; k < 4; ++k){ o0[k] = hw[k] + LAM * acc[k]; o1[k] = hw[k+4] + LAM * acc[k+4]; }
    *(f32x4*)(outp + (size_t)dst * HD + lane * 8) = o0;
    *(f32x4*)(outp + (size_t)dst * HD + lane * 8 + 4) = o1;
}

// ---------------- host ----------------

extern "C" void kernel_launch(void* const* d_in, const int* in_sizes, int n_in,
                              void* d_out, int out_size, void* d_ws, size_t ws_size,
                              hipStream_t stream){
    const float* x_window = (const float*)d_in[0];
    const float* x_example= (const float*)d_in[1];
    const int*   e_near   = (const int*)d_in[2];
    const int*   e_close  = (const int*)d_in[3];
    const int*   e_refer  = (const int*)d_in[4];
    const float* W_win    = (const float*)d_in[5];
    const float* W_exp    = (const float*)d_in[6];
    const float* W_post   = (const float*)d_in[7];
    const float* Wl_near  = (const float*)d_in[9];
    const float* Wr_near  = (const float*)d_in[10];
    const float* b_near   = (const float*)d_in[11];
    const float* Wl_close = (const float*)d_in[12];
    const float* Wr_close = (const float*)d_in[13];
    const float* b_close  = (const float*)d_in[14];
    const float* Wl_refer = (const float*)d_in[15];
    const float* Wr_refer = (const float*)d_in[16];
    const float* b_refer  = (const float*)d_in[17];
    const float* w_pool   = (const float*)d_in[18];
    const float* W_lin    = (const float*)d_in[19];
    const float* b_lin    = (const float*)d_in[20];
    float* out = (float*)d_out;
    (void)in_sizes; (void)n_in; (void)out_size;

    char* w = (char*)d_ws;
    size_t o = 0;
    auto alloc = [&](size_t bytes)->char*{
        char* p = w + o;
        o += (bytes + 255) & ~(size_t)255;
        return p;
    };
    const size_t HBH = (size_t)ROWP * HD * 2;

    short* h16[2][2];
    h16[0][0] = (short*)alloc(HBH); h16[0][1] = (short*)alloc(HBH);
    h16[1][0] = (short*)alloc(HBH); h16[1][1] = (short*)alloc(HBH);
    short* aggA = (short*)alloc(HBH);
    short* aggB = (short*)alloc(HBH);
    float* hwf  = (float*)alloc((size_t)NW * HD * 4);
    short* xe16   = (short*)alloc((size_t)ROWP * 128 * 2);
    short* WwinT  = (short*)alloc((size_t)HD * 1952 * 2);
    short* WexpT  = (short*)alloc((size_t)HD * 128 * 2);
    short* WT     = (short*)alloc((size_t)21 * WHH * 2);
    short* WlnT = WT;
    short* WlrT = WT + 4 * WHH;
    short* WlcT = WT + 8 * WHH;
    short* WrcT = WT + 12 * WHH;
    short* WcbT = WT + 16 * WHH;
    short* WpostT = WT + 20 * WHH;
    float* bsum   = (float*)alloc((size_t)NL * HD * 4);
    float* score  = (float*)alloc((size_t)NE * 4);
    int* degcur = (int*)alloc((size_t)6 * 30000 * 4);
    int* deg_n = degcur, *deg_r = degcur + 30000, *deg_c = degcur + 60000;
    int* cur_n = degcur + 90000, *cur_r = degcur + 120000, *cur_c = degcur + 150000;
    int* off_n = (int*)alloc((size_t)(NW + 1) * 4);
    int* off_r = (int*)alloc((size_t)(NW + 1) * 4);
    int* off_c = (int*)alloc((size_t)(NE + 1) * 4);
    int* el_n  = (int*)alloc((size_t)EE * 4);
    int* el_r  = (int*)alloc((size_t)EE * 4);
    int* el_c  = (int*)alloc((size_t)EE * 4);

    const size_t XWB = (size_t)ROWP * 1952 * 2;
    const size_t HEB = (size_t)NE * HD * 4;
    bool haveXW16 = false, haveF32 = false;
    short* xw16 = nullptr; float* hef = nullptr;
    size_t rem = (ws_size > o) ? ws_size - o : 0;
    if (rem >= XWB + 256){
        char* p = alloc(XWB);
        xw16 = (short*)p; hef = (float*)p;
        haveXW16 = haveF32 = true;
    } else if (rem >= HEB + 256){
        hef = (float*)alloc(HEB);
        haveF32 = true;
    }

    const int* src_n = e_near;  const int* dst_n = e_near + EE;
    const int* src_c = e_close; const int* dst_c = e_close + EE;
    const int* src_r = e_refer; const int* dst_r = e_refer + EE;

    // ---- CSR build ----
    hipMemsetAsync(degcur, 0, (size_t)6 * 30000 * 4, stream);
    int eg = (EE + 255) / 256;
    hipLaunchKernelGGL(count_kernel, dim3(eg), dim3(256), 0, stream, dst_n, deg_n, EE);
    hipLaunchKernelGGL(count_kernel, dim3(eg), dim3(256), 0, stream, dst_r, deg_r, EE);
    hipLaunchKernelGGL(count_kernel, dim3(eg), dim3(256), 0, stream, dst_c, deg_c, EE);
    hipLaunchKernelGGL(scan3_kernel, dim3(3), dim3(1024), 0, stream,
                       deg_n, NW, off_n, deg_r, NW, off_r, deg_c, NE, off_c);
    hipLaunchKernelGGL(fill_kernel, dim3(eg), dim3(256), 0, stream, src_n, dst_n, cur_n, off_n, el_n, EE);
    hipLaunchKernelGGL(fill_kernel, dim3(eg), dim3(256), 0, stream, src_r, dst_r, cur_r, off_r, el_r, EE);
    hipLaunchKernelGGL(fill_kernel, dim3(eg), dim3(256), 0, stream, src_c, dst_c, cur_c, off_c, el_c, EE);

    // ---- conversions / transposes ----
    hipLaunchKernelGGL(transpose_bf_kernel, dim3(16, 61, 1), dim3(256), 0, stream,
                       W_win, WwinT, 1949, HD, 1952);
    hipLaunchKernelGGL(transpose_bf_kernel, dim3(16, 4, 1), dim3(256), 0, stream,
                       W_exp, WexpT, 100, HD, 128);
    hipLaunchKernelGGL(transpose_all_kernel, dim3(16, 16, 21), dim3(256), 0, stream,
                       Wl_near, Wl_refer, Wl_close, Wr_close, Wr_near, Wr_refer, W_post, WT);
    hipLaunchKernelGGL(addf_kernel, dim3((NL * HD + 255) / 256), dim3(256), 0, stream,
                       b_near, b_refer, bsum, NL * HD);
    hipLaunchKernelGGL(conv_xe_kernel, dim3((ROWP * 16 + 255) / 256), dim3(256), 0, stream,
                       x_example, xe16);
    if (haveXW16)
        hipLaunchKernelGGL(conv_xw_kernel, dim3((30000 * 244 + 255) / 256), dim3(256), 0, stream,
                           x_window, xw16);

    #define MGEMM(NP,KT,ACT,WF32, a0,a1,a2, b0,b1,b2, bp, c16, c32, Mv) \
        hipLaunchKernelGGL((mgemm_kernel<NP,KT,ACT,WF32>), \
            dim3(4 * (((Mv) + 63) / 64)), dim3(128), 0, stream, \
            a0, a1, a2, b0, b1, b2, bp, c16, c32, Mv)

    // ---- feature transforms ----
    MGEMM(1,128,1,0, xe16, nullptr, nullptr, WexpT, nullptr, nullptr,
          (const float*)nullptr, aggA, (float*)nullptr, NE);
    MGEMM(1,512,1,0, aggA, nullptr, nullptr, WpostT, nullptr, nullptr,
          (const float*)nullptr, h16[1][0], (float*)nullptr, NE);
    if (haveXW16){
        MGEMM(1,1952,1,0, xw16, nullptr, nullptr, WwinT, nullptr, nullptr,
              (const float*)nullptr, aggA, (float*)nullptr, NW);
    } else {
        hipLaunchKernelGGL(mgemm_af32_kernel, dim3(4 * ((NW + 63) / 64)), dim3(128), 0, stream,
                           x_window, WwinT, aggA, NW);
    }
    MGEMM(1,512,1,0, aggA, nullptr, nullptr, WpostT, nullptr, nullptr,
          (const float*)nullptr, h16[0][0], (float*)nullptr, NW);

    // ---- layers ----
    for (int l = 0; l < NL; ++l){
        int cur = l & 1, nxt = cur ^ 1;
        const short* wl_n = WlnT + (size_t)l * WHH;
        const short* wl_r = WlrT + (size_t)l * WHH;
        const short* wl_c = WlcT + (size_t)l * WHH;
        const short* wr_c = WrcT + (size_t)l * WHH;
        const short* wcb  = WcbT + (size_t)l * WHH;
        const float* bs   = bsum + (size_t)l * HD;
        const float* bc   = b_close + (size_t)l * HD;
        bool last = (l == NL - 1);

        hipLaunchKernelGGL(seg_mean16_kernel, dim3((NW + 3) / 4), dim3(256), 0, stream,
                           h16[0][cur], off_n, el_n, aggA, NW);
        hipLaunchKernelGGL(seg_mean16_kernel, dim3((NW + 3) / 4), dim3(256), 0, stream,
                           h16[1][cur], off_r, el_r, aggB, NW);
        if (last){
            MGEMM(3,512,2,1, aggA, aggB, h16[0][cur], wl_n, wl_r, wcb, bs, h16[0][nxt], hwf, NW);
        } else {
            MGEMM(3,512,2,0, aggA, aggB, h16[0][cur], wl_n, wl_r, wcb, bs, h16[0][nxt], (float*)nullptr, NW);
        }
        hipLaunchKernelGGL(seg_mean16_kernel, dim3((NE + 3) / 4), dim3(256), 0, stream,
                           h16[1][cur], off_c, el_c, aggA, NE);
        if (last && haveF32){
            MGEMM(2,512,1,1, aggA, h16[1][cur], nullptr, wl_c, wr_c, nullptr, bc, h16[1][nxt], hef, NE);
        } else {
            MGEMM(2,512,1,0, aggA, h16[1][cur], nullptr, wl_c, wr_c, nullptr, bc, h16[1][nxt], (float*)nullptr, NE);
        }
    }
    int fin = NL & 1;

    // ---- CSRA pooling ----
    if (haveF32){
        hipLaunchKernelGGL((score_kernel<1>), dim3((NE + 3) / 4), dim3(256), 0, stream,
                           (const void*)hef, w_pool, score);
        hipLaunchKernelGGL((pool_kernel<1>), dim3((NW + 3) / 4), dim3(256), 0, stream,
                           (const void*)hef, (const void*)hwf, score, off_r, el_r, hwf);
    } else {
        hipLaunchKernelGGL((score_kernel<0>), dim3((NE + 3) / 4), dim3(256), 0, stream,
                           (const void*)h16[1][fin], w_pool, score);
        hipLaunchKernelGGL((pool_kernel<0>), dim3((NW + 3) / 4), dim3(256), 0, stream,
                           (const void*)h16[1][fin], (const void*)hwf, score, off_r, el_r, hwf);
    }

    // ---- final linear (fp32) ----
    hipLaunchKernelGGL(gemm_kernel, dim3(2, (NW + 127) / 128), dim3(256), 0, stream,
                       hwf, W_lin, b_lin, out, NW, 100, HD);
    #undef MGEMM
}

// Round 6
// 1860.845 us; speedup vs baseline: 4.4428x; 1.3359x over previous
//
#include <hip/hip_runtime.h>
#include <hip/hip_bf16.h>
#include <cstdint>
#include <cstddef>

#define NW 30000
#define NE 30000
#define EE 480000
#define HD 512
#define NL 4
#define SLOPE 0.2f
#define LAM 0.5f
#define ROWP 30080  // rows padded to multiple of 128
#define MT 235      // m-tiles per 30080-row matrix (128-row tiles)
#define WHH ((size_t)HD * HD)

typedef short short8 __attribute__((ext_vector_type(8)));
typedef float f32x4 __attribute__((ext_vector_type(4)));

static __device__ __forceinline__ float lrelu_f(float x){
    return fmaxf(x, 0.f) + SLOPE * fminf(x, 0.f);
}
static __device__ __forceinline__ short f2bf(float f){
    uint32_t u = __builtin_bit_cast(uint32_t, f);
    u += 0x7FFFu + ((u >> 16) & 1u);
    return (short)(u >> 16);
}
static __device__ __forceinline__ float bf2f(short s){
    uint32_t u = ((uint32_t)(uint16_t)s) << 16;
    return __builtin_bit_cast(float, u);
}

typedef const __attribute__((address_space(1))) void* gas_t;
typedef __attribute__((address_space(3))) void* las_t;
static __device__ __forceinline__ void gload16(const void* g, void* l){
    __builtin_amdgcn_global_load_lds((gas_t)g, (las_t)l, 16, 0, 0);
}

// ---------------- CSR build ----------------

__global__ void count_kernel(const int* __restrict__ dst, int* __restrict__ deg, int E){
    int e = blockIdx.x * 256 + threadIdx.x;
    if (e < E) atomicAdd(&deg[dst[e]], 1);
}

__global__ void scan3_kernel(const int* d0, int n0, int* o0,
                             const int* d1, int n1, int* o1,
                             const int* d2, int n2, int* o2){
    const int* deg; int n; int* off;
    if (blockIdx.x == 0){ deg=d0; n=n0; off=o0; }
    else if (blockIdx.x == 1){ deg=d1; n=n1; off=o1; }
    else { deg=d2; n=n2; off=o2; }
    __shared__ int tmp[1024];
    int t = threadIdx.x;
    int carry = 0;
    if (t == 0) off[0] = 0;
    for (int base = 0; base < n; base += 1024){
        int v = (base + t < n) ? deg[base + t] : 0;
        tmp[t] = v; __syncthreads();
        for (int d = 1; d < 1024; d <<= 1){
            int add = (t >= d) ? tmp[t - d] : 0;
            __syncthreads();
            tmp[t] += add;
            __syncthreads();
        }
        if (base + t < n) off[base + t + 1] = tmp[t] + carry;
        carry += tmp[1023];
        __syncthreads();
    }
}

__global__ void fill_kernel(const int* __restrict__ src, const int* __restrict__ dst,
                            int* __restrict__ cur, const int* __restrict__ off,
                            int* __restrict__ elist, int E){
    int e = blockIdx.x * 256 + threadIdx.x;
    if (e < E){
        int d = dst[e];
        int p = atomicAdd(&cur[d], 1);
        elist[off[d] + p] = src[e];
    }
}

// ---------------- weight transpose fp32[K,N] -> bf16[N,Kpad] ----------------

__global__ __launch_bounds__(256)
void transpose_bf_kernel(const float* __restrict__ in, short* __restrict__ out,
                         int K, int N, int Kpad){
    __shared__ float tile[32][33];
    int kbase = blockIdx.y * 32, nbase = blockIdx.x * 32;
    int tx = threadIdx.x & 31, ty = threadIdx.x >> 5;
    #pragma unroll
    for (int r = 0; r < 4; ++r){
        int k = kbase + ty + r * 8;
        float v = 0.f;
        if (k < K) v = in[(size_t)k * N + nbase + tx];
        tile[ty + r * 8][tx] = v;
    }
    __syncthreads();
    #pragma unroll
    for (int r = 0; r < 4; ++r){
        int n = nbase + ty + r * 8;
        int k = kbase + tx;
        if (k < Kpad) out[(size_t)n * Kpad + k] = f2bf(tile[tx][ty + r * 8]);
    }
}

// ---------------- all 21 HxH transposes in one dispatch ----------------

__global__ __launch_bounds__(256)
void transpose_all_kernel(const float* __restrict__ Wln, const float* __restrict__ Wlr,
                          const float* __restrict__ Wlc, const float* __restrict__ Wrc,
                          const float* __restrict__ Wrn, const float* __restrict__ Wrr,
                          const float* __restrict__ Wpost, short* __restrict__ outT){
    __shared__ float tile[32][33];
    int z = blockIdx.z;
    const float* a; const float* b = nullptr;
    if (z < 4) a = Wln + (size_t)z * WHH;
    else if (z < 8) a = Wlr + (size_t)(z - 4) * WHH;
    else if (z < 12) a = Wlc + (size_t)(z - 8) * WHH;
    else if (z < 16) a = Wrc + (size_t)(z - 12) * WHH;
    else if (z < 20){ a = Wrn + (size_t)(z - 16) * WHH; b = Wrr + (size_t)(z - 16) * WHH; }
    else a = Wpost;
    short* outp = outT + (size_t)z * WHH;
    int kbase = blockIdx.y * 32, nbase = blockIdx.x * 32;
    int tx = threadIdx.x & 31, ty = threadIdx.x >> 5;
    #pragma unroll
    for (int r = 0; r < 4; ++r){
        int k = kbase + ty + r * 8;
        float v = a[(size_t)k * HD + nbase + tx];
        if (b) v += b[(size_t)k * HD + nbase + tx];
        tile[ty + r * 8][tx] = v;
    }
    __syncthreads();
    #pragma unroll
    for (int r = 0; r < 4; ++r){
        int n = nbase + ty + r * 8;
        outp[(size_t)n * HD + kbase + tx] = f2bf(tile[tx][ty + r * 8]);
    }
}

__global__ void addf_kernel(const float* __restrict__ a, const float* __restrict__ b,
                            float* __restrict__ o, int n){
    int i = blockIdx.x * 256 + threadIdx.x;
    if (i < n) o[i] = a[i] + b[i];
}

// ---------------- x_window fp32 -> bf16 [ROWP][1952] ----------------

__global__ __launch_bounds__(256)
void conv_xw_kernel(const float* __restrict__ x, short* __restrict__ o){
    int idx = blockIdx.x * 256 + threadIdx.x;
    if (idx >= 30000 * 244) return;
    int row = idx / 244, c8 = idx - row * 244;
    int base = c8 * 8;
    short8 v = {};
    const float* xp = x + (size_t)row * 1949 + base;
    if (base + 8 <= 1949){
        f32x4 a = *(const f32x4*)xp;
        f32x4 bq = *(const f32x4*)(xp + 4);
        #pragma unroll
        for (int j = 0; j < 4; ++j){ v[j] = f2bf(a[j]); v[j + 4] = f2bf(bq[j]); }
    } else {
        #pragma unroll
        for (int j = 0; j < 8; ++j) if (base + j < 1949) v[j] = f2bf(xp[j]);
    }
    *(short8*)(o + (size_t)row * 1952 + base) = v;
}

// ---------------- x_example fp32[30000][100] -> bf16 [ROWP][128] ----------------

__global__ __launch_bounds__(256)
void conv_xe_kernel(const float* __restrict__ x, short* __restrict__ o){
    int idx = blockIdx.x * 256 + threadIdx.x;
    if (idx >= ROWP * 16) return;
    int row = idx >> 4, c8 = idx & 15;
    int base = c8 * 8;
    short8 v = {};
    if (row < 30000){
        const float* xp = x + (size_t)row * 100 + base;
        #pragma unroll
        for (int j = 0; j < 8; ++j) if (base + j < 100) v[j] = f2bf(xp[j]);
    }
    *(short8*)(o + (size_t)row * 128 + base) = v;
}

// ---------------- combined 3-relation segment mean ----------------
// slot: [0,NW) near from hw -> aggA; [NW,2NW) refer from he -> aggB; [2NW,3NW) close from he -> aggC

__global__ __launch_bounds__(256)
void seg_mean3_kernel(const short* __restrict__ hw, const short* __restrict__ he,
                      const int* __restrict__ off_n, const int* __restrict__ el_n,
                      const int* __restrict__ off_r, const int* __restrict__ el_r,
                      const int* __restrict__ off_c, const int* __restrict__ el_c,
                      short* __restrict__ aggA, short* __restrict__ aggB, short* __restrict__ aggC){
    int slot = blockIdx.x * 4 + (threadIdx.x >> 6);
    int lane = threadIdx.x & 63;
    if (slot >= 3 * NW) return;
    int seg = slot / NW;
    int dst = slot - seg * NW;
    const short* h; const int* off; const int* el; short* out;
    if (seg == 0){ h = hw; off = off_n; el = el_n; out = aggA; }
    else if (seg == 1){ h = he; off = off_r; el = el_r; out = aggB; }
    else { h = he; off = off_c; el = el_c; out = aggC; }
    int s0 = off[dst], s1 = off[dst + 1];
    float acc[8] = {};
    int e = s0;
    for (; e + 8 <= s1; e += 8){
        int idx[8];
        #pragma unroll
        for (int u = 0; u < 8; ++u) idx[u] = el[e + u];
        short8 v[8];
        #pragma unroll
        for (int u = 0; u < 8; ++u) v[u] = *(const short8*)(h + (size_t)idx[u] * HD + lane * 8);
        #pragma unroll
        for (int u = 0; u < 8; ++u)
            #pragma unroll
            for (int j = 0; j < 8; ++j) acc[j] += bf2f(v[u][j]);
    }
    for (; e < s1; ++e){
        short8 v = *(const short8*)(h + (size_t)el[e] * HD + lane * 8);
        #pragma unroll
        for (int j = 0; j < 8; ++j) acc[j] += bf2f(v[j]);
    }
    float inv = (s1 > s0) ? 1.0f / (float)(s1 - s0) : 0.0f;
    short8 o8;
    #pragma unroll
    for (int j = 0; j < 8; ++j) o8[j] = f2bf(acc[j] * inv);
    *(short8*)(out + (size_t)dst * HD + lane * 8) = o8;
}

// ---------------- routed dual multi-GEMM, 128x128 tile, 256 threads ----------------
// C_d = sum_p A_d[p] @ B_d[p]^T' (+bias)(act). A [*, kt] bf16 row-padded; B [512][kt] bf16.
// DUAL=1: m-tiles parity-interleaved between desc0/desc1 (equal tile counts, XCD-balanced).
// Counted-vmcnt pipeline: stage(s+1) -> vmcnt(4) -> barrier -> MFMA -> lgkmcnt(0) -> barrier.

template<int DUAL>
__global__ __launch_bounds__(256)
void mgemm2_kernel(
    const short* __restrict__ a00, const short* __restrict__ a01, const short* __restrict__ a02,
    const short* __restrict__ b00, const short* __restrict__ b01, const short* __restrict__ b02,
    const float* __restrict__ bias0, short* __restrict__ c160, float* __restrict__ c320,
    int np0, int kt0, int act0,
    const short* __restrict__ a10, const short* __restrict__ a11, const short* __restrict__ a12,
    const short* __restrict__ b10, const short* __restrict__ b11, const short* __restrict__ b12,
    const float* __restrict__ bias1, short* __restrict__ c161, float* __restrict__ c321,
    int np1, int kt1, int act1,
    int mreal){
    __shared__ short lds[16384];          // A: [0,8192) = 2 bufs x 128x32; B: [8192,16384)
    short* ldsA = lds;
    short* ldsB = lds + 8192;

    int nwg = gridDim.x, orig = blockIdx.x;
    int q = nwg >> 3, r = nwg & 7;
    int xcd = orig & 7, lid = orig >> 3;
    int logical = (xcd < r ? xcd * (q + 1) : r * (q + 1) + (xcd - r) * q) + lid;
    int mtile = logical >> 2, nc = logical & 3;
    int dsel, ml;
    if (DUAL){ dsel = mtile & 1; ml = mtile >> 1; } else { dsel = 0; ml = mtile; }

    const short* A0 = dsel ? a10 : a00;
    const short* A1 = dsel ? a11 : a01;
    const short* A2 = dsel ? a12 : a02;
    const short* B0 = dsel ? b10 : b00;
    const short* B1 = dsel ? b11 : b01;
    const short* B2 = dsel ? b12 : b02;
    const float* bias = dsel ? bias1 : bias0;
    short* C16 = dsel ? c161 : c160;
    float* C32 = dsel ? c321 : c320;
    const int np = dsel ? np1 : np0;
    const int kt = dsel ? kt1 : kt0;
    const int act = dsel ? act1 : act0;

    const int row0 = ml * 128, n0 = nc * 128;
    const int t = threadIdx.x, wid = t >> 6, lane = t & 63;
    const int wm = (wid >> 1) * 64, wn = (wid & 1) * 64;
    const int lg = lane >> 4, lr = lane & 15;
    f32x4 acc[4][4] = {};

    int rowi[2], ci[2];
    #pragma unroll
    for (int i = 0; i < 2; ++i){
        int sl = i * 256 + t;
        rowi[i] = sl >> 2;
        ci[i] = (sl & 3) ^ ((rowi[i] >> 1) & 3);
    }
    const int kpt = kt >> 5;
    const int nsteps = np * kpt;

    const short* Acur = A0;
    const short* Bcur = B0;
    int sk = 0, sp = 0, sbuf = 0;

    auto stage = [&](){
        int k0 = sk * 32;
        #pragma unroll
        for (int i = 0; i < 2; ++i){
            int ao = (row0 + rowi[i]) * kt + k0 + ci[i] * 8;
            gload16(Acur + ao, &ldsA[sbuf * 4096 + (i * 256 + wid * 64) * 8]);
        }
        #pragma unroll
        for (int i = 0; i < 2; ++i){
            int bo = (n0 + rowi[i]) * kt + k0 + ci[i] * 8;
            gload16(Bcur + bo, &ldsB[sbuf * 4096 + (i * 256 + wid * 64) * 8]);
        }
        sbuf ^= 1;
        if (++sk == kpt){
            sk = 0; ++sp;
            Acur = (sp == 1) ? A1 : A2;
            Bcur = (sp == 1) ? B1 : B2;
        }
    };
    auto compute = [&](int bb){
        const char* baseA = (const char*)&ldsA[bb * 4096];
        const char* baseB = (const char*)&ldsB[bb * 4096];
        short8 af[4], bfr[4];
        #pragma unroll
        for (int f = 0; f < 4; ++f){
            int rowA = wm + f * 16 + lr;
            af[f] = *(const short8*)(baseA + rowA * 64 + ((lg ^ ((rowA >> 1) & 3)) << 4));
            int rowB = wn + f * 16 + lr;
            bfr[f] = *(const short8*)(baseB + rowB * 64 + ((lg ^ ((rowB >> 1) & 3)) << 4));
        }
        #pragma unroll
        for (int i = 0; i < 4; ++i)
            #pragma unroll
            for (int j = 0; j < 4; ++j)
                acc[i][j] = __builtin_amdgcn_mfma_f32_16x16x32_bf16(af[i], bfr[j], acc[i][j], 0, 0, 0);
    };

    stage();
    for (int s = 0; s < nsteps; ++s){
        if (s + 1 < nsteps){
            stage();
            asm volatile("s_waitcnt vmcnt(4)" ::: "memory");
        } else {
            asm volatile("s_waitcnt vmcnt(0)" ::: "memory");
        }
        __builtin_amdgcn_s_barrier();
        __builtin_amdgcn_sched_barrier(0);
        compute(s & 1);
        asm volatile("s_waitcnt lgkmcnt(0)" ::: "memory");
        __builtin_amdgcn_sched_barrier(0);
        __builtin_amdgcn_s_barrier();
    }

    float bv[4];
    #pragma unroll
    for (int f = 0; f < 4; ++f) bv[f] = bias ? bias[n0 + wn + f * 16 + lr] : 0.f;
    #pragma unroll
    for (int i = 0; i < 4; ++i){
        #pragma unroll
        for (int r2 = 0; r2 < 4; ++r2){
            int gr = row0 + wm + i * 16 + lg * 4 + r2;
            #pragma unroll
            for (int j = 0; j < 4; ++j){
                int gc = n0 + wn + j * 16 + lr;
                float v = acc[i][j][r2] + bv[j];
                if (act == 2) v *= 0.5f;
                if (act) v = lrelu_f(v);
                C16[(size_t)gr * HD + gc] = f2bf(v);
                if (C32 && gr < mreal) C32[(size_t)gr * HD + gc] = v;
            }
        }
    }
}

// ---------------- AF32 fallback (x_window proj only, if ws too small) ----------------

__global__ __launch_bounds__(128)
void mgemm_af32_kernel(const float* __restrict__ A0, const short* __restrict__ B0,
                       short* __restrict__ C16, int M){
    constexpr int KT = 1952, KACT = 1949, KPT = KT / 32, NSTEPS = KPT, N = 512;
    __shared__ short ldsA[2][2048];
    __shared__ short ldsB[2][4096];
    int nwg = gridDim.x;
    int orig = blockIdx.x;
    int q = nwg >> 3, r = nwg & 7;
    int xcd = orig & 7, lid = orig >> 3;
    int logical = (xcd < r ? xcd * (q + 1) : r * (q + 1) + (xcd - r) * q) + lid;
    const int m0 = (logical >> 2) * 64, n0 = (logical & 3) * 128;
    const int t = threadIdx.x, wid = t >> 6, lane = t & 63;
    const int wn = wid * 64;
    const int lg = lane >> 4, lr = lane & 15;
    f32x4 acc[4][4] = {};
    int rowiA[2], ciA[2];
    #pragma unroll
    for (int i = 0; i < 2; ++i){
        int sl = i * 128 + t;
        rowiA[i] = sl >> 2;
        ciA[i] = (sl & 3) ^ ((rowiA[i] >> 1) & 3);
    }
    int rowiB[4], ciB[4];
    #pragma unroll
    for (int i = 0; i < 4; ++i){
        int sl = i * 128 + t;
        rowiB[i] = sl >> 2;
        ciB[i] = (sl & 3) ^ ((rowiB[i] >> 1) & 3);
    }
    f32x4 ra[2][2];
    auto stage_load = [&](int s){
        int k0 = s * 32;
        int bb = s & 1;
        #pragma unroll
        for (int i = 0; i < 2; ++i){
            int gr = m0 + rowiA[i];
            int gk = k0 + ciA[i] * 8;
            ra[i][0] = (f32x4){0,0,0,0};
            ra[i][1] = (f32x4){0,0,0,0};
            if (gr < M){
                const float* ap = A0 + (size_t)gr * KACT + gk;
                if (gk + 8 <= KACT){
                    ra[i][0] = *(const f32x4*)ap;
                    ra[i][1] = *(const f32x4*)(ap + 4);
                } else {
                    #pragma unroll
                    for (int j = 0; j < 8; ++j)
                        if (gk + j < KACT) ra[i][j >> 2][j & 3] = ap[j];
                }
            }
        }
        #pragma unroll
        for (int i = 0; i < 4; ++i)
            gload16(B0 + (size_t)(n0 + rowiB[i]) * KT + k0 + ciB[i] * 8,
                    &ldsB[bb][(i * 128 + wid * 64) * 8]);
    };
    auto stage_writeA = [&](int s){
        int bb = s & 1;
        #pragma unroll
        for (int i = 0; i < 2; ++i){
            short8 v;
            #pragma unroll
            for (int j = 0; j < 8; ++j) v[j] = f2bf(ra[i][j >> 2][j & 3]);
            *(short8*)&ldsA[bb][(i * 128 + t) * 8] = v;
        }
    };
    auto compute = [&](int s){
        int bb = s & 1;
        short8 af[4], bfr[4];
        #pragma unroll
        for (int f = 0; f < 4; ++f){
            int rowA = f * 16 + lr;
            af[f] = *(const short8*)((const char*)&ldsA[bb][0] + rowA * 64 + ((lg ^ ((rowA >> 1) & 3)) << 4));
            int rowB = wn + f * 16 + lr;
            bfr[f] = *(const short8*)((const char*)&ldsB[bb][0] + rowB * 64 + ((lg ^ ((rowB >> 1) & 3)) << 4));
        }
        #pragma unroll
        for (int i = 0; i < 4; ++i)
            #pragma unroll
            for (int j = 0; j < 4; ++j)
                acc[i][j] = __builtin_amdgcn_mfma_f32_16x16x32_bf16(af[i], bfr[j], acc[i][j], 0, 0, 0);
    };
    stage_load(0);
    stage_writeA(0);
    __syncthreads();
    for (int s = 0; s < NSTEPS; ++s){
        if (s + 1 < NSTEPS) stage_load(s + 1);
        compute(s);
        if (s + 1 < NSTEPS) stage_writeA(s + 1);
        __syncthreads();
    }
    #pragma unroll
    for (int i = 0; i < 4; ++i){
        #pragma unroll
        for (int r2 = 0; r2 < 4; ++r2){
            int gr = m0 + i * 16 + lg * 4 + r2;
            if (gr >= M) continue;
            #pragma unroll
            for (int j = 0; j < 4; ++j){
                int gc = n0 + wn + j * 16 + lr;
                C16[(size_t)gr * N + gc] = f2bf(lrelu_f(acc[i][j][r2]));
            }
        }
    }
}

// ---------------- fp32 tiled GEMM (final 512->100 only) ----------------

__global__ __launch_bounds__(256)
void gemm_kernel(const float* __restrict__ A, const float* __restrict__ B,
                 const float* __restrict__ bias, float* __restrict__ C,
                 int M, int N, int K){
    const int BM = 128, BN = 64, BK = 16;
    __shared__ float As[BK][BM];
    __shared__ float Bs[BK][BN];
    int m0 = blockIdx.y * BM, n0 = blockIdx.x * BN;
    int t = threadIdx.x;
    int tx = t & 15, ty = t >> 4;
    float acc[8][4] = {};
    for (int k0 = 0; k0 < K; k0 += BK){
        #pragma unroll
        for (int i = 0; i < 2; ++i){
            int idx = i * 256 + t;
            int row = idx >> 2, kg = idx & 3;
            float4 v = make_float4(0,0,0,0);
            int gr = m0 + row, gk = k0 + kg * 4;
            if (gr < M && gk + 4 <= K)
                v = *reinterpret_cast<const float4*>(A + (size_t)gr * K + gk);
            As[kg*4+0][row] = v.x; As[kg*4+1][row] = v.y;
            As[kg*4+2][row] = v.z; As[kg*4+3][row] = v.w;
        }
        {
            int row = t >> 4, cg = t & 15;
            int gk = k0 + row, col = n0 + cg * 4;
            float4 v = make_float4(0,0,0,0);
            if (gk < K){
                if (col + 4 <= N){
                    v = *reinterpret_cast<const float4*>(B + (size_t)gk * N + col);
                } else {
                    float tp[4] = {0,0,0,0};
                    #pragma unroll
                    for (int j = 0; j < 4; ++j) if (col + j < N) tp[j] = B[(size_t)gk * N + col + j];
                    v = make_float4(tp[0], tp[1], tp[2], tp[3]);
                }
            }
            *reinterpret_cast<float4*>(&Bs[row][cg*4]) = v;
        }
        __syncthreads();
        #pragma unroll
        for (int k = 0; k < BK; ++k){
            float a[8], b[4];
            #pragma unroll
            for (int r = 0; r < 8; ++r) a[r] = As[k][ty*8 + r];
            #pragma unroll
            for (int c = 0; c < 4; ++c) b[c] = Bs[k][tx*4 + c];
            #pragma unroll
            for (int r = 0; r < 8; ++r)
                #pragma unroll
                for (int c = 0; c < 4; ++c)
                    acc[r][c] = fmaf(a[r], b[c], acc[r][c]);
        }
        __syncthreads();
    }
    #pragma unroll
    for (int r = 0; r < 8; ++r){
        int gr = m0 + ty*8 + r;
        if (gr >= M) continue;
        #pragma unroll
        for (int c = 0; c < 4; ++c){
            int gc = n0 + tx*4 + c;
            if (gc >= N) continue;
            C[(size_t)gr * N + gc] = acc[r][c] + bias[gc];
        }
    }
}

// ---------------- pooling ----------------

template<int F32>
__global__ void score_kernel(const void* __restrict__ hep, const float* __restrict__ w,
                             float* __restrict__ score){
    int row = blockIdx.x * 4 + (threadIdx.x >> 6);
    int lane = threadIdx.x & 63;
    if (row >= NE) return;
    float s = 0.f;
    #pragma unroll
    for (int j = 0; j < 8; ++j){
        int idx = lane + j * 64;
        float x = F32 ? ((const float*)hep)[(size_t)row * HD + idx]
                      : bf2f(((const short*)hep)[(size_t)row * HD + idx]);
        s += x * w[idx];
    }
    #pragma unroll
    for (int off = 32; off > 0; off >>= 1) s += __shfl_down(s, off);
    if (lane == 0) score[row] = s;
}

template<int F32>
__global__ __launch_bounds__(256)
void pool_kernel(const void* __restrict__ hep, const void* __restrict__ hwp,
                 const float* __restrict__ score, const int* __restrict__ off,
                 const int* __restrict__ elist, float* __restrict__ outp){
    int dst = blockIdx.x * 4 + (threadIdx.x >> 6);
    int lane = threadIdx.x & 63;
    if (dst >= NW) return;
    int s0 = off[dst], s1 = off[dst + 1];
    float m = -INFINITY;
    for (int e = s0 + lane; e < s1; e += 64) m = fmaxf(m, score[elist[e]]);
    #pragma unroll
    for (int o = 1; o < 64; o <<= 1) m = fmaxf(m, __shfl_xor(m, o));
    float z = 0.f;
    for (int e = s0 + lane; e < s1; e += 64) z += expf(score[elist[e]] - m);
    #pragma unroll
    for (int o = 1; o < 64; o <<= 1) z += __shfl_xor(z, o);
    float zinv = 1.0f / fmaxf(z, 1e-12f);

    float acc[8] = {};
    int e = s0;
    for (; e + 4 <= s1; e += 4){
        int idx[4]; float at[4];
        #pragma unroll
        for (int u = 0; u < 4; ++u) idx[u] = elist[e + u];
        #pragma unroll
        for (int u = 0; u < 4; ++u) at[u] = expf(score[idx[u]] - m) * zinv;
        #pragma unroll
        for (int u = 0; u < 4; ++u){
            if (F32){
                f32x4 v0 = *(const f32x4*)((const float*)hep + (size_t)idx[u] * HD + lane * 8);
                f32x4 v1 = *(const f32x4*)((const float*)hep + (size_t)idx[u] * HD + lane * 8 + 4);
                #pragma unroll
                for (int k = 0; k < 4; ++k){ acc[k] += at[u] * v0[k]; acc[k+4] += at[u] * v1[k]; }
            } else {
                short8 v = *(const short8*)((const short*)hep + (size_t)idx[u] * HD + lane * 8);
                #pragma unroll
                for (int k = 0; k < 8; ++k) acc[k] += at[u] * bf2f(v[k]);
            }
        }
    }
    for (; e < s1; ++e){
        int src = elist[e];
        float at = expf(score[src] - m) * zinv;
        if (F32){
            f32x4 v0 = *(const f32x4*)((const float*)hep + (size_t)src * HD + lane * 8);
            f32x4 v1 = *(const f32x4*)((const float*)hep + (size_t)src * HD + lane * 8 + 4);
            #pragma unroll
            for (int k = 0; k < 4; ++k){ acc[k] += at * v0[k]; acc[k+4] += at * v1[k]; }
        } else {
            short8 v = *(const short8*)((const short*)hep + (size_t)src * HD + lane * 8);
            #pragma unroll
            for (int k = 0; k < 8; ++k) acc[k] += at * bf2f(v[k]);
        }
    }
    float hw[8];
    if (F32){
        f32x4 v0 = *(const f32x4*)((const float*)hwp + (size_t)dst * HD + lane * 8);
        f32x4 v1 = *(const f32x4*)((const float*)hwp + (size_t)dst * HD + lane * 8 + 4);
        #pragma unroll
        for (int k = 0; k < 4; ++k){ hw[k] = v0[k]; hw[k+4] = v1[k]; }
    } else {
        short8 v = *(const short8*)((const short*)hwp + (size_t)dst * HD + lane * 8);
        #pragma unroll
        for (int k = 0; k < 8; ++k) hw[k] = bf2f(v[k]);
    }
    f32x4 o0, o1;
    #pragma unroll
    for (int k = 0; k < 4; ++k){ o0[k] = hw[k] + LAM * acc[k]; o1[k] = hw[k+4] + LAM * acc[k+4]; }
    *(f32x4*)(outp + (size_t)dst * HD + lane * 8) = o0;
    *(f32x4*)(outp + (size_t)dst * HD + lane * 8 + 4) = o1;
}

// ---------------- host ----------------

extern "C" void kernel_launch(void* const* d_in, const int* in_sizes, int n_in,
                              void* d_out, int out_size, void* d_ws, size_t ws_size,
                              hipStream_t stream){
    const float* x_window = (const float*)d_in[0];
    const float* x_example= (const float*)d_in[1];
    const int*   e_near   = (const int*)d_in[2];
    const int*   e_close  = (const int*)d_in[3];
    const int*   e_refer  = (const int*)d_in[4];
    const float* W_win    = (const float*)d_in[5];
    const float* W_exp    = (const float*)d_in[6];
    const float* W_post   = (const float*)d_in[7];
    const float* Wl_near  = (const float*)d_in[9];
    const float* Wr_near  = (const float*)d_in[10];
    const float* b_near   = (const float*)d_in[11];
    const float* Wl_close = (const float*)d_in[12];
    const float* Wr_close = (const float*)d_in[13];
    const float* b_close  = (const float*)d_in[14];
    const float* Wl_refer = (const float*)d_in[15];
    const float* Wr_refer = (const float*)d_in[16];
    const float* b_refer  = (const float*)d_in[17];
    const float* w_pool   = (const float*)d_in[18];
    const float* W_lin    = (const float*)d_in[19];
    const float* b_lin    = (const float*)d_in[20];
    float* out = (float*)d_out;
    (void)in_sizes; (void)n_in; (void)out_size;

    char* w = (char*)d_ws;
    size_t o = 0;
    auto alloc = [&](size_t bytes)->char*{
        char* p = w + o;
        o += (bytes + 255) & ~(size_t)255;
        return p;
    };
    const size_t HBH = (size_t)ROWP * HD * 2;   // 30.8 MB, multiple of 256

    short* h16[2][2];
    h16[0][0] = (short*)alloc(HBH); h16[0][1] = (short*)alloc(HBH);
    h16[1][0] = (short*)alloc(HBH); h16[1][1] = (short*)alloc(HBH);
    short* aggA = (short*)alloc(HBH);   // near-mean / xe-proj out
    short* aggB = (short*)alloc(HBH);   // refer-mean / xw-proj out
    short* aggC = (short*)alloc(HBH);   // close-mean
    float* hwf  = (float*)alloc((size_t)NW * HD * 4);
    short* xe16   = (short*)alloc((size_t)ROWP * 128 * 2);
    short* WwinT  = (short*)alloc((size_t)HD * 1952 * 2);
    short* WexpT  = (short*)alloc((size_t)HD * 128 * 2);
    short* WT     = (short*)alloc((size_t)21 * WHH * 2);
    short* WlnT = WT;
    short* WlrT = WT + 4 * WHH;
    short* WlcT = WT + 8 * WHH;
    short* WrcT = WT + 12 * WHH;
    short* WcbT = WT + 16 * WHH;
    short* WpostT = WT + 20 * WHH;
    float* bsum   = (float*)alloc((size_t)NL * HD * 4);
    float* score  = (float*)alloc((size_t)NE * 4);
    int* degcur = (int*)alloc((size_t)6 * 30000 * 4);
    int* deg_n = degcur, *deg_r = degcur + 30000, *deg_c = degcur + 60000;
    int* cur_n = degcur + 90000, *cur_r = degcur + 120000, *cur_c = degcur + 150000;
    int* off_n = (int*)alloc((size_t)(NW + 1) * 4);
    int* off_r = (int*)alloc((size_t)(NW + 1) * 4);
    int* off_c = (int*)alloc((size_t)(NE + 1) * 4);
    int* el_n  = (int*)alloc((size_t)EE * 4);
    int* el_r  = (int*)alloc((size_t)EE * 4);
    int* el_c  = (int*)alloc((size_t)EE * 4);

    const size_t XWB = (size_t)ROWP * 1952 * 2;
    const size_t HEB = (size_t)NE * HD * 4;
    bool haveXW16 = false, haveF32 = false;
    short* xw16 = nullptr; float* hef = nullptr;
    size_t rem = (ws_size > o) ? ws_size - o : 0;
    if (rem >= XWB + 256){
        char* p = alloc(XWB);
        xw16 = (short*)p; hef = (float*)p;   // xw16 early-life, hef late-life
        haveXW16 = haveF32 = true;
    } else if (rem >= HEB + 256){
        hef = (float*)alloc(HEB);
        haveF32 = true;
    }

    const int* src_n = e_near;  const int* dst_n = e_near + EE;
    const int* src_c = e_close; const int* dst_c = e_close + EE;
    const int* src_r = e_refer; const int* dst_r = e_refer + EE;

    // ---- CSR build ----
    hipMemsetAsync(degcur, 0, (size_t)6 * 30000 * 4, stream);
    int eg = (EE + 255) / 256;
    hipLaunchKernelGGL(count_kernel, dim3(eg), dim3(256), 0, stream, dst_n, deg_n, EE);
    hipLaunchKernelGGL(count_kernel, dim3(eg), dim3(256), 0, stream, dst_r, deg_r, EE);
    hipLaunchKernelGGL(count_kernel, dim3(eg), dim3(256), 0, stream, dst_c, deg_c, EE);
    hipLaunchKernelGGL(scan3_kernel, dim3(3), dim3(1024), 0, stream,
                       deg_n, NW, off_n, deg_r, NW, off_r, deg_c, NE, off_c);
    hipLaunchKernelGGL(fill_kernel, dim3(eg), dim3(256), 0, stream, src_n, dst_n, cur_n, off_n, el_n, EE);
    hipLaunchKernelGGL(fill_kernel, dim3(eg), dim3(256), 0, stream, src_r, dst_r, cur_r, off_r, el_r, EE);
    hipLaunchKernelGGL(fill_kernel, dim3(eg), dim3(256), 0, stream, src_c, dst_c, cur_c, off_c, el_c, EE);

    // ---- conversions / transposes ----
    hipLaunchKernelGGL(transpose_bf_kernel, dim3(16, 61, 1), dim3(256), 0, stream,
                       W_win, WwinT, 1949, HD, 1952);
    hipLaunchKernelGGL(transpose_bf_kernel, dim3(16, 4, 1), dim3(256), 0, stream,
                       W_exp, WexpT, 100, HD, 128);
    hipLaunchKernelGGL(transpose_all_kernel, dim3(16, 16, 21), dim3(256), 0, stream,
                       Wl_near, Wl_refer, Wl_close, Wr_close, Wr_near, Wr_refer, W_post, WT);
    hipLaunchKernelGGL(addf_kernel, dim3((NL * HD + 255) / 256), dim3(256), 0, stream,
                       b_near, b_refer, bsum, NL * HD);
    hipLaunchKernelGGL(conv_xe_kernel, dim3((ROWP * 16 + 255) / 256), dim3(256), 0, stream,
                       x_example, xe16);
    if (haveXW16)
        hipLaunchKernelGGL(conv_xw_kernel, dim3((30000 * 244 + 255) / 256), dim3(256), 0, stream,
                           x_window, xw16);

    const short* z16 = xe16;          // harmless placeholder for unused panels
    const float* zf = nullptr;

    // ---- feature projections ----
    // xe-proj: aggA = lrelu(xe16 @ WexpT')
    hipLaunchKernelGGL((mgemm2_kernel<0>), dim3(MT * 4), dim3(256), 0, stream,
        xe16, z16, z16, WexpT, z16, z16, zf, aggA, (float*)nullptr, 1, 128, 1,
        z16, z16, z16, z16, z16, z16, zf, (short*)nullptr, (float*)nullptr, 0, 32, 0, 30000);
    // xw-proj: aggB = lrelu(xw @ WwinT')
    if (haveXW16){
        hipLaunchKernelGGL((mgemm2_kernel<0>), dim3(MT * 4), dim3(256), 0, stream,
            xw16, z16, z16, WwinT, z16, z16, zf, aggB, (float*)nullptr, 1, 1952, 1,
            z16, z16, z16, z16, z16, z16, zf, (short*)nullptr, (float*)nullptr, 0, 32, 0, 30000);
    } else {
        hipLaunchKernelGGL(mgemm_af32_kernel, dim3(4 * ((NW + 63) / 64)), dim3(128), 0, stream,
                           x_window, WwinT, aggB, NW);
    }
    // post-pair: h_exp = lrelu(aggA @ WpostT'); h_win = lrelu(aggB @ WpostT')
    hipLaunchKernelGGL((mgemm2_kernel<1>), dim3(2 * MT * 4), dim3(256), 0, stream,
        aggA, z16, z16, WpostT, z16, z16, zf, h16[1][0], (float*)nullptr, 1, 512, 1,
        aggB, z16, z16, WpostT, z16, z16, zf, h16[0][0], (float*)nullptr, 1, 512, 1, 30000);

    // ---- layers ----
    for (int l = 0; l < NL; ++l){
        int cur = l & 1, nxt = cur ^ 1;
        const short* wl_n = WlnT + (size_t)l * WHH;
        const short* wl_r = WlrT + (size_t)l * WHH;
        const short* wl_c = WlcT + (size_t)l * WHH;
        const short* wr_c = WrcT + (size_t)l * WHH;
        const short* wcb  = WcbT + (size_t)l * WHH;
        const float* bs   = bsum + (size_t)l * HD;
        const float* bc   = b_close + (size_t)l * HD;
        bool last = (l == NL - 1);

        hipLaunchKernelGGL(seg_mean3_kernel, dim3((3 * NW + 3) / 4), dim3(256), 0, stream,
                           h16[0][cur], h16[1][cur], off_n, el_n, off_r, el_r, off_c, el_c,
                           aggA, aggB, aggC);
        hipLaunchKernelGGL((mgemm2_kernel<1>), dim3(2 * MT * 4), dim3(256), 0, stream,
            aggA, aggB, h16[0][cur], wl_n, wl_r, wcb, bs, h16[0][nxt],
            last ? hwf : (float*)nullptr, 3, 512, 2,
            aggC, h16[1][cur], z16, wl_c, wr_c, z16, bc, h16[1][nxt],
            (last && haveF32) ? hef : (float*)nullptr, 2, 512, 1, 30000);
    }
    int fin = NL & 1;

    // ---- CSRA pooling (hwf = hwf + LAM*pooled, in place) ----
    if (haveF32){
        hipLaunchKernelGGL((score_kernel<1>), dim3((NE + 3) / 4), dim3(256), 0, stream,
                           (const void*)hef, w_pool, score);
        hipLaunchKernelGGL((pool_kernel<1>), dim3((NW + 3) / 4), dim3(256), 0, stream,
                           (const void*)hef, (const void*)hwf, score, off_r, el_r, hwf);
    } else {
        hipLaunchKernelGGL((score_kernel<0>), dim3((NE + 3) / 4), dim3(256), 0, stream,
                           (const void*)h16[1][fin], w_pool, score);
        hipLaunchKernelGGL((pool_kernel<0>), dim3((NW + 3) / 4), dim3(256), 0, stream,
                           (const void*)h16[1][fin], (const void*)hwf, score, off_r, el_r, hwf);
    }

    // ---- final linear (fp32) ----
    hipLaunchKernelGGL(gemm_kernel, dim3(2, (NW + 127) / 128), dim3(256), 0, stream,
                       hwf, W_lin, b_lin, out, NW, 100, HD);
}

// Round 7
// 1761.842 us; speedup vs baseline: 4.6925x; 1.0562x over previous
//
#include <hip/hip_runtime.h>
#include <hip/hip_bf16.h>
#include <cstdint>
#include <cstddef>

#define NW 30000
#define NE 30000
#define EE 480000
#define HD 512
#define NL 4
#define SLOPE 0.2f
#define LAM 0.5f
#define ROWP 30080  // rows padded to multiple of 128
#define MT 235      // 128-row m-tiles per ROWP matrix
#define WHH ((size_t)HD * HD)

typedef short short8 __attribute__((ext_vector_type(8)));
typedef float f32x4 __attribute__((ext_vector_type(4)));

static __device__ __forceinline__ float lrelu_f(float x){
    return fmaxf(x, 0.f) + SLOPE * fminf(x, 0.f);
}
static __device__ __forceinline__ short f2bf(float f){
    uint32_t u = __builtin_bit_cast(uint32_t, f);
    u += 0x7FFFu + ((u >> 16) & 1u);
    return (short)(u >> 16);
}
static __device__ __forceinline__ float bf2f(short s){
    uint32_t u = ((uint32_t)(uint16_t)s) << 16;
    return __builtin_bit_cast(float, u);
}

typedef const __attribute__((address_space(1))) void* gas_t;
typedef __attribute__((address_space(3))) void* las_t;
static __device__ __forceinline__ void gload16(const void* g, void* l){
    __builtin_amdgcn_global_load_lds((gas_t)g, (las_t)l, 16, 0, 0);
}

// ---------------- CSR build (3 relations per dispatch) ----------------

__global__ void count3_kernel(const int* __restrict__ dn, const int* __restrict__ dr,
                              const int* __restrict__ dc, int* __restrict__ deg){
    int z = blockIdx.y;
    const int* dst = (z == 0) ? dn : ((z == 1) ? dr : dc);
    int e = blockIdx.x * 256 + threadIdx.x;
    if (e < EE) atomicAdd(&deg[z * 30000 + dst[e]], 1);
}

__global__ void scan3_kernel(const int* __restrict__ deg, int* __restrict__ off3){
    const int* dg = deg + blockIdx.x * 30000;
    int* off = off3 + blockIdx.x * (NW + 1);
    int n = 30000;
    __shared__ int tmp[1024];
    int t = threadIdx.x;
    int carry = 0;
    if (t == 0) off[0] = 0;
    for (int base = 0; base < n; base += 1024){
        int v = (base + t < n) ? dg[base + t] : 0;
        tmp[t] = v; __syncthreads();
        for (int d = 1; d < 1024; d <<= 1){
            int add = (t >= d) ? tmp[t - d] : 0;
            __syncthreads();
            tmp[t] += add;
            __syncthreads();
        }
        if (base + t < n) off[base + t + 1] = tmp[t] + carry;
        carry += tmp[1023];
        __syncthreads();
    }
}

__global__ void fill3_kernel(const int* __restrict__ sn, const int* __restrict__ dn,
                             const int* __restrict__ sr, const int* __restrict__ dr,
                             const int* __restrict__ sc, const int* __restrict__ dc,
                             int* __restrict__ cur, const int* __restrict__ off3,
                             int* __restrict__ el3){
    int z = blockIdx.y;
    const int* src = (z == 0) ? sn : ((z == 1) ? sr : sc);
    const int* dst = (z == 0) ? dn : ((z == 1) ? dr : dc);
    const int* off = off3 + z * (NW + 1);
    int* el = el3 + (size_t)z * EE;
    int e = blockIdx.x * 256 + threadIdx.x;
    if (e < EE){
        int d = dst[e];
        int p = atomicAdd(&cur[z * 30000 + d], 1);
        el[off[d] + p] = src[e];
    }
}

// ---------------- weight transpose fp32[K,N] -> bf16[N,Kpad] ----------------

__global__ __launch_bounds__(256)
void transpose_bf_kernel(const float* __restrict__ in, short* __restrict__ out,
                         int K, int N, int Kpad){
    __shared__ float tile[32][33];
    int kbase = blockIdx.y * 32, nbase = blockIdx.x * 32;
    int tx = threadIdx.x & 31, ty = threadIdx.x >> 5;
    #pragma unroll
    for (int r = 0; r < 4; ++r){
        int k = kbase + ty + r * 8;
        float v = 0.f;
        if (k < K) v = in[(size_t)k * N + nbase + tx];
        tile[ty + r * 8][tx] = v;
    }
    __syncthreads();
    #pragma unroll
    for (int r = 0; r < 4; ++r){
        int n = nbase + ty + r * 8;
        int k = kbase + tx;
        if (k < Kpad) out[(size_t)n * Kpad + k] = f2bf(tile[tx][ty + r * 8]);
    }
}

// ---------------- all 21 HxH transposes in one dispatch ----------------

__global__ __launch_bounds__(256)
void transpose_all_kernel(const float* __restrict__ Wln, const float* __restrict__ Wlr,
                          const float* __restrict__ Wlc, const float* __restrict__ Wrc,
                          const float* __restrict__ Wrn, const float* __restrict__ Wrr,
                          const float* __restrict__ Wpost, short* __restrict__ outT){
    __shared__ float tile[32][33];
    int z = blockIdx.z;
    const float* a; const float* b = nullptr;
    if (z < 4) a = Wln + (size_t)z * WHH;
    else if (z < 8) a = Wlr + (size_t)(z - 4) * WHH;
    else if (z < 12) a = Wlc + (size_t)(z - 8) * WHH;
    else if (z < 16) a = Wrc + (size_t)(z - 12) * WHH;
    else if (z < 20){ a = Wrn + (size_t)(z - 16) * WHH; b = Wrr + (size_t)(z - 16) * WHH; }
    else a = Wpost;
    short* outp = outT + (size_t)z * WHH;
    int kbase = blockIdx.y * 32, nbase = blockIdx.x * 32;
    int tx = threadIdx.x & 31, ty = threadIdx.x >> 5;
    #pragma unroll
    for (int r = 0; r < 4; ++r){
        int k = kbase + ty + r * 8;
        float v = a[(size_t)k * HD + nbase + tx];
        if (b) v += b[(size_t)k * HD + nbase + tx];
        tile[ty + r * 8][tx] = v;
    }
    __syncthreads();
    #pragma unroll
    for (int r = 0; r < 4; ++r){
        int n = nbase + ty + r * 8;
        outp[(size_t)n * HD + kbase + tx] = f2bf(tile[tx][ty + r * 8]);
    }
}

__global__ void addf_kernel(const float* __restrict__ a, const float* __restrict__ b,
                            float* __restrict__ o, int n){
    int i = blockIdx.x * 256 + threadIdx.x;
    if (i < n) o[i] = a[i] + b[i];
}

// ---------------- x_window fp32 -> bf16 [ROWP][1952] ----------------

__global__ __launch_bounds__(256)
void conv_xw_kernel(const float* __restrict__ x, short* __restrict__ o){
    int idx = blockIdx.x * 256 + threadIdx.x;
    if (idx >= 30000 * 244) return;
    int row = idx / 244, c8 = idx - row * 244;
    int base = c8 * 8;
    short8 v = {};
    const float* xp = x + (size_t)row * 1949 + base;
    if (base + 8 <= 1949){
        f32x4 a = *(const f32x4*)xp;
        f32x4 bq = *(const f32x4*)(xp + 4);
        #pragma unroll
        for (int j = 0; j < 4; ++j){ v[j] = f2bf(a[j]); v[j + 4] = f2bf(bq[j]); }
    } else {
        #pragma unroll
        for (int j = 0; j < 8; ++j) if (base + j < 1949) v[j] = f2bf(xp[j]);
    }
    *(short8*)(o + (size_t)row * 1952 + base) = v;
}

// ---------------- x_example fp32[30000][100] -> bf16 [ROWP][128] ----------------

__global__ __launch_bounds__(256)
void conv_xe_kernel(const float* __restrict__ x, short* __restrict__ o){
    int idx = blockIdx.x * 256 + threadIdx.x;
    if (idx >= ROWP * 16) return;
    int row = idx >> 4, c8 = idx & 15;
    int base = c8 * 8;
    short8 v = {};
    if (row < 30000){
        const float* xp = x + (size_t)row * 100 + base;
        #pragma unroll
        for (int j = 0; j < 8; ++j) if (base + j < 100) v[j] = f2bf(xp[j]);
    }
    *(short8*)(o + (size_t)row * 128 + base) = v;
}

// ---------------- combined 3-relation segment mean ----------------

__global__ __launch_bounds__(256)
void seg_mean3_kernel(const short* __restrict__ hw, const short* __restrict__ he,
                      const int* __restrict__ off3, const int* __restrict__ el3,
                      short* __restrict__ aggA, short* __restrict__ aggB, short* __restrict__ aggC){
    int slot = blockIdx.x * 4 + (threadIdx.x >> 6);
    int lane = threadIdx.x & 63;
    if (slot >= 3 * NW) return;
    int seg = slot / NW;
    int dst = slot - seg * NW;
    const short* h = (seg == 0) ? hw : he;
    const int* off = off3 + seg * (NW + 1);
    const int* el = el3 + (size_t)seg * EE;
    short* out = (seg == 0) ? aggA : ((seg == 1) ? aggB : aggC);
    int s0 = off[dst], s1 = off[dst + 1];
    float acc[8] = {};
    int e = s0;
    for (; e + 8 <= s1; e += 8){
        int idx[8];
        #pragma unroll
        for (int u = 0; u < 8; ++u) idx[u] = el[e + u];
        short8 v[8];
        #pragma unroll
        for (int u = 0; u < 8; ++u) v[u] = *(const short8*)(h + (size_t)idx[u] * HD + lane * 8);
        #pragma unroll
        for (int u = 0; u < 8; ++u)
            #pragma unroll
            for (int j = 0; j < 8; ++j) acc[j] += bf2f(v[u][j]);
    }
    for (; e < s1; ++e){
        short8 v = *(const short8*)(h + (size_t)el[e] * HD + lane * 8);
        #pragma unroll
        for (int j = 0; j < 8; ++j) acc[j] += bf2f(v[j]);
    }
    float inv = (s1 > s0) ? 1.0f / (float)(s1 - s0) : 0.0f;
    short8 o8;
    #pragma unroll
    for (int j = 0; j < 8; ++j) o8[j] = f2bf(acc[j] * inv);
    *(short8*)(out + (size_t)dst * HD + lane * 8) = o8;
}

// ---------------- routed dual multi-GEMM, 128x128 tile, triple-buffer 1-barrier ----------------
// Per step: stage(s+1) [4 gload16] -> vmcnt(4) -> s_barrier -> compute(s).
// 3 LDS buffers: stage(s+1) writes (s+1)%3 while slowest wave computes (s-1)%3 -> no 2nd barrier.

template<int DUAL>
__global__ __launch_bounds__(256)
void mgemm2_kernel(
    const short* __restrict__ a00, const short* __restrict__ a01, const short* __restrict__ a02,
    const short* __restrict__ b00, const short* __restrict__ b01, const short* __restrict__ b02,
    const float* __restrict__ bias0, short* __restrict__ c160, float* __restrict__ c320,
    int np0, int kt0, int act0,
    const short* __restrict__ a10, const short* __restrict__ a11, const short* __restrict__ a12,
    const short* __restrict__ b10, const short* __restrict__ b11, const short* __restrict__ b12,
    const float* __restrict__ bias1, short* __restrict__ c161, float* __restrict__ c321,
    int np1, int kt1, int act1,
    int mreal){
    __shared__ short lds[24576];          // A: 3 x 4096 shorts at 0; B: 3 x 4096 at 12288

    int nwg = gridDim.x, orig = blockIdx.x;
    int q = nwg >> 3, r = nwg & 7;
    int xcd = orig & 7, lid = orig >> 3;
    int logical = (xcd < r ? xcd * (q + 1) : r * (q + 1) + (xcd - r) * q) + lid;
    int mtile = logical >> 2, nc = logical & 3;
    int dsel, ml;
    if (DUAL){ dsel = mtile & 1; ml = mtile >> 1; } else { dsel = 0; ml = mtile; }

    const short* A0 = dsel ? a10 : a00;
    const short* A1 = dsel ? a11 : a01;
    const short* A2 = dsel ? a12 : a02;
    const short* B0 = dsel ? b10 : b00;
    const short* B1 = dsel ? b11 : b01;
    const short* B2 = dsel ? b12 : b02;
    const float* bias = dsel ? bias1 : bias0;
    short* C16 = dsel ? c161 : c160;
    float* C32 = dsel ? c321 : c320;
    const int np = dsel ? np1 : np0;
    const int kt = dsel ? kt1 : kt0;
    const int act = dsel ? act1 : act0;

    const int row0 = ml * 128, n0 = nc * 128;
    const int t = threadIdx.x, wid = t >> 6, lane = t & 63;
    const int wm = (wid >> 1) * 64, wn = (wid & 1) * 64;
    const int lg = lane >> 4, lr = lane & 15;
    f32x4 acc[4][4] = {};

    int rowi[2], ci[2];
    #pragma unroll
    for (int i = 0; i < 2; ++i){
        int sl = i * 256 + t;
        rowi[i] = sl >> 2;
        ci[i] = (sl & 3) ^ ((rowi[i] >> 1) & 3);
    }
    const int kpt = kt >> 5;
    const int nsteps = np * kpt;

    const short* Acur = A0;
    const short* Bcur = B0;
    int sk = 0, sp = 0, sbuf = 0;

    auto stage = [&](){
        int k0 = sk * 32;
        #pragma unroll
        for (int i = 0; i < 2; ++i){
            int ao = (row0 + rowi[i]) * kt + k0 + ci[i] * 8;
            gload16(Acur + ao, &lds[sbuf * 4096 + (i * 256 + wid * 64) * 8]);
        }
        #pragma unroll
        for (int i = 0; i < 2; ++i){
            int bo = (n0 + rowi[i]) * kt + k0 + ci[i] * 8;
            gload16(Bcur + bo, &lds[12288 + sbuf * 4096 + (i * 256 + wid * 64) * 8]);
        }
        sbuf = (sbuf == 2) ? 0 : sbuf + 1;
        if (++sk == kpt){
            sk = 0; ++sp;
            Acur = (sp == 1) ? A1 : A2;
            Bcur = (sp == 1) ? B1 : B2;
        }
    };
    auto compute = [&](int cb){
        const char* baseA = (const char*)(lds + cb * 4096);
        const char* baseB = (const char*)(lds + 12288 + cb * 4096);
        short8 af[4], bfr[4];
        #pragma unroll
        for (int f = 0; f < 4; ++f){
            int rowA = wm + f * 16 + lr;
            af[f] = *(const short8*)(baseA + rowA * 64 + ((lg ^ ((rowA >> 1) & 3)) << 4));
            int rowB = wn + f * 16 + lr;
            bfr[f] = *(const short8*)(baseB + rowB * 64 + ((lg ^ ((rowB >> 1) & 3)) << 4));
        }
        #pragma unroll
        for (int i = 0; i < 4; ++i)
            #pragma unroll
            for (int j = 0; j < 4; ++j)
                acc[i][j] = __builtin_amdgcn_mfma_f32_16x16x32_bf16(af[i], bfr[j], acc[i][j], 0, 0, 0);
    };

    stage();
    int cbuf = 0;
    for (int s = 0; s < nsteps; ++s){
        if (s + 1 < nsteps){
            stage();
            asm volatile("s_waitcnt vmcnt(4)" ::: "memory");   // step-s loads complete; s+1 in flight
        } else {
            asm volatile("s_waitcnt vmcnt(0)" ::: "memory");
        }
        __builtin_amdgcn_s_barrier();                          // all waves' step-s data in LDS
        __builtin_amdgcn_sched_barrier(0);
        compute(cbuf);
        cbuf = (cbuf == 2) ? 0 : cbuf + 1;
    }

    float bv[4];
    #pragma unroll
    for (int f = 0; f < 4; ++f) bv[f] = bias ? bias[n0 + wn + f * 16 + lr] : 0.f;
    #pragma unroll
    for (int i = 0; i < 4; ++i){
        #pragma unroll
        for (int r2 = 0; r2 < 4; ++r2){
            int gr = row0 + wm + i * 16 + lg * 4 + r2;
            #pragma unroll
            for (int j = 0; j < 4; ++j){
                int gc = n0 + wn + j * 16 + lr;
                float v = acc[i][j][r2] + bv[j];
                if (act == 2) v *= 0.5f;
                if (act) v = lrelu_f(v);
                C16[(size_t)gr * HD + gc] = f2bf(v);
                if (C32 && gr < mreal) C32[(size_t)gr * HD + gc] = v;
            }
        }
    }
}

// ---------------- AF32 fallback (x_window proj only, if ws too small) ----------------

__global__ __launch_bounds__(128)
void mgemm_af32_kernel(const float* __restrict__ A0, const short* __restrict__ B0,
                       short* __restrict__ C16, int M){
    constexpr int KT = 1952, KACT = 1949, KPT = KT / 32, NSTEPS = KPT, N = 512;
    __shared__ short ldsA[2][2048];
    __shared__ short ldsB[2][4096];
    int nwg = gridDim.x;
    int orig = blockIdx.x;
    int q = nwg >> 3, r = nwg & 7;
    int xcd = orig & 7, lid = orig >> 3;
    int logical = (xcd < r ? xcd * (q + 1) : r * (q + 1) + (xcd - r) * q) + lid;
    const int m0 = (logical >> 2) * 64, n0 = (logical & 3) * 128;
    const int t = threadIdx.x, wid = t >> 6, lane = t & 63;
    const int wn = wid * 64;
    const int lg = lane >> 4, lr = lane & 15;
    f32x4 acc[4][4] = {};
    int rowiA[2], ciA[2];
    #pragma unroll
    for (int i = 0; i < 2; ++i){
        int sl = i * 128 + t;
        rowiA[i] = sl >> 2;
        ciA[i] = (sl & 3) ^ ((rowiA[i] >> 1) & 3);
    }
    int rowiB[4], ciB[4];
    #pragma unroll
    for (int i = 0; i < 4; ++i){
        int sl = i * 128 + t;
        rowiB[i] = sl >> 2;
        ciB[i] = (sl & 3) ^ ((rowiB[i] >> 1) & 3);
    }
    f32x4 ra[2][2];
    auto stage_load = [&](int s){
        int k0 = s * 32;
        int bb = s & 1;
        #pragma unroll
        for (int i = 0; i < 2; ++i){
            int gr = m0 + rowiA[i];
            int gk = k0 + ciA[i] * 8;
            ra[i][0] = (f32x4){0,0,0,0};
            ra[i][1] = (f32x4){0,0,0,0};
            if (gr < M){
                const float* ap = A0 + (size_t)gr * KACT + gk;
                if (gk + 8 <= KACT){
                    ra[i][0] = *(const f32x4*)ap;
                    ra[i][1] = *(const f32x4*)(ap + 4);
                } else {
                    #pragma unroll
                    for (int j = 0; j < 8; ++j)
                        if (gk + j < KACT) ra[i][j >> 2][j & 3] = ap[j];
                }
            }
        }
        #pragma unroll
        for (int i = 0; i < 4; ++i)
            gload16(B0 + (size_t)(n0 + rowiB[i]) * KT + k0 + ciB[i] * 8,
                    &ldsB[bb][(i * 128 + wid * 64) * 8]);
    };
    auto stage_writeA = [&](int s){
        int bb = s & 1;
        #pragma unroll
        for (int i = 0; i < 2; ++i){
            short8 v;
            #pragma unroll
            for (int j = 0; j < 8; ++j) v[j] = f2bf(ra[i][j >> 2][j & 3]);
            *(short8*)&ldsA[bb][(i * 128 + t) * 8] = v;
        }
    };
    auto compute = [&](int s){
        int bb = s & 1;
        short8 af[4], bfr[4];
        #pragma unroll
        for (int f = 0; f < 4; ++f){
            int rowA = f * 16 + lr;
            af[f] = *(const short8*)((const char*)&ldsA[bb][0] + rowA * 64 + ((lg ^ ((rowA >> 1) & 3)) << 4));
            int rowB = wn + f * 16 + lr;
            bfr[f] = *(const short8*)((const char*)&ldsB[bb][0] + rowB * 64 + ((lg ^ ((rowB >> 1) & 3)) << 4));
        }
        #pragma unroll
        for (int i = 0; i < 4; ++i)
            #pragma unroll
            for (int j = 0; j < 4; ++j)
                acc[i][j] = __builtin_amdgcn_mfma_f32_16x16x32_bf16(af[i], bfr[j], acc[i][j], 0, 0, 0);
    };
    stage_load(0);
    stage_writeA(0);
    __syncthreads();
    for (int s = 0; s < NSTEPS; ++s){
        if (s + 1 < NSTEPS) stage_load(s + 1);
        compute(s);
        if (s + 1 < NSTEPS) stage_writeA(s + 1);
        __syncthreads();
    }
    #pragma unroll
    for (int i = 0; i < 4; ++i){
        #pragma unroll
        for (int r2 = 0; r2 < 4; ++r2){
            int gr = m0 + i * 16 + lg * 4 + r2;
            if (gr >= M) continue;
            #pragma unroll
            for (int j = 0; j < 4; ++j){
                int gc = n0 + wn + j * 16 + lr;
                C16[(size_t)gr * N + gc] = f2bf(lrelu_f(acc[i][j][r2]));
            }
        }
    }
}

// ---------------- fp32 tiled GEMM (final 512->100 only) ----------------

__global__ __launch_bounds__(256)
void gemm_kernel(const float* __restrict__ A, const float* __restrict__ B,
                 const float* __restrict__ bias, float* __restrict__ C,
                 int M, int N, int K){
    const int BM = 128, BN = 64, BK = 16;
    __shared__ float As[BK][BM];
    __shared__ float Bs[BK][BN];
    int m0 = blockIdx.y * BM, n0 = blockIdx.x * BN;
    int t = threadIdx.x;
    int tx = t & 15, ty = t >> 4;
    float acc[8][4] = {};
    for (int k0 = 0; k0 < K; k0 += BK){
        #pragma unroll
        for (int i = 0; i < 2; ++i){
            int idx = i * 256 + t;
            int row = idx >> 2, kg = idx & 3;
            float4 v = make_float4(0,0,0,0);
            int gr = m0 + row, gk = k0 + kg * 4;
            if (gr < M && gk + 4 <= K)
                v = *reinterpret_cast<const float4*>(A + (size_t)gr * K + gk);
            As[kg*4+0][row] = v.x; As[kg*4+1][row] = v.y;
            As[kg*4+2][row] = v.z; As[kg*4+3][row] = v.w;
        }
        {
            int row = t >> 4, cg = t & 15;
            int gk = k0 + row, col = n0 + cg * 4;
            float4 v = make_float4(0,0,0,0);
            if (gk < K){
                if (col + 4 <= N){
                    v = *reinterpret_cast<const float4*>(B + (size_t)gk * N + col);
                } else {
                    float tp[4] = {0,0,0,0};
                    #pragma unroll
                    for (int j = 0; j < 4; ++j) if (col + j < N) tp[j] = B[(size_t)gk * N + col + j];
                    v = make_float4(tp[0], tp[1], tp[2], tp[3]);
                }
            }
            *reinterpret_cast<float4*>(&Bs[row][cg*4]) = v;
        }
        __syncthreads();
        #pragma unroll
        for (int k = 0; k < BK; ++k){
            float a[8], b[4];
            #pragma unroll
            for (int r = 0; r < 8; ++r) a[r] = As[k][ty*8 + r];
            #pragma unroll
            for (int c = 0; c < 4; ++c) b[c] = Bs[k][tx*4 + c];
            #pragma unroll
            for (int r = 0; r < 8; ++r)
                #pragma unroll
                for (int c = 0; c < 4; ++c)
                    acc[r][c] = fmaf(a[r], b[c], acc[r][c]);
        }
        __syncthreads();
    }
    #pragma unroll
    for (int r = 0; r < 8; ++r){
        int gr = m0 + ty*8 + r;
        if (gr >= M) continue;
        #pragma unroll
        for (int c = 0; c < 4; ++c){
            int gc = n0 + tx*4 + c;
            if (gc >= N) continue;
            C[(size_t)gr * N + gc] = acc[r][c] + bias[gc];
        }
    }
}

// ---------------- pooling (bf16 gather) ----------------

__global__ void score_kernel(const short* __restrict__ he, const float* __restrict__ w,
                             float* __restrict__ score){
    int row = blockIdx.x * 4 + (threadIdx.x >> 6);
    int lane = threadIdx.x & 63;
    if (row >= NE) return;
    float s = 0.f;
    #pragma unroll
    for (int j = 0; j < 8; ++j){
        int idx = lane + j * 64;
        s += bf2f(he[(size_t)row * HD + idx]) * w[idx];
    }
    #pragma unroll
    for (int off = 32; off > 0; off >>= 1) s += __shfl_down(s, off);
    if (lane == 0) score[row] = s;
}

__global__ __launch_bounds__(256)
void pool_kernel(const short* __restrict__ he, const float* __restrict__ hwf,
                 const float* __restrict__ score, const int* __restrict__ off,
                 const int* __restrict__ elist, float* __restrict__ outp){
    int dst = blockIdx.x * 4 + (threadIdx.x >> 6);
    int lane = threadIdx.x & 63;
    if (dst >= NW) return;
    int s0 = off[dst], s1 = off[dst + 1];
    float m = -INFINITY;
    for (int e = s0 + lane; e < s1; e += 64) m = fmaxf(m, score[elist[e]]);
    #pragma unroll
    for (int o = 1; o < 64; o <<= 1) m = fmaxf(m, __shfl_xor(m, o));
    float z = 0.f;
    for (int e = s0 + lane; e < s1; e += 64) z += expf(score[elist[e]] - m);
    #pragma unroll
    for (int o = 1; o < 64; o <<= 1) z += __shfl_xor(z, o);
    float zinv = 1.0f / fmaxf(z, 1e-12f);

    float acc[8] = {};
    int e = s0;
    for (; e + 4 <= s1; e += 4){
        int idx[4]; float at[4];
        #pragma unroll
        for (int u = 0; u < 4; ++u) idx[u] = elist[e + u];
        #pragma unroll
        for (int u = 0; u < 4; ++u) at[u] = expf(score[idx[u]] - m) * zinv;
        #pragma unroll
        for (int u = 0; u < 4; ++u){
            short8 v = *(const short8*)(he + (size_t)idx[u] * HD + lane * 8);
            #pragma unroll
            for (int k = 0; k < 8; ++k) acc[k] += at[u] * bf2f(v[k]);
        }
    }
    for (; e < s1; ++e){
        int src = elist[e];
        float at = expf(score[src] - m) * zinv;
        short8 v = *(const short8*)(he + (size_t)src * HD + lane * 8);
        #pragma unroll
        for (int k = 0; k < 8; ++k) acc[k] += at * bf2f(v[k]);
    }
    f32x4 h0 = *(const f32x4*)(hwf + (size_t)dst * HD + lane * 8);
    f32x4 h1 = *(const f32x4*)(hwf + (size_t)dst * HD + lane * 8 + 4);
    f32x4 o0, o1;
    #pragma unroll
    for (int k = 0; k < 4; ++k){ o0[k] = h0[k] + LAM * acc[k]; o1[k] = h1[k] + LAM * acc[k+4]; }
    *(f32x4*)(outp + (size_t)dst * HD + lane * 8) = o0;
    *(f32x4*)(outp + (size_t)dst * HD + lane * 8 + 4) = o1;
}

// ---------------- host ----------------

extern "C" void kernel_launch(void* const* d_in, const int* in_sizes, int n_in,
                              void* d_out, int out_size, void* d_ws, size_t ws_size,
                              hipStream_t stream){
    const float* x_window = (const float*)d_in[0];
    const float* x_example= (const float*)d_in[1];
    const int*   e_near   = (const int*)d_in[2];
    const int*   e_close  = (const int*)d_in[3];
    const int*   e_refer  = (const int*)d_in[4];
    const float* W_win    = (const float*)d_in[5];
    const float* W_exp    = (const float*)d_in[6];
    const float* W_post   = (const float*)d_in[7];
    const float* Wl_near  = (const float*)d_in[9];
    const float* Wr_near  = (const float*)d_in[10];
    const float* b_near   = (const float*)d_in[11];
    const float* Wl_close = (const float*)d_in[12];
    const float* Wr_close = (const float*)d_in[13];
    const float* b_close  = (const float*)d_in[14];
    const float* Wl_refer = (const float*)d_in[15];
    const float* Wr_refer = (const float*)d_in[16];
    const float* b_refer  = (const float*)d_in[17];
    const float* w_pool   = (const float*)d_in[18];
    const float* W_lin    = (const float*)d_in[19];
    const float* b_lin    = (const float*)d_in[20];
    float* out = (float*)d_out;
    (void)in_sizes; (void)n_in; (void)out_size;

    char* w = (char*)d_ws;
    size_t o = 0;
    auto alloc = [&](size_t bytes)->char*{
        char* p = w + o;
        o += (bytes + 255) & ~(size_t)255;
        return p;
    };
    const size_t HBH = (size_t)ROWP * HD * 2;

    short* h16[2][2];
    h16[0][0] = (short*)alloc(HBH); h16[0][1] = (short*)alloc(HBH);
    h16[1][0] = (short*)alloc(HBH); h16[1][1] = (short*)alloc(HBH);
    short* aggA = (short*)alloc(HBH);
    short* aggB = (short*)alloc(HBH);
    short* aggC = (short*)alloc(HBH);
    float* hwf  = (float*)alloc((size_t)NW * HD * 4);
    float* pooled = (float*)alloc((size_t)NW * HD * 4);
    short* xe16   = (short*)alloc((size_t)ROWP * 128 * 2);
    short* WwinT  = (short*)alloc((size_t)HD * 1952 * 2);
    short* WexpT  = (short*)alloc((size_t)HD * 128 * 2);
    short* WT     = (short*)alloc((size_t)21 * WHH * 2);
    short* WlnT = WT;
    short* WlrT = WT + 4 * WHH;
    short* WlcT = WT + 8 * WHH;
    short* WrcT = WT + 12 * WHH;
    short* WcbT = WT + 16 * WHH;
    short* WpostT = WT + 20 * WHH;
    float* bsum   = (float*)alloc((size_t)NL * HD * 4);
    float* score  = (float*)alloc((size_t)NE * 4);
    int* degcur = (int*)alloc((size_t)6 * 30000 * 4);
    int* deg3 = degcur;                  // 3 x 30000
    int* cur3 = degcur + 90000;          // 3 x 30000
    int* off3 = (int*)alloc((size_t)3 * (NW + 1) * 4);
    int* el3  = (int*)alloc((size_t)3 * EE * 4);
    int* off_r = off3 + (NW + 1);

    const size_t XWB = (size_t)ROWP * 1952 * 2;
    bool haveXW16 = false;
    short* xw16 = nullptr;
    size_t rem = (ws_size > o) ? ws_size - o : 0;
    if (rem >= XWB + 256){
        xw16 = (short*)alloc(XWB);
        haveXW16 = true;
    }

    const int* src_n = e_near;  const int* dst_n = e_near + EE;
    const int* src_c = e_close; const int* dst_c = e_close + EE;
    const int* src_r = e_refer; const int* dst_r = e_refer + EE;

    // ---- CSR build ----
    hipMemsetAsync(degcur, 0, (size_t)6 * 30000 * 4, stream);
    int eg = (EE + 255) / 256;
    hipLaunchKernelGGL(count3_kernel, dim3(eg, 3), dim3(256), 0, stream, dst_n, dst_r, dst_c, deg3);
    hipLaunchKernelGGL(scan3_kernel, dim3(3), dim3(1024), 0, stream, deg3, off3);
    hipLaunchKernelGGL(fill3_kernel, dim3(eg, 3), dim3(256), 0, stream,
                       src_n, dst_n, src_r, dst_r, src_c, dst_c, cur3, off3, el3);

    // ---- conversions / transposes ----
    hipLaunchKernelGGL(transpose_bf_kernel, dim3(16, 61, 1), dim3(256), 0, stream,
                       W_win, WwinT, 1949, HD, 1952);
    hipLaunchKernelGGL(transpose_bf_kernel, dim3(16, 4, 1), dim3(256), 0, stream,
                       W_exp, WexpT, 100, HD, 128);
    hipLaunchKernelGGL(transpose_all_kernel, dim3(16, 16, 21), dim3(256), 0, stream,
                       Wl_near, Wl_refer, Wl_close, Wr_close, Wr_near, Wr_refer, W_post, WT);
    hipLaunchKernelGGL(addf_kernel, dim3((NL * HD + 255) / 256), dim3(256), 0, stream,
                       b_near, b_refer, bsum, NL * HD);
    hipLaunchKernelGGL(conv_xe_kernel, dim3((ROWP * 16 + 255) / 256), dim3(256), 0, stream,
                       x_example, xe16);
    if (haveXW16)
        hipLaunchKernelGGL(conv_xw_kernel, dim3((30000 * 244 + 255) / 256), dim3(256), 0, stream,
                           x_window, xw16);

    const short* z16 = xe16;
    const float* zf = nullptr;

    // ---- feature projections ----
    hipLaunchKernelGGL((mgemm2_kernel<0>), dim3(MT * 4), dim3(256), 0, stream,
        xe16, z16, z16, WexpT, z16, z16, zf, aggA, (float*)nullptr, 1, 128, 1,
        z16, z16, z16, z16, z16, z16, zf, (short*)nullptr, (float*)nullptr, 0, 32, 0, 30000);
    if (haveXW16){
        hipLaunchKernelGGL((mgemm2_kernel<0>), dim3(MT * 4), dim3(256), 0, stream,
            xw16, z16, z16, WwinT, z16, z16, zf, aggB, (float*)nullptr, 1, 1952, 1,
            z16, z16, z16, z16, z16, z16, zf, (short*)nullptr, (float*)nullptr, 0, 32, 0, 30000);
    } else {
        hipLaunchKernelGGL(mgemm_af32_kernel, dim3(4 * ((NW + 63) / 64)), dim3(128), 0, stream,
                           x_window, WwinT, aggB, NW);
    }
    hipLaunchKernelGGL((mgemm2_kernel<1>), dim3(2 * MT * 4), dim3(256), 0, stream,
        aggA, z16, z16, WpostT, z16, z16, zf, h16[1][0], (float*)nullptr, 1, 512, 1,
        aggB, z16, z16, WpostT, z16, z16, zf, h16[0][0], (float*)nullptr, 1, 512, 1, 30000);

    // ---- layers ----
    for (int l = 0; l < NL; ++l){
        int cur = l & 1, nxt = cur ^ 1;
        const short* wl_n = WlnT + (size_t)l * WHH;
        const short* wl_r = WlrT + (size_t)l * WHH;
        const short* wl_c = WlcT + (size_t)l * WHH;
        const short* wr_c = WrcT + (size_t)l * WHH;
        const short* wcb  = WcbT + (size_t)l * WHH;
        const float* bs   = bsum + (size_t)l * HD;
        const float* bc   = b_close + (size_t)l * HD;
        bool last = (l == NL - 1);

        hipLaunchKernelGGL(seg_mean3_kernel, dim3((3 * NW + 3) / 4), dim3(256), 0, stream,
                           h16[0][cur], h16[1][cur], off3, el3, aggA, aggB, aggC);
        hipLaunchKernelGGL((mgemm2_kernel<1>), dim3(2 * MT * 4), dim3(256), 0, stream,
            aggA, aggB, h16[0][cur], wl_n, wl_r, wcb, bs, h16[0][nxt],
            last ? hwf : (float*)nullptr, 3, 512, 2,
            aggC, h16[1][cur], z16, wl_c, wr_c, z16, bc, h16[1][nxt],
            (float*)nullptr, 2, 512, 1, 30000);
    }
    int fin = NL & 1;

    // ---- CSRA pooling: pooled = hwf + LAM * attn-gather(h_exp bf16) ----
    hipLaunchKernelGGL(score_kernel, dim3((NE + 3) / 4), dim3(256), 0, stream,
                       h16[1][fin], w_pool, score);
    hipLaunchKernelGGL(pool_kernel, dim3((NW + 3) / 4), dim3(256), 0, stream,
                       h16[1][fin], hwf, score, off_r, el3 + (size_t)EE, pooled);

    // ---- final linear (fp32) ----
    hipLaunchKernelGGL(gemm_kernel, dim3(2, (NW + 127) / 128), dim3(256), 0, stream,
                       pooled, W_lin, b_lin, out, NW, 100, HD);
}